// Round 8
// baseline (491.067 us; speedup 1.0000x reference)
//
#include <hip/hip_runtime.h>
#include <cmath>

#define CDIV(a,b) (((a)+(b)-1)/(b))

typedef unsigned short bf16_t;
using short8 = __attribute__((ext_vector_type(8))) short;
using f32x4  = __attribute__((ext_vector_type(4))) float;
using u16x4  = __attribute__((ext_vector_type(4))) unsigned short;
using u16x8  = __attribute__((ext_vector_type(8))) unsigned short;

__device__ __forceinline__ float bf2f(unsigned short b) {
    unsigned u = ((unsigned)b) << 16;
    float f;
    __builtin_memcpy(&f, &u, 4);
    return f;
}
__device__ __forceinline__ unsigned short f2bf(float f) {
    unsigned u;
    __builtin_memcpy(&u, &f, 4);
    u = (u + 0x7FFFu + ((u >> 16) & 1u)) >> 16;
    return (unsigned short)u;
}

// async global->LDS, 16B per lane. LDS dest must be linear in lane order
// (wave-uniform base + lane*16); swizzle is folded into the GLOBAL address.
__device__ __forceinline__ void gload16(const bf16_t* g, unsigned short* l) {
    __builtin_amdgcn_global_load_lds(
        (const __attribute__((address_space(1))) void*)(g),
        (__attribute__((address_space(3))) void*)(l), 16, 0, 0);
}

__device__ __forceinline__ int edge_src(const int* ei, int E, int f, int i) {
    return f ? ei[2 * (size_t)i] : ei[i];
}
__device__ __forceinline__ int edge_dst(const int* ei, int E, int f, int i) {
    return f ? ei[2 * ((size_t)E + (size_t)i)] : ei[(size_t)E + (size_t)i];
}

// ---- pack edges to int32 + 8x-privatized dst histogram (detect inlined) ----
__global__ __launch_bounds__(256) void k_packhist(const int* __restrict__ ei, int E,
                                                  int* __restrict__ src32,
                                                  int* __restrict__ dst32,
                                                  int* __restrict__ cnt8, int N) {
    __shared__ int sflag;
    int t = threadIdx.x;
    if (t < 64) {   // whole wave 0: detect int64 layout from first 64 edges
        unsigned v = (unsigned)ei[2 * t + 1];
        unsigned long long m = __ballot(v != 0u);
        if (t == 0) sflag = (m == 0ULL) ? 1 : 0;
    }
    __syncthreads();
    int i = blockIdx.x * 256 + t;
    if (i >= E) return;
    int f = sflag;
    int s = edge_src(ei, E, f, i);
    int d = edge_dst(ei, E, f, i);
    src32[i] = s;
    dst32[i] = d;
    if ((unsigned)d < (unsigned)N)
        atomicAdd(&cnt8[(blockIdx.x & 7) * N + d], 1);
}

__global__ void k_blockred(const int* __restrict__ cnt8, int* __restrict__ bsum, int N) {
    __shared__ int sd[256];
    int b = blockIdx.x, t = threadIdx.x;
    int base = b * 1024 + t * 4;
    int s = 0;
#pragma unroll
    for (int i = 0; i < 4; i++) {
        int idx = base + i;
        if (idx < N)
#pragma unroll
            for (int r = 0; r < 8; r++) s += cnt8[r * N + idx];
    }
    sd[t] = s; __syncthreads();
    for (int off = 128; off > 0; off >>= 1) { if (t < off) sd[t] += sd[t + off]; __syncthreads(); }
    if (t == 0) bsum[b] = sd[0];
}

// scanwrite with the bsum scan inlined (each block redundantly scans <=256
// partials in LDS — no separate k_scanpartials dispatch).
__global__ void k_scanwrite(const int* __restrict__ cnt8, const int* __restrict__ bsum,
                            int* __restrict__ rowptr, int* __restrict__ cur,
                            float* __restrict__ dis, int N, int nb) {
    __shared__ int sb[256];
    __shared__ int sd[256];
    int b = blockIdx.x, t = threadIdx.x;
    int v0 = (t < nb) ? bsum[t] : 0;
    sb[t] = v0; __syncthreads();
    for (int off = 1; off < 256; off <<= 1) {
        int y = (t >= off) ? sb[t - off] : 0;
        __syncthreads();
        sb[t] += y;
        __syncthreads();
    }
    int block_pre = (b == 0) ? 0 : sb[b - 1];

    int base = b * 1024 + t * 4;
    int tot[4]; int s = 0;
#pragma unroll
    for (int i = 0; i < 4; i++) {
        int idx = base + i;
        tot[i] = 0;
        if (idx < N) {
#pragma unroll
            for (int r = 0; r < 8; r++) tot[i] += cnt8[r * N + idx];
        }
        s += tot[i];
    }
    sd[t] = s; __syncthreads();
    for (int off = 1; off < 256; off <<= 1) {
        int y = (t >= off) ? sd[t - off] : 0;
        __syncthreads();
        sd[t] += y;
        __syncthreads();
    }
    int pre = block_pre + sd[t] - s;
#pragma unroll
    for (int i = 0; i < 4; i++) {
        int idx = base + i;
        if (idx < N) {
            rowptr[idx] = pre;
            cur[idx] = pre;
            dis[idx] = rsqrtf((float)tot[i] + 1.0f);
            pre += tot[i];
        } else if (idx == N) {
            rowptr[N] = pre;
        }
    }
}

// Range-filtered fill: block b handles edge chunk (b>>3) restricted to dst
// range (b&7); consecutive blockIdx round-robin across XCDs so each csr
// region is written from ONE XCD's L2 (kills cross-XCD partial-line write
// amplification).
#define FILL_EPB 4096
__global__ __launch_bounds__(256) void k_fill_r(
        const int* __restrict__ src32, const int* __restrict__ dst32, int E,
        int* __restrict__ cur, int* __restrict__ csr, int N, int NR) {
    int r = blockIdx.x & 7;
    int chunk = blockIdx.x >> 3;
    int lo = r * NR;
    int hi = min(lo + NR, N);
    int base = chunk * FILL_EPB;
    int end = min(base + FILL_EPB, E);
    for (int i = base + threadIdx.x; i < end; i += 256) {
        int d = dst32[i];
        if (d >= lo && d < hi) {
            int s = src32[i];
            if ((unsigned)s < (unsigned)N) {
                int p = atomicAdd(&cur[d], 1);
                csr[p] = s;
            }
        }
    }
}

// ---------------- weight pre-convert: fp32 [M,KW] -> bf16 [M,KP] ------------
// Segment 5 is the x pad/convert; indices past wtotal zero-fill cnt8
// (replaces the hipMemsetAsync dispatch; k_wconv precedes k_packhist).

struct WcSeg { const float* src; bf16_t* dst; int M, KW, KP, nchunk; };

__global__ __launch_bounds__(256) void k_wconv(WcSeg s0, WcSeg s1, WcSeg s2,
                                               WcSeg s3, WcSeg s4, WcSeg s5,
                                               int wtotal, int* __restrict__ zdst,
                                               int total) {
    int i = blockIdx.x * 256 + threadIdx.x;
    if (i >= total) return;
    if (i >= wtotal) {   // zero-fill tail: 16 B of cnt8 per thread
        int4 z = {0, 0, 0, 0};
        *(int4*)(zdst + (size_t)(i - wtotal) * 4) = z;
        return;
    }
    WcSeg s;
    if (i < s0.nchunk) s = s0;
    else if ((i -= s0.nchunk) < s1.nchunk) s = s1;
    else if ((i -= s1.nchunk) < s2.nchunk) s = s2;
    else if ((i -= s2.nchunk) < s3.nchunk) s = s3;
    else if ((i -= s3.nchunk) < s4.nchunk) s = s4;
    else { i -= s4.nchunk; s = s5; }
    int cpr = s.KP >> 3;                // chunks per row
    int row = i / cpr, kk = (i % cpr) << 3;
    short8 v = {};
    if (kk < s.KW) {
        const float4* p = (const float4*)(s.src + (size_t)row * s.KW + kk);
        float4 a = p[0], b = p[1];
        v[0] = (short)f2bf(a.x); v[1] = (short)f2bf(a.y);
        v[2] = (short)f2bf(a.z); v[3] = (short)f2bf(a.w);
        v[4] = (short)f2bf(b.x); v[5] = (short)f2bf(b.y);
        v[6] = (short)f2bf(b.z); v[7] = (short)f2bf(b.w);
    }
    *(short8*)(s.dst + (size_t)row * s.KP + kk) = v;
}

// ---------------- MFMA GEMM: C[i][j] = sum_k A[i][k] * Wb[j][k] --------------
// Staging via global_load_lds w=16: linear LDS dest, XOR-swizzle folded into
// the global source chunk index. A rows clamped to N-1 (masked at store).
// SPLIT path: 1D grid, XCD-grouped decode — all nx M-tile blocks of one
// (y,z) pair land on the SAME XCD so the shared A-tile is fetched from HBM
// once and served from that XCD's L2.

template <bool CBF, bool BIAS, int ACT, bool SPLIT>
__global__ __launch_bounds__(256) void gemm_mfma(
        const bf16_t* __restrict__ A, const bf16_t* __restrict__ Wb,
        const float* __restrict__ bias, void* __restrict__ Cv,
        int N, int K, int M, int Kseg, int nx, int ny) {
    constexpr int BM = 128, BK = 64;
    __shared__ __align__(16) unsigned short lds[4 * 64 * 68];
    unsigned short* Als = lds;
    unsigned short* Bls = lds + BM * BK;

    int t = threadIdx.x;
    int lane = t & 63, wid = t >> 6;
    int quad = lane >> 4, l15 = lane & 15;
    int wave_m = wid & 1, wave_n = wid >> 1;

    int bx, by, bz;
    if (SPLIT) {
        int bid = (int)blockIdx.x;
        int xcd = bid & 7, li = bid >> 3;
        bx = li % nx;
        int pl = li / nx;
        int ppx = (int)(gridDim.x >> 3) / nx;   // pairs per XCD
        int pair = xcd * ppx + pl;
        by = pair % ny;
        bz = pair / ny;
    } else {
        bx = blockIdx.x; by = blockIdx.y; bz = 0;
    }

    int bm0 = by * BM;     // node tile
    int bn0 = bx * BM;     // M tile
    int kbeg = SPLIT ? bz * Kseg : 0;
    int kend = SPLIT ? min(kbeg + Kseg, K) : K;

    f32x4 acc[4][4] = {};

    for (int k0 = kbeg; k0 < kend; k0 += BK) {
#pragma unroll
        for (int it = 0; it < 4; it++) {
            int idx = t + it * 256;
            int row = idx >> 3, sc = idx & 7;
            int c = sc ^ (row & 7);            // pre-swizzled source chunk
            int ga = bm0 + row; if (ga >= N) ga = N - 1;   // clamp (masked at store)
            gload16(A + (size_t)ga * K + k0 + c * 8, Als + idx * 8);
            gload16(Wb + (size_t)(bn0 + row) * K + k0 + c * 8, Bls + idx * 8);
        }
        __syncthreads();                        // drains vmcnt

#pragma unroll
        for (int ks = 0; ks < 2; ks++) {
            short8 af[4], bfr[4];
            int ck = ks * 4 + quad;
            int sw = (ck ^ (l15 & 7)) << 3;
#pragma unroll
            for (int mt = 0; mt < 4; mt++)
                af[mt] = *(const short8*)&Als[(wave_m * 64 + mt * 16 + l15) * BK + sw];
#pragma unroll
            for (int nt = 0; nt < 4; nt++)
                bfr[nt] = *(const short8*)&Bls[(wave_n * 64 + nt * 16 + l15) * BK + sw];
#pragma unroll
            for (int mt = 0; mt < 4; mt++)
#pragma unroll
                for (int nt = 0; nt < 4; nt++)
                    acc[mt][nt] = __builtin_amdgcn_mfma_f32_16x16x32_bf16(
                        af[mt], bfr[nt], acc[mt][nt], 0, 0, 0);
        }
        __syncthreads();
    }

    if (!SPLIT && CBF) {
        constexpr int TST = 68;
        unsigned short* tw = lds + wid * 64 * TST;
#pragma unroll
        for (int mt = 0; mt < 4; mt++) {
#pragma unroll
            for (int nt = 0; nt < 4; nt++) {
                int tcol = nt * 16 + l15;
                float bv = BIAS ? bias[bn0 + wave_n * 64 + tcol] : 0.f;
#pragma unroll
                for (int r = 0; r < 4; r++) {
                    float x = acc[mt][nt][r];
                    if (BIAS) x += bv;
                    if (ACT == 1) x = x > 0.f ? x : 0.1f * x;
                    tw[(mt * 16 + quad * 4 + r) * TST + tcol] = f2bf(x);
                }
            }
        }
        __syncthreads();
        bf16_t* C = (bf16_t*)Cv;
        int lrow0 = lane >> 3, lcol = (lane & 7) * 8;
#pragma unroll
        for (int it = 0; it < 8; it++) {
            int lrow = it * 8 + lrow0;
            int row = bm0 + wave_m * 64 + lrow;
            if (row < N) {
                u16x8 v = *(const u16x8*)&tw[lrow * TST + lcol];
                *(u16x8*)&C[(size_t)row * M + bn0 + wave_n * 64 + lcol] = v;
            }
        }
    } else {
        float* Pz = SPLIT ? ((float*)Cv + (size_t)bz * N * M) : (float*)Cv;
#pragma unroll
        for (int mt = 0; mt < 4; mt++) {
            int rbase = bm0 + wave_m * 64 + mt * 16 + quad * 4;
#pragma unroll
            for (int nt = 0; nt < 4; nt++) {
                int col = bn0 + wave_n * 64 + nt * 16 + l15;
                float bv = (BIAS && !SPLIT) ? bias[col] : 0.f;
#pragma unroll
                for (int r = 0; r < 4; r++) {
                    int row = rbase + r;
                    if (row >= N) continue;
                    float x = acc[mt][nt][r];
                    if (!SPLIT) {
                        if (BIAS) x += bv;
                        if (ACT == 1) x = x > 0.f ? x : 0.1f * x;
                    }
                    Pz[(size_t)row * M + col] = x;
                }
            }
        }
    }
}

// ---------------- MLP2 GEMM with fused MLP1-reduce in A-staging -------------
__global__ __launch_bounds__(256) void gemm_mlp2(
        const float* __restrict__ part6,   // [6][G*512] fp32
        const float* __restrict__ L1b,     // [512]
        const bf16_t* __restrict__ Wb,     // L2wb [128,512] bf16
        float* __restrict__ Pout,          // [4][G*128] fp32
        int G) {
    constexpr int BM = 128, BK = 64, K = 512, M = 128, NY = 40;
    __shared__ __align__(16) unsigned short lds[2 * BM * BK];   // 32 KB
    unsigned short* Als = lds;
    unsigned short* Bls = lds + BM * BK;

    int t = threadIdx.x;
    int lane = t & 63, wid = t >> 6;
    int quad = lane >> 4, l15 = lane & 15;
    int wave_m = wid & 1, wave_n = wid >> 1;

    int bid = (int)blockIdx.x;
    int xcd = bid & 7, li = bid >> 3;
    int ppx = (int)(gridDim.x >> 3);        // pairs per XCD (nx=1)
    int pair = xcd * ppx + li;
    int by = pair % NY;
    int bz = pair / NY;

    int bm0 = by * BM;
    int kbeg = bz * (K / 4);                // Kseg = 128
    size_t GK = (size_t)G * K;

    f32x4 acc[4][4] = {};

    for (int k0 = kbeg; k0 < kbeg + K / 4; k0 += BK) {
#pragma unroll
        for (int it = 0; it < 4; it++) {
            int idx = t + it * 256;
            int row = idx >> 3, sc = idx & 7;
            int cW = sc ^ (row & 7);
            gload16(Wb + (size_t)row * K + k0 + cW * 8, Bls + idx * 8);
            int g = bm0 + row; if (g >= G) g = G - 1;
            const float* pb = part6 + (size_t)g * K + k0 + sc * 8;
            float v[8] = {};
#pragma unroll
            for (int z = 0; z < 6; z++) {
                const float* pz = pb + (size_t)z * GK;
                float4 a = *(const float4*)pz;
                float4 b = *(const float4*)(pz + 4);
                v[0] += a.x; v[1] += a.y; v[2] += a.z; v[3] += a.w;
                v[4] += b.x; v[5] += b.y; v[6] += b.z; v[7] += b.w;
            }
            float4 b0 = *(const float4*)&L1b[k0 + sc * 8];
            float4 b1 = *(const float4*)&L1b[k0 + sc * 8 + 4];
            float bb[8] = {b0.x, b0.y, b0.z, b0.w, b1.x, b1.y, b1.z, b1.w};
            u16x8 o;
#pragma unroll
            for (int j = 0; j < 8; j++) {
                float xv = v[j] + bb[j];
                xv = xv > 0.f ? xv : 0.1f * xv;
                o[j] = f2bf(xv);
            }
            *(u16x8*)&Als[row * BK + ((sc ^ (row & 7)) << 3)] = o;
        }
        __syncthreads();                    // drains vmcnt + lgkm

#pragma unroll
        for (int ks = 0; ks < 2; ks++) {
            short8 af[4], bfr[4];
            int ck = ks * 4 + quad;
            int sw = (ck ^ (l15 & 7)) << 3;
#pragma unroll
            for (int mt = 0; mt < 4; mt++)
                af[mt] = *(const short8*)&Als[(wave_m * 64 + mt * 16 + l15) * BK + sw];
#pragma unroll
            for (int nt = 0; nt < 4; nt++)
                bfr[nt] = *(const short8*)&Bls[(wave_n * 64 + nt * 16 + l15) * BK + sw];
#pragma unroll
            for (int mt = 0; mt < 4; mt++)
#pragma unroll
                for (int nt = 0; nt < 4; nt++)
                    acc[mt][nt] = __builtin_amdgcn_mfma_f32_16x16x32_bf16(
                        af[mt], bfr[nt], acc[mt][nt], 0, 0, 0);
        }
        __syncthreads();
    }

    float* Pz = Pout + (size_t)bz * G * M;
#pragma unroll
    for (int mt = 0; mt < 4; mt++) {
        int rbase = bm0 + wave_m * 64 + mt * 16 + quad * 4;
#pragma unroll
        for (int nt = 0; nt < 4; nt++) {
            int col = wave_n * 64 + nt * 16 + l15;
#pragma unroll
            for (int r = 0; r < 4; r++) {
                int row = rbase + r;
                if (row >= G) continue;
                Pz[(size_t)row * M + col] = acc[mt][nt][r];
            }
        }
    }
}

// ---------------- fused conv2+conv3, persistent weights, grid-stride --------
// W2 (64 KB) and W3 (64 KB) staged ONCE per block into resident LDS; a 32 KB
// shared region is time-multiplexed per tile as {A [2][64][64] -> H2 [64][256]
// -> tw}. Each of 256 blocks (1/CU) grid-strides over ~12 tiles of 64 rows,
// staging only 16 KB of A per tile (vs 112 KB of weights before).
__global__ __launch_bounds__(256, 1) void gemm_fused23(
        const bf16_t* __restrict__ A,    // [N,128] (A2)
        const bf16_t* __restrict__ W2,   // [256,128] bf16
        const float*  __restrict__ b2,
        const bf16_t* __restrict__ W3,   // [128,256] bf16
        bf16_t* __restrict__ C,          // [N,128] (may alias A; rows block-private)
        int N, int ntiles) {
    __shared__ __align__(16) unsigned short lds[81920];   // 160 KB
    unsigned short* W2ls = lds;            // [2][256][64]  64 KB resident
    unsigned short* W3ls = lds + 32768;    // [4][128][64]  64 KB resident
    unsigned short* SH   = lds + 65536;    // 32 KB: A / H2 / tw (time-muxed)

    int t = threadIdx.x;
    int lane = t & 63, wid = t >> 6;
    int quad = lane >> 4, l15 = lane & 15;
    int wm = wid & 1, wn = wid >> 1;       // 2x2 wave tiling

    // ---- one-time resident weight staging (drained by first tile barrier) --
#pragma unroll
    for (int it = 0; it < 16; it++) {      // W2: 4096 chunks
        int idx = t + it * 256;
        int h = idx >> 11, r = (idx >> 3) & 255, sc = idx & 7;
        int c = sc ^ (r & 7);
        gload16(W2 + (size_t)r * 128 + h * 64 + c * 8, W2ls + idx * 8);
    }
#pragma unroll
    for (int it = 0; it < 16; it++) {      // W3: 4096 chunks
        int idx = t + it * 256;
        int q = idx >> 10, r = (idx >> 3) & 127, sc = idx & 7;
        int c = sc ^ (r & 7);
        gload16(W3 + (size_t)r * 256 + q * 64 + c * 8, W3ls + idx * 8);
    }

    float bv[8];
#pragma unroll
    for (int nt = 0; nt < 8; nt++) bv[nt] = b2[wn * 128 + nt * 16 + l15];

    for (int tile = blockIdx.x; tile < ntiles; tile += gridDim.x) {
        int bm0 = tile * 64;
        // ---- stage A tile [2][64][64] (16 KB) ----
#pragma unroll
        for (int it = 0; it < 4; it++) {
            int idx = t + it * 256;
            int h = idx >> 9, r = (idx >> 3) & 63, sc = idx & 7;
            int c = sc ^ (r & 7);
            int g = bm0 + r; if (g >= N) g = N - 1;
            gload16(A + (size_t)g * 128 + h * 64 + c * 8, SH + idx * 8);
        }
        __syncthreads();                   // drain A (+ weights, first iter)

        // ---- phase 1: [64,128] x W2^T -> acc1 [64,256] (no staging) ----
        f32x4 acc1[2][8] = {};
#pragma unroll
        for (int h = 0; h < 2; h++) {
#pragma unroll
            for (int ks = 0; ks < 2; ks++) {
                int ck = ks * 4 + quad;
                int sw = (ck ^ (l15 & 7)) << 3;
                short8 af[2];
#pragma unroll
                for (int mt = 0; mt < 2; mt++)
                    af[mt] = *(const short8*)&SH[(h * 64 + wm * 32 + mt * 16 + l15) * 64 + sw];
#pragma unroll
                for (int nt = 0; nt < 8; nt++) {
                    short8 bfr = *(const short8*)&W2ls[(h * 256 + wn * 128 + nt * 16 + l15) * 64 + sw];
#pragma unroll
                    for (int mt = 0; mt < 2; mt++)
                        acc1[mt][nt] = __builtin_amdgcn_mfma_f32_16x16x32_bf16(
                            af[mt], bfr, acc1[mt][nt], 0, 0, 0);
                }
            }
        }
        __syncthreads();                   // all A reads done before H2 writes

        // ---- epilogue: bias + lrelu -> bf16, swizzled into SH as H2[64][256]
#pragma unroll
        for (int mt = 0; mt < 2; mt++) {
#pragma unroll
            for (int nt = 0; nt < 8; nt++) {
                int col = wn * 128 + nt * 16 + l15;
                int chunk = col >> 3, within = col & 7;
#pragma unroll
                for (int r = 0; r < 4; r++) {
                    int row = wm * 32 + mt * 16 + quad * 4 + r;
                    float xv = acc1[mt][nt][r] + bv[nt];
                    xv = xv > 0.f ? xv : 0.1f * xv;
                    SH[row * 256 + ((chunk ^ (row & 7)) << 3) + within] = f2bf(xv);
                }
            }
        }
        __syncthreads();                   // H2 visible

        // ---- phase 2: H2 x W3^T -> acc2 [64,128] (no staging) ----
        f32x4 acc2[2][4] = {};
#pragma unroll
        for (int q = 0; q < 4; q++) {
#pragma unroll
            for (int ks = 0; ks < 2; ks++) {
                int kc = q * 8 + ks * 4 + quad;        // global k-chunk 0..31
                int swa = (kc ^ (l15 & 7)) << 3;
                int swb = ((ks * 4 + quad) ^ (l15 & 7)) << 3;
                short8 af[2], bfr[4];
#pragma unroll
                for (int mt = 0; mt < 2; mt++)
                    af[mt] = *(const short8*)&SH[(wm * 32 + mt * 16 + l15) * 256 + swa];
#pragma unroll
                for (int nt = 0; nt < 4; nt++)
                    bfr[nt] = *(const short8*)&W3ls[(q * 128 + wn * 64 + nt * 16 + l15) * 64 + swb];
#pragma unroll
                for (int mt = 0; mt < 2; mt++)
#pragma unroll
                    for (int nt = 0; nt < 4; nt++)
                        acc2[mt][nt] = __builtin_amdgcn_mfma_f32_16x16x32_bf16(
                            af[mt], bfr[nt], acc2[mt][nt], 0, 0, 0);
            }
        }
        __syncthreads();                   // all H2 reads done before tw writes

        // ---- coalesced store epilogue (tw in SH, per-wave 32x68) ----
        constexpr int TST = 68;
        unsigned short* tw = SH + wid * 32 * TST;   // 8704 shorts <= 16384
#pragma unroll
        for (int mt = 0; mt < 2; mt++) {
#pragma unroll
            for (int nt = 0; nt < 4; nt++) {
                int tcol = nt * 16 + l15;
#pragma unroll
                for (int r = 0; r < 4; r++)
                    tw[(mt * 16 + quad * 4 + r) * TST + tcol] = f2bf(acc2[mt][nt][r]);
            }
        }
        __syncthreads();                   // tw visible
        int lrow0 = lane >> 3, lcol = (lane & 7) * 8;
#pragma unroll
        for (int it = 0; it < 4; it++) {
            int lrow = it * 8 + lrow0;
            int row = bm0 + wm * 32 + lrow;
            if (row < N) {
                u16x8 v = *(const u16x8*)&tw[lrow * TST + lcol];
                *(u16x8*)&C[(size_t)row * 128 + wn * 64 + lcol] = v;
            }
        }
        __syncthreads();                   // tw reads done before next A stage
    }
}

// ---------------- fused aggregation, sub-wave-per-node, 4-edge pipeline ------

template <int F, bool BACT>
__global__ __launch_bounds__(256) void k_agg(
        const bf16_t* __restrict__ H, const int* __restrict__ rowptr,
        const int* __restrict__ csr, const float* __restrict__ dis,
        const float* __restrict__ bias, bf16_t* __restrict__ out, int N) {
    constexpr int SUB = F / 8;          // lanes per node
    constexpr int NPW = 64 / SUB;       // nodes per wave
    constexpr int SH  = (SUB == 16) ? 4 : 3;
    int gtid = blockIdx.x * 256 + threadIdx.x;
    int wave = gtid >> 6, lane = gtid & 63;
    int sub = lane >> SH, sl = lane & (SUB - 1);
    int node = wave * NPW + sub;
    if (node >= N) return;
    float di = dis[node];
    int s = rowptr[node], e = rowptr[node + 1];

    auto load_row = [&](const bf16_t* p, float (&r)[8]) {
        u16x8 v = *(const u16x8*)p;
#pragma unroll
        for (int f = 0; f < 8; f++) r[f] = bf2f(v[f]);
    };

    float acc[8], acc2[8];
    {
        float r[8];
        load_row(H + (size_t)node * F + sl * 8, r);
        float sln = di * di;   // self-loop norm = 1/deg
#pragma unroll
        for (int f = 0; f < 8; f++) { acc[f] = r[f] * sln; acc2[f] = 0.f; }
    }
    int p = s;
    for (; p + 4 <= e; p += 4) {
        int s0 = csr[p], s1 = csr[p + 1], s2 = csr[p + 2], s3 = csr[p + 3];
        float n0 = dis[s0] * di, n1 = dis[s1] * di;
        float n2 = dis[s2] * di, n3 = dis[s3] * di;
        float r0[8], r1[8], r2[8], r3[8];
        load_row(H + (size_t)s0 * F + sl * 8, r0);
        load_row(H + (size_t)s1 * F + sl * 8, r1);
        load_row(H + (size_t)s2 * F + sl * 8, r2);
        load_row(H + (size_t)s3 * F + sl * 8, r3);
#pragma unroll
        for (int f = 0; f < 8; f++) {
            acc[f]  += r0[f] * n0; acc2[f] += r1[f] * n1;
            acc[f]  += r2[f] * n2; acc2[f] += r3[f] * n3;
        }
    }
    if (p + 2 <= e) {
        int s0 = csr[p], s1 = csr[p + 1];
        float n0 = dis[s0] * di, n1 = dis[s1] * di;
        float r0[8], r1[8];
        load_row(H + (size_t)s0 * F + sl * 8, r0);
        load_row(H + (size_t)s1 * F + sl * 8, r1);
#pragma unroll
        for (int f = 0; f < 8; f++) { acc[f] += r0[f] * n0; acc2[f] += r1[f] * n1; }
        p += 2;
    }
    if (p < e) {
        int s0 = csr[p];
        float n0 = dis[s0] * di;
        float r0[8];
        load_row(H + (size_t)s0 * F + sl * 8, r0);
#pragma unroll
        for (int f = 0; f < 8; f++) acc[f] += r0[f] * n0;
    }

    float o[8];
#pragma unroll
    for (int f = 0; f < 8; f++) {
        float v = acc[f] + acc2[f];
        if (BACT) {
            v += bias[sl * 8 + f];
            v = v > 0.f ? v : 0.1f * v;
        }
        o[f] = v;
    }
    u16x8 w = {f2bf(o[0]), f2bf(o[1]), f2bf(o[2]), f2bf(o[3]),
               f2bf(o[4]), f2bf(o[5]), f2bf(o[6]), f2bf(o[7])};
    *(u16x8*)(out + (size_t)node * F + sl * 8) = w;
}

// ---------------- fused MLP2-reduce + bias + lrelu + head ------------------

__global__ __launch_bounds__(256) void k_head2(
        const float* __restrict__ part, const float* __restrict__ L2b,
        const float* __restrict__ L3w, const float* __restrict__ L3b,
        float* __restrict__ out, int G) {
    int wv = (int)((blockIdx.x * blockDim.x + threadIdx.x) >> 6);
    int lane = threadIdx.x & 63;
    if (wv >= G) return;
    size_t base = (size_t)wv * 128 + lane * 2;
    size_t GM = (size_t)G * 128;
    float2 s = *(const float2*)&part[base];
#pragma unroll
    for (int z = 1; z < 4; z++) {
        float2 p = *(const float2*)&part[z * GM + base];
        s.x += p.x; s.y += p.y;
    }
    float2 b = *(const float2*)&L2b[lane * 2];
    float vx = s.x + b.x, vy = s.y + b.y;
    vx = vx > 0.f ? vx : 0.1f * vx;
    vy = vy > 0.f ? vy : 0.1f * vy;
    float2 wl = *(const float2*)&L3w[lane * 2];
    float d = vx * wl.x + vy * wl.y;
    for (int off = 32; off > 0; off >>= 1) d += __shfl_xor(d, off, 64);
    if (lane == 0) out[wv] = 1.f / (1.f + expf(-(d + L3b[0])));
}

// ---------------- launch ----------------

extern "C" void kernel_launch(void* const* d_in, const int* in_sizes, int n_in,
                              void* d_out, int out_size, void* d_ws, size_t ws_size,
                              hipStream_t stream) {
    const float* x   = (const float*)d_in[0];
    const int*   ei  = (const int*)d_in[1];
    const float* W1  = (const float*)d_in[2];  const float* b1  = (const float*)d_in[3];
    const float* W2  = (const float*)d_in[4];  const float* b2  = (const float*)d_in[5];
    const float* W3  = (const float*)d_in[6];  const float* b3  = (const float*)d_in[7];
    const float* L1w = (const float*)d_in[8];  const float* L1b = (const float*)d_in[9];
    const float* L2w = (const float*)d_in[10]; const float* L2b = (const float*)d_in[11];
    const float* L3w = (const float*)d_in[12]; const float* L3b = (const float*)d_in[13];
    float* out = (float*)d_out;

    const int C = 40;
    const int N = in_sizes[0] / C;     // 200000
    const int E = in_sizes[1] / 2;     // 1000000
    const int G = N / 40;              // 5000
    const int H1d = 128, H2d = 256, H3d = 128, M1 = 512, M2 = 128;
    const int K1 = 40 * H3d;           // 5120

    // ---- workspace layout ----
    char* wsb = (char*)d_ws;
    size_t off = 0;
    auto alloc = [&](size_t bytes) -> void* {
        void* p = wsb + off;
        off += (bytes + 255) & ~(size_t)255;
        return p;
    };
    int*    cnt8   = (int*)alloc(4 * 8 * (size_t)N);
    int*    rowptr = (int*)alloc(4 * (size_t)(N + 1));
    int*    cur    = (int*)alloc(4 * (size_t)N);
    int*    csr    = (int*)alloc(4 * (size_t)E);
    int*    bsum   = (int*)alloc(4 * 512);
    float*  dis    = (float*)alloc(4 * (size_t)N);
    bf16_t* Hb     = (bf16_t*)alloc(2 * (size_t)N * H2d);   // ping (102.4 MB)
    bf16_t* Xb     = (bf16_t*)alloc(2 * (size_t)N * H2d);   // pong (102.4 MB)
    bf16_t* W1b    = (bf16_t*)alloc(2 * (size_t)H1d * 64);
    bf16_t* W2b    = (bf16_t*)alloc(2 * (size_t)H2d * H1d);
    bf16_t* W3b    = (bf16_t*)alloc(2 * (size_t)H3d * H2d);
    bf16_t* L1wb   = (bf16_t*)alloc(2 * (size_t)M1 * K1);
    bf16_t* L2wb   = (bf16_t*)alloc(2 * (size_t)M2 * M1);
    if (off > ws_size) return;   // fail cleanly instead of faulting

    // aliasing (all within dead regions at time of use):
    int* src32 = (int*)Xb;        // packed edges during CSR build (Xb dead)
    int* dst32 = src32 + E;
    bf16_t* xb   = Hb;            // [N,64]  pad(x)          — dead after agg1
    bf16_t* A1b  = Xb;            // [N,64]  agg(x)          — overwrites src32/dst32
    bf16_t* H1   = Hb;            // [N,128] lrelu(A1 W1+b1) — overwrites xb
    bf16_t* A2   = Xb;            // [N,128] agg(H1)         — overwrites A1b
    bf16_t* H3p  = Xb;            // [N,128] fused conv2+3 out — IN-PLACE over A2
    bf16_t* X3   = Hb;            // [N,128] lrelu(agg(H3p)+b3) — overwrites H1
    float*  part = (float*)Xb;    // MLP1 split-K partials [6][G*512] (61.4 MB)
    float*  part2 = part + 6 * (size_t)G * M1;   // MLP2 partials [4][G*128]

    // ---- weight pre-convert + x pad + cnt8 zero-fill (one dispatch) ----
    WcSeg s0 = {W1,  W1b,  H1d, 40,  64,  H1d * 64 / 8};
    WcSeg s1 = {W2,  W2b,  H2d, H1d, H1d, H2d * H1d / 8};
    WcSeg s2 = {W3,  W3b,  H3d, H2d, H2d, H3d * H2d / 8};
    WcSeg s3 = {L1w, L1wb, M1,  K1,  K1,  M1 * K1 / 8};
    WcSeg s4 = {L2w, L2wb, M2,  M1,  M1,  M2 * M1 / 8};
    WcSeg s5 = {x,   xb,   N,   40,  64,  N * 64 / 8};
    int wtotal = s0.nchunk + s1.nchunk + s2.nchunk + s3.nchunk + s4.nchunk + s5.nchunk;
    int ztotal = wtotal + 2 * N;       // 2N int4-chunks zero 8N ints of cnt8
    k_wconv<<<CDIV(ztotal, 256), 256, 0, stream>>>(s0, s1, s2, s3, s4, s5,
                                                   wtotal, cnt8, ztotal);

    // ---- CSR by dst (pack+hist+detect fused, XCD-range-filtered fill) ----
    k_packhist<<<CDIV(E, 256), 256, 0, stream>>>(ei, E, src32, dst32, cnt8, N);
    int nb = CDIV(N + 1, 1024);        // 196 <= 256
    k_blockred<<<nb, 256, 0, stream>>>(cnt8, bsum, N);
    k_scanwrite<<<nb, 256, 0, stream>>>(cnt8, bsum, rowptr, cur, dis, N, nb);
    int NR = CDIV(N, 8);               // nodes per XCD range
    k_fill_r<<<8 * CDIV(E, FILL_EPB), 256, 0, stream>>>(src32, dst32, E, cur, csr, N, NR);

    const int NB = CDIV(N, 128);       // 1563
    const int GB = CDIV(G, 128);       // 40

    // ---- conv1 (aggregate-first in 40->64-dim) ----
    k_agg<64, false><<<CDIV(N, 32), 256, 0, stream>>>(xb, rowptr, csr, dis, nullptr, A1b, N);
    gemm_mfma<true, true, 1, false><<<dim3(1, NB), 256, 0, stream>>>(A1b, W1b, b1, H1, N, 64, H1d, 0, 0, 0);
    // ---- conv2 + conv3-transform fused (persistent weights, 1 block/CU) ----
    k_agg<128, false><<<CDIV(N, 16), 256, 0, stream>>>(H1, rowptr, csr, dis, nullptr, A2, N);
    gemm_fused23<<<256, 256, 0, stream>>>(A2, W2b, b2, W3b, H3p, N, CDIV(N, 64));
    k_agg<128, true><<<CDIV(N, 16), 256, 0, stream>>>(H3p, rowptr, csr, dis, b3, X3, N);

    // ---- readout MLP1: split-K S=6, XCD-grouped 1D grid (960 blocks) ----
    gemm_mfma<false, false, 0, true><<<960, 256, 0, stream>>>(X3, L1wb, nullptr, part, G, K1, M1, 896, 4, 40);
    // ---- readout MLP2: k_red fused into A-staging; S=4, 160 blocks ----
    gemm_mlp2<<<160, 256, 0, stream>>>(part, L1b, L2wb, part2, G);
    k_head2<<<CDIV(G, 4), 256, 0, stream>>>(part2, L2b, L3w, L3b, out, G);
}

// Round 9
// 471.946 us; speedup vs baseline: 1.0405x; 1.0405x over previous
//
#include <hip/hip_runtime.h>
#include <cmath>

#define CDIV(a,b) (((a)+(b)-1)/(b))

typedef unsigned short bf16_t;
using short8 = __attribute__((ext_vector_type(8))) short;
using f32x4  = __attribute__((ext_vector_type(4))) float;
using u16x4  = __attribute__((ext_vector_type(4))) unsigned short;
using u16x8  = __attribute__((ext_vector_type(8))) unsigned short;

__device__ __forceinline__ float bf2f(unsigned short b) {
    unsigned u = ((unsigned)b) << 16;
    float f;
    __builtin_memcpy(&f, &u, 4);
    return f;
}
__device__ __forceinline__ unsigned short f2bf(float f) {
    unsigned u;
    __builtin_memcpy(&u, &f, 4);
    u = (u + 0x7FFFu + ((u >> 16) & 1u)) >> 16;
    return (unsigned short)u;
}

// async global->LDS, 16B per lane. LDS dest must be linear in lane order
// (wave-uniform base + lane*16); swizzle is folded into the GLOBAL address.
__device__ __forceinline__ void gload16(const bf16_t* g, unsigned short* l) {
    __builtin_amdgcn_global_load_lds(
        (const __attribute__((address_space(1))) void*)(g),
        (__attribute__((address_space(3))) void*)(l), 16, 0, 0);
}

__device__ __forceinline__ int edge_src(const int* ei, int E, int f, int i) {
    return f ? ei[2 * (size_t)i] : ei[i];
}
__device__ __forceinline__ int edge_dst(const int* ei, int E, int f, int i) {
    return f ? ei[2 * ((size_t)E + (size_t)i)] : ei[(size_t)E + (size_t)i];
}

// ---- pack edges to int32 + 8x-privatized dst histogram (detect inlined) ----
__global__ __launch_bounds__(256) void k_packhist(const int* __restrict__ ei, int E,
                                                  int* __restrict__ src32,
                                                  int* __restrict__ dst32,
                                                  int* __restrict__ cnt8, int N) {
    __shared__ int sflag;
    int t = threadIdx.x;
    if (t < 64) {   // whole wave 0: detect int64 layout from first 64 edges
        unsigned v = (unsigned)ei[2 * t + 1];
        unsigned long long m = __ballot(v != 0u);
        if (t == 0) sflag = (m == 0ULL) ? 1 : 0;
    }
    __syncthreads();
    int i = blockIdx.x * 256 + t;
    if (i >= E) return;
    int f = sflag;
    int s = edge_src(ei, E, f, i);
    int d = edge_dst(ei, E, f, i);
    src32[i] = s;
    dst32[i] = d;
    if ((unsigned)d < (unsigned)N)
        atomicAdd(&cnt8[(blockIdx.x & 7) * N + d], 1);
}

__global__ void k_blockred(const int* __restrict__ cnt8, int* __restrict__ bsum, int N) {
    __shared__ int sd[256];
    int b = blockIdx.x, t = threadIdx.x;
    int base = b * 1024 + t * 4;
    int s = 0;
#pragma unroll
    for (int i = 0; i < 4; i++) {
        int idx = base + i;
        if (idx < N)
#pragma unroll
            for (int r = 0; r < 8; r++) s += cnt8[r * N + idx];
    }
    sd[t] = s; __syncthreads();
    for (int off = 128; off > 0; off >>= 1) { if (t < off) sd[t] += sd[t + off]; __syncthreads(); }
    if (t == 0) bsum[b] = sd[0];
}

// scanwrite with the bsum scan inlined
__global__ void k_scanwrite(const int* __restrict__ cnt8, const int* __restrict__ bsum,
                            int* __restrict__ rowptr, int* __restrict__ cur,
                            float* __restrict__ dis, int N, int nb) {
    __shared__ int sb[256];
    __shared__ int sd[256];
    int b = blockIdx.x, t = threadIdx.x;
    int v0 = (t < nb) ? bsum[t] : 0;
    sb[t] = v0; __syncthreads();
    for (int off = 1; off < 256; off <<= 1) {
        int y = (t >= off) ? sb[t - off] : 0;
        __syncthreads();
        sb[t] += y;
        __syncthreads();
    }
    int block_pre = (b == 0) ? 0 : sb[b - 1];

    int base = b * 1024 + t * 4;
    int tot[4]; int s = 0;
#pragma unroll
    for (int i = 0; i < 4; i++) {
        int idx = base + i;
        tot[i] = 0;
        if (idx < N) {
#pragma unroll
            for (int r = 0; r < 8; r++) tot[i] += cnt8[r * N + idx];
        }
        s += tot[i];
    }
    sd[t] = s; __syncthreads();
    for (int off = 1; off < 256; off <<= 1) {
        int y = (t >= off) ? sd[t - off] : 0;
        __syncthreads();
        sd[t] += y;
        __syncthreads();
    }
    int pre = block_pre + sd[t] - s;
#pragma unroll
    for (int i = 0; i < 4; i++) {
        int idx = base + i;
        if (idx < N) {
            rowptr[idx] = pre;
            cur[idx] = pre;
            dis[idx] = rsqrtf((float)tot[i] + 1.0f);
            pre += tot[i];
        } else if (idx == N) {
            rowptr[N] = pre;
        }
    }
}

// Range-filtered fill (XCD write locality)
#define FILL_EPB 4096
__global__ __launch_bounds__(256) void k_fill_r(
        const int* __restrict__ src32, const int* __restrict__ dst32, int E,
        int* __restrict__ cur, int* __restrict__ csr, int N, int NR) {
    int r = blockIdx.x & 7;
    int chunk = blockIdx.x >> 3;
    int lo = r * NR;
    int hi = min(lo + NR, N);
    int base = chunk * FILL_EPB;
    int end = min(base + FILL_EPB, E);
    for (int i = base + threadIdx.x; i < end; i += 256) {
        int d = dst32[i];
        if (d >= lo && d < hi) {
            int s = src32[i];
            if ((unsigned)s < (unsigned)N) {
                int p = atomicAdd(&cur[d], 1);
                csr[p] = s;
            }
        }
    }
}

// ---------------- weight pre-convert + x pad + cnt8 zero-fill ---------------

struct WcSeg { const float* src; bf16_t* dst; int M, KW, KP, nchunk; };

__global__ __launch_bounds__(256) void k_wconv(WcSeg s0, WcSeg s1, WcSeg s2,
                                               WcSeg s3, WcSeg s4, WcSeg s5,
                                               int wtotal, int* __restrict__ zdst,
                                               int total) {
    int i = blockIdx.x * 256 + threadIdx.x;
    if (i >= total) return;
    if (i >= wtotal) {   // zero-fill tail: 16 B of cnt8 per thread
        int4 z = {0, 0, 0, 0};
        *(int4*)(zdst + (size_t)(i - wtotal) * 4) = z;
        return;
    }
    WcSeg s;
    if (i < s0.nchunk) s = s0;
    else if ((i -= s0.nchunk) < s1.nchunk) s = s1;
    else if ((i -= s1.nchunk) < s2.nchunk) s = s2;
    else if ((i -= s2.nchunk) < s3.nchunk) s = s3;
    else if ((i -= s3.nchunk) < s4.nchunk) s = s4;
    else { i -= s4.nchunk; s = s5; }
    int cpr = s.KP >> 3;                // chunks per row
    int row = i / cpr, kk = (i % cpr) << 3;
    short8 v = {};
    if (kk < s.KW) {
        const float4* p = (const float4*)(s.src + (size_t)row * s.KW + kk);
        float4 a = p[0], b = p[1];
        v[0] = (short)f2bf(a.x); v[1] = (short)f2bf(a.y);
        v[2] = (short)f2bf(a.z); v[3] = (short)f2bf(a.w);
        v[4] = (short)f2bf(b.x); v[5] = (short)f2bf(b.y);
        v[6] = (short)f2bf(b.z); v[7] = (short)f2bf(b.w);
    }
    *(short8*)(s.dst + (size_t)row * s.KP + kk) = v;
}

// ---------------- MFMA GEMM: C[i][j] = sum_k A[i][k] * Wb[j][k] --------------
// SCALE: multiply the (activated) output row by rowscale[row] in the CBF
// epilogue — used to pre-scale H1 by deg_inv_sqrt for the PRE aggregation.

template <bool CBF, bool BIAS, int ACT, bool SPLIT, bool SCALE>
__global__ __launch_bounds__(256) void gemm_mfma(
        const bf16_t* __restrict__ A, const bf16_t* __restrict__ Wb,
        const float* __restrict__ bias, void* __restrict__ Cv,
        int N, int K, int M, int Kseg, int nx, int ny,
        const float* __restrict__ rowscale) {
    constexpr int BM = 128, BK = 64;
    __shared__ __align__(16) unsigned short lds[4 * 64 * 68];
    unsigned short* Als = lds;
    unsigned short* Bls = lds + BM * BK;

    int t = threadIdx.x;
    int lane = t & 63, wid = t >> 6;
    int quad = lane >> 4, l15 = lane & 15;
    int wave_m = wid & 1, wave_n = wid >> 1;

    int bx, by, bz;
    if (SPLIT) {
        int bid = (int)blockIdx.x;
        int xcd = bid & 7, li = bid >> 3;
        bx = li % nx;
        int pl = li / nx;
        int ppx = (int)(gridDim.x >> 3) / nx;   // pairs per XCD
        int pair = xcd * ppx + pl;
        by = pair % ny;
        bz = pair / ny;
    } else {
        bx = blockIdx.x; by = blockIdx.y; bz = 0;
    }

    int bm0 = by * BM;     // node tile
    int bn0 = bx * BM;     // M tile
    int kbeg = SPLIT ? bz * Kseg : 0;
    int kend = SPLIT ? min(kbeg + Kseg, K) : K;

    f32x4 acc[4][4] = {};

    for (int k0 = kbeg; k0 < kend; k0 += BK) {
#pragma unroll
        for (int it = 0; it < 4; it++) {
            int idx = t + it * 256;
            int row = idx >> 3, sc = idx & 7;
            int c = sc ^ (row & 7);            // pre-swizzled source chunk
            int ga = bm0 + row; if (ga >= N) ga = N - 1;   // clamp (masked at store)
            gload16(A + (size_t)ga * K + k0 + c * 8, Als + idx * 8);
            gload16(Wb + (size_t)(bn0 + row) * K + k0 + c * 8, Bls + idx * 8);
        }
        __syncthreads();                        // drains vmcnt

#pragma unroll
        for (int ks = 0; ks < 2; ks++) {
            short8 af[4], bfr[4];
            int ck = ks * 4 + quad;
            int sw = (ck ^ (l15 & 7)) << 3;
#pragma unroll
            for (int mt = 0; mt < 4; mt++)
                af[mt] = *(const short8*)&Als[(wave_m * 64 + mt * 16 + l15) * BK + sw];
#pragma unroll
            for (int nt = 0; nt < 4; nt++)
                bfr[nt] = *(const short8*)&Bls[(wave_n * 64 + nt * 16 + l15) * BK + sw];
#pragma unroll
            for (int mt = 0; mt < 4; mt++)
#pragma unroll
                for (int nt = 0; nt < 4; nt++)
                    acc[mt][nt] = __builtin_amdgcn_mfma_f32_16x16x32_bf16(
                        af[mt], bfr[nt], acc[mt][nt], 0, 0, 0);
        }
        __syncthreads();
    }

    if (!SPLIT && CBF) {
        constexpr int TST = 68;
        unsigned short* tw = lds + wid * 64 * TST;
#pragma unroll
        for (int mt = 0; mt < 4; mt++) {
#pragma unroll
            for (int nt = 0; nt < 4; nt++) {
                int tcol = nt * 16 + l15;
                float bv = BIAS ? bias[bn0 + wave_n * 64 + tcol] : 0.f;
#pragma unroll
                for (int r = 0; r < 4; r++) {
                    float x = acc[mt][nt][r];
                    if (BIAS) x += bv;
                    if (ACT == 1) x = x > 0.f ? x : 0.1f * x;
                    if (SCALE) {
                        int row = bm0 + wave_m * 64 + mt * 16 + quad * 4 + r;
                        x *= rowscale[row < N ? row : N - 1];
                    }
                    tw[(mt * 16 + quad * 4 + r) * TST + tcol] = f2bf(x);
                }
            }
        }
        __syncthreads();
        bf16_t* C = (bf16_t*)Cv;
        int lrow0 = lane >> 3, lcol = (lane & 7) * 8;
#pragma unroll
        for (int it = 0; it < 8; it++) {
            int lrow = it * 8 + lrow0;
            int row = bm0 + wave_m * 64 + lrow;
            if (row < N) {
                u16x8 v = *(const u16x8*)&tw[lrow * TST + lcol];
                *(u16x8*)&C[(size_t)row * M + bn0 + wave_n * 64 + lcol] = v;
            }
        }
    } else {
        float* Pz = SPLIT ? ((float*)Cv + (size_t)bz * N * M) : (float*)Cv;
#pragma unroll
        for (int mt = 0; mt < 4; mt++) {
            int rbase = bm0 + wave_m * 64 + mt * 16 + quad * 4;
#pragma unroll
            for (int nt = 0; nt < 4; nt++) {
                int col = bn0 + wave_n * 64 + nt * 16 + l15;
                float bv = (BIAS && !SPLIT) ? bias[col] : 0.f;
#pragma unroll
                for (int r = 0; r < 4; r++) {
                    int row = rbase + r;
                    if (row >= N) continue;
                    float x = acc[mt][nt][r];
                    if (!SPLIT) {
                        if (BIAS) x += bv;
                        if (ACT == 1) x = x > 0.f ? x : 0.1f * x;
                    }
                    Pz[(size_t)row * M + col] = x;
                }
            }
        }
    }
}

// ---------------- MLP2 GEMM with fused MLP1-reduce in A-staging -------------
__global__ __launch_bounds__(256) void gemm_mlp2(
        const float* __restrict__ part6,   // [6][G*512] fp32
        const float* __restrict__ L1b,     // [512]
        const bf16_t* __restrict__ Wb,     // L2wb [128,512] bf16
        float* __restrict__ Pout,          // [4][G*128] fp32
        int G) {
    constexpr int BM = 128, BK = 64, K = 512, M = 128, NY = 40;
    __shared__ __align__(16) unsigned short lds[2 * BM * BK];   // 32 KB
    unsigned short* Als = lds;
    unsigned short* Bls = lds + BM * BK;

    int t = threadIdx.x;
    int lane = t & 63, wid = t >> 6;
    int quad = lane >> 4, l15 = lane & 15;
    int wave_m = wid & 1, wave_n = wid >> 1;

    int bid = (int)blockIdx.x;
    int xcd = bid & 7, li = bid >> 3;
    int ppx = (int)(gridDim.x >> 3);        // pairs per XCD (nx=1)
    int pair = xcd * ppx + li;
    int by = pair % NY;
    int bz = pair / NY;

    int bm0 = by * BM;
    int kbeg = bz * (K / 4);                // Kseg = 128
    size_t GK = (size_t)G * K;

    f32x4 acc[4][4] = {};

    for (int k0 = kbeg; k0 < kbeg + K / 4; k0 += BK) {
#pragma unroll
        for (int it = 0; it < 4; it++) {
            int idx = t + it * 256;
            int row = idx >> 3, sc = idx & 7;
            int cW = sc ^ (row & 7);
            gload16(Wb + (size_t)row * K + k0 + cW * 8, Bls + idx * 8);
            int g = bm0 + row; if (g >= G) g = G - 1;
            const float* pb = part6 + (size_t)g * K + k0 + sc * 8;
            float v[8] = {};
#pragma unroll
            for (int z = 0; z < 6; z++) {
                const float* pz = pb + (size_t)z * GK;
                float4 a = *(const float4*)pz;
                float4 b = *(const float4*)(pz + 4);
                v[0] += a.x; v[1] += a.y; v[2] += a.z; v[3] += a.w;
                v[4] += b.x; v[5] += b.y; v[6] += b.z; v[7] += b.w;
            }
            float4 b0 = *(const float4*)&L1b[k0 + sc * 8];
            float4 b1 = *(const float4*)&L1b[k0 + sc * 8 + 4];
            float bb[8] = {b0.x, b0.y, b0.z, b0.w, b1.x, b1.y, b1.z, b1.w};
            u16x8 o;
#pragma unroll
            for (int j = 0; j < 8; j++) {
                float xv = v[j] + bb[j];
                xv = xv > 0.f ? xv : 0.1f * xv;
                o[j] = f2bf(xv);
            }
            *(u16x8*)&Als[row * BK + ((sc ^ (row & 7)) << 3)] = o;
        }
        __syncthreads();                    // drains vmcnt + lgkm

#pragma unroll
        for (int ks = 0; ks < 2; ks++) {
            short8 af[4], bfr[4];
            int ck = ks * 4 + quad;
            int sw = (ck ^ (l15 & 7)) << 3;
#pragma unroll
            for (int mt = 0; mt < 4; mt++)
                af[mt] = *(const short8*)&Als[(wave_m * 64 + mt * 16 + l15) * BK + sw];
#pragma unroll
            for (int nt = 0; nt < 4; nt++)
                bfr[nt] = *(const short8*)&Bls[(wave_n * 64 + nt * 16 + l15) * BK + sw];
#pragma unroll
            for (int mt = 0; mt < 4; mt++)
#pragma unroll
                for (int nt = 0; nt < 4; nt++)
                    acc[mt][nt] = __builtin_amdgcn_mfma_f32_16x16x32_bf16(
                        af[mt], bfr[nt], acc[mt][nt], 0, 0, 0);
        }
        __syncthreads();
    }

    float* Pz = Pout + (size_t)bz * G * M;
#pragma unroll
    for (int mt = 0; mt < 4; mt++) {
        int rbase = bm0 + wave_m * 64 + mt * 16 + quad * 4;
#pragma unroll
        for (int nt = 0; nt < 4; nt++) {
            int col = wave_n * 64 + nt * 16 + l15;
#pragma unroll
            for (int r = 0; r < 4; r++) {
                int row = rbase + r;
                if (row >= G) continue;
                Pz[(size_t)row * M + col] = acc[mt][nt][r];
            }
        }
    }
}

// ---------------- fused conv2-GEMM + lrelu + conv3-GEMM (BM=64, 48 KB) ------
// REVERTED to the round-5 structure (57.5 µs measured; the persistent-weight
// 160 KB variant regressed to 66.6 µs at 1 block/CU). Output is pre-scaled by
// dis[row] so the following aggregation runs in PRE (add-only) form.
__global__ __launch_bounds__(256, 3) void gemm_fused23(
        const bf16_t* __restrict__ A,    // [N,128] (A2)
        const bf16_t* __restrict__ W2,   // [256,128] bf16
        const float*  __restrict__ b2,
        const bf16_t* __restrict__ W3,   // [128,256] bf16
        const float*  __restrict__ dis,  // [N] deg_inv_sqrt (output pre-scale)
        bf16_t* __restrict__ C,          // [N,128] (may alias A; rows block-private)
        int N) {
    __shared__ __align__(16) unsigned short lds[24576];   // 48 KB
    unsigned short* Als  = lds;            // [64][64]   8 KB  phase-1 A tile
    unsigned short* Bls  = lds + 4096;     // [256][64] 32 KB  phase-1 W2 tile
    unsigned short* H2ls = lds;            // [64][256] 32 KB  (aliases Als+Bls head)
    unsigned short* B2ls = lds + 16384;    // [128][64] 16 KB  phase-2 W3 tile

    int t = threadIdx.x;
    int lane = t & 63, wid = t >> 6;
    int quad = lane >> 4, l15 = lane & 15;
    int wm = wid & 1, wn = wid >> 1;       // 2x2 wave tiling (both phases)
    int bm0 = blockIdx.x * 64;

    float bv[8];
#pragma unroll
    for (int nt = 0; nt < 8; nt++) bv[nt] = b2[wn * 128 + nt * 16 + l15];

    // ---- phase 1: C1 = A_tile * W2^T  -> [64,256], wave owns 32x128 ----
    f32x4 acc1[2][8] = {};
    for (int k0 = 0; k0 < 128; k0 += 64) {
#pragma unroll
        for (int it = 0; it < 2; it++) {           // A: 512 16B-chunks
            int idx = t + it * 256;
            int row = idx >> 3, sc = idx & 7;
            int c = sc ^ (row & 7);                // pre-swizzled source chunk
            int g = bm0 + row; if (g >= N) g = N - 1;   // clamp: masked at store
            gload16(A + (size_t)g * 128 + k0 + c * 8, Als + idx * 8);
        }
#pragma unroll
        for (int it = 0; it < 8; it++) {           // W2: 2048 chunks
            int idx = t + it * 256;
            int row = idx >> 3, sc = idx & 7;
            int c = sc ^ (row & 7);
            gload16(W2 + (size_t)row * 128 + k0 + c * 8, Bls + idx * 8);
        }
        __syncthreads();                            // drains vmcnt
#pragma unroll
        for (int ks = 0; ks < 2; ks++) {
            int ck = ks * 4 + quad;
            int sw = (ck ^ (l15 & 7)) << 3;
            short8 af[2];
#pragma unroll
            for (int mt = 0; mt < 2; mt++)
                af[mt] = *(const short8*)&Als[(wm * 32 + mt * 16 + l15) * 64 + sw];
#pragma unroll
            for (int nt = 0; nt < 8; nt++) {
                short8 bfr = *(const short8*)&Bls[(wn * 128 + nt * 16 + l15) * 64 + sw];
#pragma unroll
                for (int mt = 0; mt < 2; mt++)
                    acc1[mt][nt] = __builtin_amdgcn_mfma_f32_16x16x32_bf16(
                        af[mt], bfr, acc1[mt][nt], 0, 0, 0);
            }
        }
        __syncthreads();
    }

    // ---- prefetch W3 k0=0 into B2ls (disjoint from H2ls) while epilogue runs
#pragma unroll
    for (int it = 0; it < 4; it++) {               // W3: 1024 chunks
        int idx = t + it * 256;
        int row = idx >> 3, sc = idx & 7;
        int c = sc ^ (row & 7);
        gload16(W3 + (size_t)row * 256 + c * 8, B2ls + idx * 8);
    }

    // ---- phase-1 epilogue: bias + lrelu -> bf16, swizzled into H2ls ----
#pragma unroll
    for (int mt = 0; mt < 2; mt++) {
#pragma unroll
        for (int nt = 0; nt < 8; nt++) {
            int col = wn * 128 + nt * 16 + l15;
            int chunk = col >> 3, within = col & 7;
#pragma unroll
            for (int r = 0; r < 4; r++) {
                int row = wm * 32 + mt * 16 + quad * 4 + r;
                float xv = acc1[mt][nt][r] + bv[nt];
                xv = xv > 0.f ? xv : 0.1f * xv;
                H2ls[row * 256 + ((chunk ^ (row & 7)) << 3) + within] = f2bf(xv);
            }
        }
    }
    __syncthreads();   // drains W3 prefetch (vmcnt) + H2 ds_writes (lgkm)

    // ---- phase 2: C2 = H2ls * W3^T -> [64,128], wave owns 32x64 ----
    f32x4 acc2[2][4] = {};
    for (int k0 = 0; k0 < 256; k0 += 64) {
        if (k0 > 0) {
#pragma unroll
            for (int it = 0; it < 4; it++) {       // W3 tile: 1024 chunks
                int idx = t + it * 256;
                int row = idx >> 3, sc = idx & 7;
                int c = sc ^ (row & 7);
                gload16(W3 + (size_t)row * 256 + k0 + c * 8, B2ls + idx * 8);
            }
            __syncthreads();
        }
#pragma unroll
        for (int ks = 0; ks < 2; ks++) {
            int kc = (k0 >> 3) + ks * 4 + quad;
            int swa = (kc ^ (l15 & 7)) << 3;
            int swb = ((ks * 4 + quad) ^ (l15 & 7)) << 3;
            short8 af[2], bfr[4];
#pragma unroll
            for (int mt = 0; mt < 2; mt++)
                af[mt] = *(const short8*)&H2ls[(wm * 32 + mt * 16 + l15) * 256 + swa];
#pragma unroll
            for (int nt = 0; nt < 4; nt++)
                bfr[nt] = *(const short8*)&B2ls[(wn * 64 + nt * 16 + l15) * 64 + swb];
#pragma unroll
            for (int mt = 0; mt < 2; mt++)
#pragma unroll
                for (int nt = 0; nt < 4; nt++)
                    acc2[mt][nt] = __builtin_amdgcn_mfma_f32_16x16x32_bf16(
                        af[mt], bfr[nt], acc2[mt][nt], 0, 0, 0);
        }
        __syncthreads();
    }

    // ---- coalesced store epilogue (per-wave 32x64 via LDS), pre-scaled -----
    constexpr int TST = 68;
    unsigned short* tw = lds + wid * 32 * TST;     // 8704 shorts total, safe
#pragma unroll
    for (int mt = 0; mt < 2; mt++) {
#pragma unroll
        for (int r = 0; r < 4; r++) {
            int row = bm0 + wm * 32 + mt * 16 + quad * 4 + r;
            float ds = dis[row < N ? row : N - 1];
#pragma unroll
            for (int nt = 0; nt < 4; nt++) {
                int tcol = nt * 16 + l15;
                tw[(mt * 16 + quad * 4 + r) * TST + tcol] = f2bf(acc2[mt][nt][r] * ds);
            }
        }
    }
    __syncthreads();
    int lrow0 = lane >> 3, lcol = (lane & 7) * 8;
#pragma unroll
    for (int it = 0; it < 4; it++) {
        int lrow = it * 8 + lrow0;
        int row = bm0 + wm * 32 + lrow;
        if (row < N) {
            u16x8 v = *(const u16x8*)&tw[lrow * TST + lcol];
            *(u16x8*)&C[(size_t)row * 128 + wn * 64 + lcol] = v;
        }
    }
}

// ---------------- fused aggregation, sub-wave-per-node ----------------------
// PRE=true: input rows are pre-scaled by dis (H'[j] = H[j]*dis[j]); the
// aggregation is then agg[i] = dis[i] * (H'[i] + sum_s H'[s]) — inner loop is
// pure ADD with no per-edge dis gather.

template <int F, bool BACT, bool PRE>
__global__ __launch_bounds__(256) void k_agg(
        const bf16_t* __restrict__ H, const int* __restrict__ rowptr,
        const int* __restrict__ csr, const float* __restrict__ dis,
        const float* __restrict__ bias, bf16_t* __restrict__ out, int N) {
    constexpr int SUB = F / 8;          // lanes per node
    constexpr int NPW = 64 / SUB;       // nodes per wave
    constexpr int SH  = (SUB == 16) ? 4 : 3;
    int gtid = blockIdx.x * 256 + threadIdx.x;
    int wave = gtid >> 6, lane = gtid & 63;
    int sub = lane >> SH, sl = lane & (SUB - 1);
    int node = wave * NPW + sub;
    if (node >= N) return;
    float di = dis[node];
    int s = rowptr[node], e = rowptr[node + 1];

    auto load_row = [&](const bf16_t* p, float (&r)[8]) {
        u16x8 v = *(const u16x8*)p;
#pragma unroll
        for (int f = 0; f < 8; f++) r[f] = bf2f(v[f]);
    };

    float acc[8], acc2[8];
    {
        float r[8];
        load_row(H + (size_t)node * F + sl * 8, r);
        float sln = PRE ? 1.f : di * di;   // PRE: self row already carries di
#pragma unroll
        for (int f = 0; f < 8; f++) { acc[f] = r[f] * sln; acc2[f] = 0.f; }
    }
    int p = s;
    for (; p + 4 <= e; p += 4) {
        int s0 = csr[p], s1 = csr[p + 1], s2 = csr[p + 2], s3 = csr[p + 3];
        float r0[8], r1[8], r2[8], r3[8];
        load_row(H + (size_t)s0 * F + sl * 8, r0);
        load_row(H + (size_t)s1 * F + sl * 8, r1);
        load_row(H + (size_t)s2 * F + sl * 8, r2);
        load_row(H + (size_t)s3 * F + sl * 8, r3);
        if (PRE) {
#pragma unroll
            for (int f = 0; f < 8; f++) {
                acc[f]  += r0[f] + r2[f];
                acc2[f] += r1[f] + r3[f];
            }
        } else {
            float n0 = dis[s0] * di, n1 = dis[s1] * di;
            float n2 = dis[s2] * di, n3 = dis[s3] * di;
#pragma unroll
            for (int f = 0; f < 8; f++) {
                acc[f]  += r0[f] * n0; acc2[f] += r1[f] * n1;
                acc[f]  += r2[f] * n2; acc2[f] += r3[f] * n3;
            }
        }
    }
    if (p + 2 <= e) {
        int s0 = csr[p], s1 = csr[p + 1];
        float r0[8], r1[8];
        load_row(H + (size_t)s0 * F + sl * 8, r0);
        load_row(H + (size_t)s1 * F + sl * 8, r1);
        if (PRE) {
#pragma unroll
            for (int f = 0; f < 8; f++) { acc[f] += r0[f]; acc2[f] += r1[f]; }
        } else {
            float n0 = dis[s0] * di, n1 = dis[s1] * di;
#pragma unroll
            for (int f = 0; f < 8; f++) { acc[f] += r0[f] * n0; acc2[f] += r1[f] * n1; }
        }
        p += 2;
    }
    if (p < e) {
        int s0 = csr[p];
        float r0[8];
        load_row(H + (size_t)s0 * F + sl * 8, r0);
        if (PRE) {
#pragma unroll
            for (int f = 0; f < 8; f++) acc[f] += r0[f];
        } else {
            float n0 = dis[s0] * di;
#pragma unroll
            for (int f = 0; f < 8; f++) acc[f] += r0[f] * n0;
        }
    }

    float o[8];
#pragma unroll
    for (int f = 0; f < 8; f++) {
        float v = acc[f] + acc2[f];
        if (PRE) v *= di;
        if (BACT) {
            v += bias[sl * 8 + f];
            v = v > 0.f ? v : 0.1f * v;
        }
        o[f] = v;
    }
    u16x8 w = {f2bf(o[0]), f2bf(o[1]), f2bf(o[2]), f2bf(o[3]),
               f2bf(o[4]), f2bf(o[5]), f2bf(o[6]), f2bf(o[7])};
    *(u16x8*)(out + (size_t)node * F + sl * 8) = w;
}

// ---------------- fused MLP2-reduce + bias + lrelu + head ------------------

__global__ __launch_bounds__(256) void k_head2(
        const float* __restrict__ part, const float* __restrict__ L2b,
        const float* __restrict__ L3w, const float* __restrict__ L3b,
        float* __restrict__ out, int G) {
    int wv = (int)((blockIdx.x * blockDim.x + threadIdx.x) >> 6);
    int lane = threadIdx.x & 63;
    if (wv >= G) return;
    size_t base = (size_t)wv * 128 + lane * 2;
    size_t GM = (size_t)G * 128;
    float2 s = *(const float2*)&part[base];
#pragma unroll
    for (int z = 1; z < 4; z++) {
        float2 p = *(const float2*)&part[z * GM + base];
        s.x += p.x; s.y += p.y;
    }
    float2 b = *(const float2*)&L2b[lane * 2];
    float vx = s.x + b.x, vy = s.y + b.y;
    vx = vx > 0.f ? vx : 0.1f * vx;
    vy = vy > 0.f ? vy : 0.1f * vy;
    float2 wl = *(const float2*)&L3w[lane * 2];
    float d = vx * wl.x + vy * wl.y;
    for (int off = 32; off > 0; off >>= 1) d += __shfl_xor(d, off, 64);
    if (lane == 0) out[wv] = 1.f / (1.f + expf(-(d + L3b[0])));
}

// ---------------- launch ----------------

extern "C" void kernel_launch(void* const* d_in, const int* in_sizes, int n_in,
                              void* d_out, int out_size, void* d_ws, size_t ws_size,
                              hipStream_t stream) {
    const float* x   = (const float*)d_in[0];
    const int*   ei  = (const int*)d_in[1];
    const float* W1  = (const float*)d_in[2];  const float* b1  = (const float*)d_in[3];
    const float* W2  = (const float*)d_in[4];  const float* b2  = (const float*)d_in[5];
    const float* W3  = (const float*)d_in[6];  const float* b3  = (const float*)d_in[7];
    const float* L1w = (const float*)d_in[8];  const float* L1b = (const float*)d_in[9];
    const float* L2w = (const float*)d_in[10]; const float* L2b = (const float*)d_in[11];
    const float* L3w = (const float*)d_in[12]; const float* L3b = (const float*)d_in[13];
    float* out = (float*)d_out;

    const int C = 40;
    const int N = in_sizes[0] / C;     // 200000
    const int E = in_sizes[1] / 2;     // 1000000
    const int G = N / 40;              // 5000
    const int H1d = 128, H2d = 256, H3d = 128, M1 = 512, M2 = 128;
    const int K1 = 40 * H3d;           // 5120

    // ---- workspace layout ----
    char* wsb = (char*)d_ws;
    size_t off = 0;
    auto alloc = [&](size_t bytes) -> void* {
        void* p = wsb + off;
        off += (bytes + 255) & ~(size_t)255;
        return p;
    };
    int*    cnt8   = (int*)alloc(4 * 8 * (size_t)N);
    int*    rowptr = (int*)alloc(4 * (size_t)(N + 1));
    int*    cur    = (int*)alloc(4 * (size_t)N);
    int*    csr    = (int*)alloc(4 * (size_t)E);
    int*    bsum   = (int*)alloc(4 * 512);
    float*  dis    = (float*)alloc(4 * (size_t)N);
    bf16_t* Hb     = (bf16_t*)alloc(2 * (size_t)N * H2d);   // ping (102.4 MB)
    bf16_t* Xb     = (bf16_t*)alloc(2 * (size_t)N * H2d);   // pong (102.4 MB)
    bf16_t* W1b    = (bf16_t*)alloc(2 * (size_t)H1d * 64);
    bf16_t* W2b    = (bf16_t*)alloc(2 * (size_t)H2d * H1d);
    bf16_t* W3b    = (bf16_t*)alloc(2 * (size_t)H3d * H2d);
    bf16_t* L1wb   = (bf16_t*)alloc(2 * (size_t)M1 * K1);
    bf16_t* L2wb   = (bf16_t*)alloc(2 * (size_t)M2 * M1);
    if (off > ws_size) return;   // fail cleanly instead of faulting

    // aliasing (all within dead regions at time of use):
    int* src32 = (int*)Xb;        // packed edges during CSR build (Xb dead)
    int* dst32 = src32 + E;
    bf16_t* xb   = Hb;            // [N,64]  pad(x)          — dead after agg1
    bf16_t* A1b  = Xb;            // [N,64]  agg(x)          — overwrites src32/dst32
    bf16_t* H1   = Hb;            // [N,128] lrelu(A1 W1+b1)·dis — overwrites xb
    bf16_t* A2   = Xb;            // [N,128] agg(H1)         — overwrites A1b
    bf16_t* H3p  = Xb;            // [N,128] (A2 fused)·dis  — IN-PLACE over A2
    bf16_t* X3   = Hb;            // [N,128] lrelu(agg(H3p)+b3) — overwrites H1
    float*  part = (float*)Xb;    // MLP1 split-K partials [6][G*512] (61.4 MB)
    float*  part2 = part + 6 * (size_t)G * M1;   // MLP2 partials [4][G*128]

    // ---- weight pre-convert + x pad + cnt8 zero-fill (one dispatch) ----
    WcSeg s0 = {W1,  W1b,  H1d, 40,  64,  H1d * 64 / 8};
    WcSeg s1 = {W2,  W2b,  H2d, H1d, H1d, H2d * H1d / 8};
    WcSeg s2 = {W3,  W3b,  H3d, H2d, H2d, H3d * H2d / 8};
    WcSeg s3 = {L1w, L1wb, M1,  K1,  K1,  M1 * K1 / 8};
    WcSeg s4 = {L2w, L2wb, M2,  M1,  M1,  M2 * M1 / 8};
    WcSeg s5 = {x,   xb,   N,   40,  64,  N * 64 / 8};
    int wtotal = s0.nchunk + s1.nchunk + s2.nchunk + s3.nchunk + s4.nchunk + s5.nchunk;
    int ztotal = wtotal + 2 * N;       // 2N int4-chunks zero 8N ints of cnt8
    k_wconv<<<CDIV(ztotal, 256), 256, 0, stream>>>(s0, s1, s2, s3, s4, s5,
                                                   wtotal, cnt8, ztotal);

    // ---- CSR by dst (pack+hist+detect fused, XCD-range-filtered fill) ----
    k_packhist<<<CDIV(E, 256), 256, 0, stream>>>(ei, E, src32, dst32, cnt8, N);
    int nb = CDIV(N + 1, 1024);        // 196 <= 256
    k_blockred<<<nb, 256, 0, stream>>>(cnt8, bsum, N);
    k_scanwrite<<<nb, 256, 0, stream>>>(cnt8, bsum, rowptr, cur, dis, N, nb);
    int NR = CDIV(N, 8);               // nodes per XCD range
    k_fill_r<<<8 * CDIV(E, FILL_EPB), 256, 0, stream>>>(src32, dst32, E, cur, csr, N, NR);

    const int NB = CDIV(N, 128);       // 1563

    // ---- conv1 (aggregate-first in 40->64-dim); H1 output pre-scaled ----
    k_agg<64, false, false><<<CDIV(N, 32), 256, 0, stream>>>(xb, rowptr, csr, dis, nullptr, A1b, N);
    gemm_mfma<true, true, 1, false, true><<<dim3(1, NB), 256, 0, stream>>>(A1b, W1b, b1, H1, N, 64, H1d, 0, 0, 0, dis);
    // ---- conv2 + conv3-transform fused (H2 never hits HBM), BM=64 ----
    k_agg<128, false, true><<<CDIV(N, 16), 256, 0, stream>>>(H1, rowptr, csr, dis, nullptr, A2, N);
    gemm_fused23<<<CDIV(N, 64), 256, 0, stream>>>(A2, W2b, b2, W3b, dis, H3p, N);
    k_agg<128, true, true><<<CDIV(N, 16), 256, 0, stream>>>(H3p, rowptr, csr, dis, b3, X3, N);

    // ---- readout MLP1: split-K S=6, XCD-grouped 1D grid (960 blocks) ----
    gemm_mfma<false, false, 0, true, false><<<960, 256, 0, stream>>>(X3, L1wb, nullptr, part, G, K1, M1, 896, 4, 40, nullptr);
    // ---- readout MLP2: k_red fused into A-staging; S=4, 160 blocks ----
    gemm_mlp2<<<160, 256, 0, stream>>>(part, L1b, L2wb, part2, G);
    k_head2<<<CDIV(G, 4), 256, 0, stream>>>(part2, L2b, L3w, L3b, out, G);
}

// Round 10
// 458.782 us; speedup vs baseline: 1.0704x; 1.0287x over previous
//
#include <hip/hip_runtime.h>
#include <cmath>

#define CDIV(a,b) (((a)+(b)-1)/(b))

typedef unsigned short bf16_t;
using short8 = __attribute__((ext_vector_type(8))) short;
using f32x4  = __attribute__((ext_vector_type(4))) float;
using u16x4  = __attribute__((ext_vector_type(4))) unsigned short;
using u16x8  = __attribute__((ext_vector_type(8))) unsigned short;

__device__ __forceinline__ float bf2f(unsigned short b) {
    unsigned u = ((unsigned)b) << 16;
    float f;
    __builtin_memcpy(&f, &u, 4);
    return f;
}
__device__ __forceinline__ unsigned short f2bf(float f) {
    unsigned u;
    __builtin_memcpy(&u, &f, 4);
    u = (u + 0x7FFFu + ((u >> 16) & 1u)) >> 16;
    return (unsigned short)u;
}

// async global->LDS, 16B per lane. LDS dest must be linear in lane order
// (wave-uniform base + lane*16); swizzle is folded into the GLOBAL address.
__device__ __forceinline__ void gload16(const bf16_t* g, unsigned short* l) {
    __builtin_amdgcn_global_load_lds(
        (const __attribute__((address_space(1))) void*)(g),
        (__attribute__((address_space(3))) void*)(l), 16, 0, 0);
}

__device__ __forceinline__ int edge_src(const int* ei, int E, int f, int i) {
    return f ? ei[2 * (size_t)i] : ei[i];
}
__device__ __forceinline__ int edge_dst(const int* ei, int E, int f, int i) {
    return f ? ei[2 * ((size_t)E + (size_t)i)] : ei[(size_t)E + (size_t)i];
}

// ---- pack edges to int32 + 8x-privatized dst histogram (detect inlined) ----
__global__ __launch_bounds__(256) void k_packhist(const int* __restrict__ ei, int E,
                                                  int* __restrict__ src32,
                                                  int* __restrict__ dst32,
                                                  int* __restrict__ cnt8, int N) {
    __shared__ int sflag;
    int t = threadIdx.x;
    if (t < 64) {   // whole wave 0: detect int64 layout from first 64 edges
        unsigned v = (unsigned)ei[2 * t + 1];
        unsigned long long m = __ballot(v != 0u);
        if (t == 0) sflag = (m == 0ULL) ? 1 : 0;
    }
    __syncthreads();
    int i = blockIdx.x * 256 + t;
    if (i >= E) return;
    int f = sflag;
    int s = edge_src(ei, E, f, i);
    int d = edge_dst(ei, E, f, i);
    src32[i] = s;
    dst32[i] = d;
    if ((unsigned)d < (unsigned)N)
        atomicAdd(&cnt8[(blockIdx.x & 7) * N + d], 1);
}

__global__ void k_blockred(const int* __restrict__ cnt8, int* __restrict__ bsum, int N) {
    __shared__ int sd[256];
    int b = blockIdx.x, t = threadIdx.x;
    int base = b * 1024 + t * 4;
    int s = 0;
#pragma unroll
    for (int i = 0; i < 4; i++) {
        int idx = base + i;
        if (idx < N)
#pragma unroll
            for (int r = 0; r < 8; r++) s += cnt8[r * N + idx];
    }
    sd[t] = s; __syncthreads();
    for (int off = 128; off > 0; off >>= 1) { if (t < off) sd[t] += sd[t + off]; __syncthreads(); }
    if (t == 0) bsum[b] = sd[0];
}

// scanwrite with the bsum scan inlined
__global__ void k_scanwrite(const int* __restrict__ cnt8, const int* __restrict__ bsum,
                            int* __restrict__ rowptr, int* __restrict__ cur,
                            float* __restrict__ dis, int N, int nb) {
    __shared__ int sb[256];
    __shared__ int sd[256];
    int b = blockIdx.x, t = threadIdx.x;
    int v0 = (t < nb) ? bsum[t] : 0;
    sb[t] = v0; __syncthreads();
    for (int off = 1; off < 256; off <<= 1) {
        int y = (t >= off) ? sb[t - off] : 0;
        __syncthreads();
        sb[t] += y;
        __syncthreads();
    }
    int block_pre = (b == 0) ? 0 : sb[b - 1];

    int base = b * 1024 + t * 4;
    int tot[4]; int s = 0;
#pragma unroll
    for (int i = 0; i < 4; i++) {
        int idx = base + i;
        tot[i] = 0;
        if (idx < N) {
#pragma unroll
            for (int r = 0; r < 8; r++) tot[i] += cnt8[r * N + idx];
        }
        s += tot[i];
    }
    sd[t] = s; __syncthreads();
    for (int off = 1; off < 256; off <<= 1) {
        int y = (t >= off) ? sd[t - off] : 0;
        __syncthreads();
        sd[t] += y;
        __syncthreads();
    }
    int pre = block_pre + sd[t] - s;
#pragma unroll
    for (int i = 0; i < 4; i++) {
        int idx = base + i;
        if (idx < N) {
            rowptr[idx] = pre;
            cur[idx] = pre;
            dis[idx] = rsqrtf((float)tot[i] + 1.0f);
            pre += tot[i];
        } else if (idx == N) {
            rowptr[N] = pre;
        }
    }
}

// Range-filtered fill (XCD write locality)
#define FILL_EPB 4096
__global__ __launch_bounds__(256) void k_fill_r(
        const int* __restrict__ src32, const int* __restrict__ dst32, int E,
        int* __restrict__ cur, int* __restrict__ csr, int N, int NR) {
    int r = blockIdx.x & 7;
    int chunk = blockIdx.x >> 3;
    int lo = r * NR;
    int hi = min(lo + NR, N);
    int base = chunk * FILL_EPB;
    int end = min(base + FILL_EPB, E);
    for (int i = base + threadIdx.x; i < end; i += 256) {
        int d = dst32[i];
        if (d >= lo && d < hi) {
            int s = src32[i];
            if ((unsigned)s < (unsigned)N) {
                int p = atomicAdd(&cur[d], 1);
                csr[p] = s;
            }
        }
    }
}

// ---------------- weight pre-convert + x pad + cnt8 zero-fill ---------------

struct WcSeg { const float* src; bf16_t* dst; int M, KW, KP, nchunk; };

__global__ __launch_bounds__(256) void k_wconv(WcSeg s0, WcSeg s1, WcSeg s2,
                                               WcSeg s3, WcSeg s4, WcSeg s5,
                                               int wtotal, int* __restrict__ zdst,
                                               int total) {
    int i = blockIdx.x * 256 + threadIdx.x;
    if (i >= total) return;
    if (i >= wtotal) {   // zero-fill tail: 16 B of cnt8 per thread
        int4 z = {0, 0, 0, 0};
        *(int4*)(zdst + (size_t)(i - wtotal) * 4) = z;
        return;
    }
    WcSeg s;
    if (i < s0.nchunk) s = s0;
    else if ((i -= s0.nchunk) < s1.nchunk) s = s1;
    else if ((i -= s1.nchunk) < s2.nchunk) s = s2;
    else if ((i -= s2.nchunk) < s3.nchunk) s = s3;
    else if ((i -= s3.nchunk) < s4.nchunk) s = s4;
    else { i -= s4.nchunk; s = s5; }
    int cpr = s.KP >> 3;                // chunks per row
    int row = i / cpr, kk = (i % cpr) << 3;
    short8 v = {};
    if (kk < s.KW) {
        const float4* p = (const float4*)(s.src + (size_t)row * s.KW + kk);
        float4 a = p[0], b = p[1];
        v[0] = (short)f2bf(a.x); v[1] = (short)f2bf(a.y);
        v[2] = (short)f2bf(a.z); v[3] = (short)f2bf(a.w);
        v[4] = (short)f2bf(b.x); v[5] = (short)f2bf(b.y);
        v[6] = (short)f2bf(b.z); v[7] = (short)f2bf(b.w);
    }
    *(short8*)(s.dst + (size_t)row * s.KP + kk) = v;
}

// ---------------- MFMA GEMM: C[i][j] = sum_k A[i][k] * Wb[j][k] --------------
// SCALE: multiply the (activated) output row by rowscale[row] in the CBF
// epilogue — used to pre-scale H1 by deg_inv_sqrt for the PRE aggregation.

template <bool CBF, bool BIAS, int ACT, bool SPLIT, bool SCALE>
__global__ __launch_bounds__(256) void gemm_mfma(
        const bf16_t* __restrict__ A, const bf16_t* __restrict__ Wb,
        const float* __restrict__ bias, void* __restrict__ Cv,
        int N, int K, int M, int Kseg, int nx, int ny,
        const float* __restrict__ rowscale) {
    constexpr int BM = 128, BK = 64;
    __shared__ __align__(16) unsigned short lds[4 * 64 * 68];
    unsigned short* Als = lds;
    unsigned short* Bls = lds + BM * BK;

    int t = threadIdx.x;
    int lane = t & 63, wid = t >> 6;
    int quad = lane >> 4, l15 = lane & 15;
    int wave_m = wid & 1, wave_n = wid >> 1;

    int bx, by, bz;
    if (SPLIT) {
        int bid = (int)blockIdx.x;
        int xcd = bid & 7, li = bid >> 3;
        bx = li % nx;
        int pl = li / nx;
        int ppx = (int)(gridDim.x >> 3) / nx;   // pairs per XCD
        int pair = xcd * ppx + pl;
        by = pair % ny;
        bz = pair / ny;
    } else {
        bx = blockIdx.x; by = blockIdx.y; bz = 0;
    }

    int bm0 = by * BM;     // node tile
    int bn0 = bx * BM;     // M tile
    int kbeg = SPLIT ? bz * Kseg : 0;
    int kend = SPLIT ? min(kbeg + Kseg, K) : K;

    f32x4 acc[4][4] = {};

    for (int k0 = kbeg; k0 < kend; k0 += BK) {
#pragma unroll
        for (int it = 0; it < 4; it++) {
            int idx = t + it * 256;
            int row = idx >> 3, sc = idx & 7;
            int c = sc ^ (row & 7);            // pre-swizzled source chunk
            int ga = bm0 + row; if (ga >= N) ga = N - 1;   // clamp (masked at store)
            gload16(A + (size_t)ga * K + k0 + c * 8, Als + idx * 8);
            gload16(Wb + (size_t)(bn0 + row) * K + k0 + c * 8, Bls + idx * 8);
        }
        __syncthreads();                        // drains vmcnt

#pragma unroll
        for (int ks = 0; ks < 2; ks++) {
            short8 af[4], bfr[4];
            int ck = ks * 4 + quad;
            int sw = (ck ^ (l15 & 7)) << 3;
#pragma unroll
            for (int mt = 0; mt < 4; mt++)
                af[mt] = *(const short8*)&Als[(wave_m * 64 + mt * 16 + l15) * BK + sw];
#pragma unroll
            for (int nt = 0; nt < 4; nt++)
                bfr[nt] = *(const short8*)&Bls[(wave_n * 64 + nt * 16 + l15) * BK + sw];
#pragma unroll
            for (int mt = 0; mt < 4; mt++)
#pragma unroll
                for (int nt = 0; nt < 4; nt++)
                    acc[mt][nt] = __builtin_amdgcn_mfma_f32_16x16x32_bf16(
                        af[mt], bfr[nt], acc[mt][nt], 0, 0, 0);
        }
        __syncthreads();
    }

    if (!SPLIT && CBF) {
        constexpr int TST = 68;
        unsigned short* tw = lds + wid * 64 * TST;
#pragma unroll
        for (int mt = 0; mt < 4; mt++) {
#pragma unroll
            for (int nt = 0; nt < 4; nt++) {
                int tcol = nt * 16 + l15;
                float bv = BIAS ? bias[bn0 + wave_n * 64 + tcol] : 0.f;
#pragma unroll
                for (int r = 0; r < 4; r++) {
                    float x = acc[mt][nt][r];
                    if (BIAS) x += bv;
                    if (ACT == 1) x = x > 0.f ? x : 0.1f * x;
                    if (SCALE) {
                        int row = bm0 + wave_m * 64 + mt * 16 + quad * 4 + r;
                        x *= rowscale[row < N ? row : N - 1];
                    }
                    tw[(mt * 16 + quad * 4 + r) * TST + tcol] = f2bf(x);
                }
            }
        }
        __syncthreads();
        bf16_t* C = (bf16_t*)Cv;
        int lrow0 = lane >> 3, lcol = (lane & 7) * 8;
#pragma unroll
        for (int it = 0; it < 8; it++) {
            int lrow = it * 8 + lrow0;
            int row = bm0 + wave_m * 64 + lrow;
            if (row < N) {
                u16x8 v = *(const u16x8*)&tw[lrow * TST + lcol];
                *(u16x8*)&C[(size_t)row * M + bn0 + wave_n * 64 + lcol] = v;
            }
        }
    } else {
        float* Pz = SPLIT ? ((float*)Cv + (size_t)bz * N * M) : (float*)Cv;
#pragma unroll
        for (int mt = 0; mt < 4; mt++) {
            int rbase = bm0 + wave_m * 64 + mt * 16 + quad * 4;
#pragma unroll
            for (int nt = 0; nt < 4; nt++) {
                int col = bn0 + wave_n * 64 + nt * 16 + l15;
                float bv = (BIAS && !SPLIT) ? bias[col] : 0.f;
#pragma unroll
                for (int r = 0; r < 4; r++) {
                    int row = rbase + r;
                    if (row >= N) continue;
                    float x = acc[mt][nt][r];
                    if (!SPLIT) {
                        if (BIAS) x += bv;
                        if (ACT == 1) x = x > 0.f ? x : 0.1f * x;
                    }
                    Pz[(size_t)row * M + col] = x;
                }
            }
        }
    }
}

// ---------------- MLP2 GEMM with fused MLP1-reduce in A-staging -------------
__global__ __launch_bounds__(256) void gemm_mlp2(
        const float* __restrict__ part6,   // [6][G*512] fp32
        const float* __restrict__ L1b,     // [512]
        const bf16_t* __restrict__ Wb,     // L2wb [128,512] bf16
        float* __restrict__ Pout,          // [4][G*128] fp32
        int G) {
    constexpr int BM = 128, BK = 64, K = 512, M = 128, NY = 40;
    __shared__ __align__(16) unsigned short lds[2 * BM * BK];   // 32 KB
    unsigned short* Als = lds;
    unsigned short* Bls = lds + BM * BK;

    int t = threadIdx.x;
    int lane = t & 63, wid = t >> 6;
    int quad = lane >> 4, l15 = lane & 15;
    int wave_m = wid & 1, wave_n = wid >> 1;

    int bid = (int)blockIdx.x;
    int xcd = bid & 7, li = bid >> 3;
    int ppx = (int)(gridDim.x >> 3);        // pairs per XCD (nx=1)
    int pair = xcd * ppx + li;
    int by = pair % NY;
    int bz = pair / NY;

    int bm0 = by * BM;
    int kbeg = bz * (K / 4);                // Kseg = 128
    size_t GK = (size_t)G * K;

    f32x4 acc[4][4] = {};

    for (int k0 = kbeg; k0 < kbeg + K / 4; k0 += BK) {
#pragma unroll
        for (int it = 0; it < 4; it++) {
            int idx = t + it * 256;
            int row = idx >> 3, sc = idx & 7;
            int cW = sc ^ (row & 7);
            gload16(Wb + (size_t)row * K + k0 + cW * 8, Bls + idx * 8);
            int g = bm0 + row; if (g >= G) g = G - 1;
            const float* pb = part6 + (size_t)g * K + k0 + sc * 8;
            float v[8] = {};
#pragma unroll
            for (int z = 0; z < 6; z++) {
                const float* pz = pb + (size_t)z * GK;
                float4 a = *(const float4*)pz;
                float4 b = *(const float4*)(pz + 4);
                v[0] += a.x; v[1] += a.y; v[2] += a.z; v[3] += a.w;
                v[4] += b.x; v[5] += b.y; v[6] += b.z; v[7] += b.w;
            }
            float4 b0 = *(const float4*)&L1b[k0 + sc * 8];
            float4 b1 = *(const float4*)&L1b[k0 + sc * 8 + 4];
            float bb[8] = {b0.x, b0.y, b0.z, b0.w, b1.x, b1.y, b1.z, b1.w};
            u16x8 o;
#pragma unroll
            for (int j = 0; j < 8; j++) {
                float xv = v[j] + bb[j];
                xv = xv > 0.f ? xv : 0.1f * xv;
                o[j] = f2bf(xv);
            }
            *(u16x8*)&Als[row * BK + ((sc ^ (row & 7)) << 3)] = o;
        }
        __syncthreads();                    // drains vmcnt + lgkm

#pragma unroll
        for (int ks = 0; ks < 2; ks++) {
            short8 af[4], bfr[4];
            int ck = ks * 4 + quad;
            int sw = (ck ^ (l15 & 7)) << 3;
#pragma unroll
            for (int mt = 0; mt < 4; mt++)
                af[mt] = *(const short8*)&Als[(wave_m * 64 + mt * 16 + l15) * BK + sw];
#pragma unroll
            for (int nt = 0; nt < 4; nt++)
                bfr[nt] = *(const short8*)&Bls[(wave_n * 64 + nt * 16 + l15) * BK + sw];
#pragma unroll
            for (int mt = 0; mt < 4; mt++)
#pragma unroll
                for (int nt = 0; nt < 4; nt++)
                    acc[mt][nt] = __builtin_amdgcn_mfma_f32_16x16x32_bf16(
                        af[mt], bfr[nt], acc[mt][nt], 0, 0, 0);
        }
        __syncthreads();
    }

    float* Pz = Pout + (size_t)bz * G * M;
#pragma unroll
    for (int mt = 0; mt < 4; mt++) {
        int rbase = bm0 + wave_m * 64 + mt * 16 + quad * 4;
#pragma unroll
        for (int nt = 0; nt < 4; nt++) {
            int col = wave_n * 64 + nt * 16 + l15;
#pragma unroll
            for (int r = 0; r < 4; r++) {
                int row = rbase + r;
                if (row >= G) continue;
                Pz[(size_t)row * M + col] = acc[mt][nt][r];
            }
        }
    }
}

// ------- fused agg(H1) + conv2-GEMM + lrelu + conv3-GEMM (BM=64, 48 KB) -----
// The A2 = dis.(H1' + sum_s H1') aggregation is computed IN-KERNEL per 64-row
// tile (4 lanes/row x 32 cols, 2-deep neighbor unroll, pure adds in PRE form)
// and written bf16 straight into the swizzled A-LDS layout — eliminates the
// separate k_agg dispatch + the 50 MB A2 write / 26 MB re-read. W2's first
// k-half staging is issued BEFORE the gather so its loads fly underneath.
// Output pre-scaled by dis[row] for the following PRE aggregation.
__global__ __launch_bounds__(256, 3) void gemm_fused23(
        const bf16_t* __restrict__ H1,   // [N,128] pre-scaled by dis
        const int* __restrict__ rowptr, const int* __restrict__ csr,
        const float* __restrict__ dis,
        const bf16_t* __restrict__ W2,   // [256,128] bf16
        const float*  __restrict__ b2,
        const bf16_t* __restrict__ W3,   // [128,256] bf16
        bf16_t* __restrict__ C,          // [N,128]
        int N) {
    __shared__ __align__(16) unsigned short lds[24576];   // 48 KB
    unsigned short* Als  = lds;            // [2][64][64] 16 KB  A tile (both halves)
    unsigned short* Bls  = lds + 8192;     // [256][64]   32 KB  W2 k-half tile
    unsigned short* H2ls = lds;            // [64][256]   32 KB  (aliases A + W2 head)
    unsigned short* B2ls = lds + 16384;    // [128][64]   16 KB  phase-2 W3 tile

    int t = threadIdx.x;
    int lane = t & 63, wid = t >> 6;
    int quad = lane >> 4, l15 = lane & 15;
    int wm = wid & 1, wn = wid >> 1;       // 2x2 wave tiling (both phases)
    int bm0 = blockIdx.x * 64;

    float bv[8];
#pragma unroll
    for (int nt = 0; nt < 8; nt++) bv[nt] = b2[wn * 128 + nt * 16 + l15];

    // ---- issue W2 k-half 0 staging first (flies under the gather) ----
#pragma unroll
    for (int it = 0; it < 8; it++) {           // W2 half: 2048 chunks
        int idx = t + it * 256;
        int row = idx >> 3, sc = idx & 7;
        int c = sc ^ (row & 7);
        gload16(W2 + (size_t)row * 128 + c * 8, Bls + idx * 8);
    }

    // ---- in-kernel PRE aggregation -> swizzled A tile in LDS ----
    {
        int r = t >> 2, l4 = t & 3;            // 64 rows x 4 lanes
        int row = bm0 + r; if (row >= N) row = N - 1;   // masked at C store
        int cb = l4 * 32;                      // 32 cols per lane
        const bf16_t* Hrow = H1 + (size_t)row * 128 + cb;
        float acc[32];
        {
            u16x8 v[4];
#pragma unroll
            for (int j = 0; j < 4; j++) v[j] = *(const u16x8*)(Hrow + j * 8);
#pragma unroll
            for (int j = 0; j < 4; j++)
#pragma unroll
                for (int f = 0; f < 8; f++) acc[j * 8 + f] = bf2f(v[j][f]);
        }
        int s = rowptr[row], e = rowptr[row + 1];
        int p = s;
        for (; p + 2 <= e; p += 2) {
            int s0 = csr[p], s1 = csr[p + 1];
            const bf16_t* p0 = H1 + (size_t)s0 * 128 + cb;
            const bf16_t* p1 = H1 + (size_t)s1 * 128 + cb;
            u16x8 a0[4], a1[4];
#pragma unroll
            for (int j = 0; j < 4; j++) { a0[j] = *(const u16x8*)(p0 + j * 8);
                                          a1[j] = *(const u16x8*)(p1 + j * 8); }
#pragma unroll
            for (int j = 0; j < 4; j++)
#pragma unroll
                for (int f = 0; f < 8; f++)
                    acc[j * 8 + f] += bf2f(a0[j][f]) + bf2f(a1[j][f]);
        }
        if (p < e) {
            int s0 = csr[p];
            const bf16_t* p0 = H1 + (size_t)s0 * 128 + cb;
            u16x8 a0[4];
#pragma unroll
            for (int j = 0; j < 4; j++) a0[j] = *(const u16x8*)(p0 + j * 8);
#pragma unroll
            for (int j = 0; j < 4; j++)
#pragma unroll
                for (int f = 0; f < 8; f++) acc[j * 8 + f] += bf2f(a0[j][f]);
        }
        float di = dis[row];
#pragma unroll
        for (int j = 0; j < 4; j++) {
            int col0 = cb + j * 8;
            int h = col0 >> 6;                 // k-half
            int ck = (col0 & 63) >> 3;         // chunk within half
            int swc = ck ^ (r & 7);
            u16x8 o;
#pragma unroll
            for (int f = 0; f < 8; f++) o[f] = f2bf(acc[j * 8 + f] * di);
            *(u16x8*)&Als[h * 4096 + r * 64 + (swc << 3)] = o;
        }
    }
    __syncthreads();                           // gather ds_writes + W2 h0 loads

    // ---- phase 1: A x W2^T -> acc1 [64,256], per k-half ----
    f32x4 acc1[2][8] = {};
    for (int h = 0; h < 2; h++) {
        if (h > 0) {
#pragma unroll
            for (int it = 0; it < 8; it++) {   // W2 half 1
                int idx = t + it * 256;
                int row = idx >> 3, sc = idx & 7;
                int c = sc ^ (row & 7);
                gload16(W2 + (size_t)row * 128 + 64 + c * 8, Bls + idx * 8);
            }
            __syncthreads();
        }
#pragma unroll
        for (int ks = 0; ks < 2; ks++) {
            int ck = ks * 4 + quad;
            int sw = (ck ^ (l15 & 7)) << 3;
            short8 af[2];
#pragma unroll
            for (int mt = 0; mt < 2; mt++)
                af[mt] = *(const short8*)&Als[h * 4096 + (wm * 32 + mt * 16 + l15) * 64 + sw];
#pragma unroll
            for (int nt = 0; nt < 8; nt++) {
                short8 bfr = *(const short8*)&Bls[(wn * 128 + nt * 16 + l15) * 64 + sw];
#pragma unroll
                for (int mt = 0; mt < 2; mt++)
                    acc1[mt][nt] = __builtin_amdgcn_mfma_f32_16x16x32_bf16(
                        af[mt], bfr, acc1[mt][nt], 0, 0, 0);
            }
        }
        __syncthreads();
    }

    // ---- prefetch W3 k0=0 into B2ls while the H2 epilogue runs ----
#pragma unroll
    for (int it = 0; it < 4; it++) {           // W3: 1024 chunks
        int idx = t + it * 256;
        int row = idx >> 3, sc = idx & 7;
        int c = sc ^ (row & 7);
        gload16(W3 + (size_t)row * 256 + c * 8, B2ls + idx * 8);
    }

    // ---- phase-1 epilogue: bias + lrelu -> bf16, swizzled into H2ls ----
#pragma unroll
    for (int mt = 0; mt < 2; mt++) {
#pragma unroll
        for (int nt = 0; nt < 8; nt++) {
            int col = wn * 128 + nt * 16 + l15;
            int chunk = col >> 3, within = col & 7;
#pragma unroll
            for (int r = 0; r < 4; r++) {
                int row = wm * 32 + mt * 16 + quad * 4 + r;
                float xv = acc1[mt][nt][r] + bv[nt];
                xv = xv > 0.f ? xv : 0.1f * xv;
                H2ls[row * 256 + ((chunk ^ (row & 7)) << 3) + within] = f2bf(xv);
            }
        }
    }
    __syncthreads();   // drains W3 prefetch (vmcnt) + H2 ds_writes (lgkm)

    // ---- phase 2: C2 = H2ls * W3^T -> [64,128], wave owns 32x64 ----
    f32x4 acc2[2][4] = {};
    for (int k0 = 0; k0 < 256; k0 += 64) {
        if (k0 > 0) {
#pragma unroll
            for (int it = 0; it < 4; it++) {   // W3 tile: 1024 chunks
                int idx = t + it * 256;
                int row = idx >> 3, sc = idx & 7;
                int c = sc ^ (row & 7);
                gload16(W3 + (size_t)row * 256 + k0 + c * 8, B2ls + idx * 8);
            }
            __syncthreads();
        }
#pragma unroll
        for (int ks = 0; ks < 2; ks++) {
            int kc = (k0 >> 3) + ks * 4 + quad;
            int swa = (kc ^ (l15 & 7)) << 3;
            int swb = ((ks * 4 + quad) ^ (l15 & 7)) << 3;
            short8 af[2], bfr[4];
#pragma unroll
            for (int mt = 0; mt < 2; mt++)
                af[mt] = *(const short8*)&H2ls[(wm * 32 + mt * 16 + l15) * 256 + swa];
#pragma unroll
            for (int nt = 0; nt < 4; nt++)
                bfr[nt] = *(const short8*)&B2ls[(wn * 64 + nt * 16 + l15) * 64 + swb];
#pragma unroll
            for (int mt = 0; mt < 2; mt++)
#pragma unroll
                for (int nt = 0; nt < 4; nt++)
                    acc2[mt][nt] = __builtin_amdgcn_mfma_f32_16x16x32_bf16(
                        af[mt], bfr[nt], acc2[mt][nt], 0, 0, 0);
        }
        __syncthreads();
    }

    // ---- coalesced store epilogue (per-wave 32x64 via LDS), pre-scaled -----
    constexpr int TST = 68;
    unsigned short* tw = lds + wid * 32 * TST;     // 8704 shorts total, safe
#pragma unroll
    for (int mt = 0; mt < 2; mt++) {
#pragma unroll
        for (int r = 0; r < 4; r++) {
            int row = bm0 + wm * 32 + mt * 16 + quad * 4 + r;
            float ds = dis[row < N ? row : N - 1];
#pragma unroll
            for (int nt = 0; nt < 4; nt++) {
                int tcol = nt * 16 + l15;
                tw[(mt * 16 + quad * 4 + r) * TST + tcol] = f2bf(acc2[mt][nt][r] * ds);
            }
        }
    }
    __syncthreads();
    int lrow0 = lane >> 3, lcol = (lane & 7) * 8;
#pragma unroll
    for (int it = 0; it < 4; it++) {
        int lrow = it * 8 + lrow0;
        int row = bm0 + wm * 32 + lrow;
        if (row < N) {
            u16x8 v = *(const u16x8*)&tw[lrow * TST + lcol];
            *(u16x8*)&C[(size_t)row * 128 + wn * 64 + lcol] = v;
        }
    }
}

// ---------------- fused aggregation, sub-wave-per-node ----------------------
// PRE=true: input rows are pre-scaled by dis; inner loop is pure ADD.

template <int F, bool BACT, bool PRE>
__global__ __launch_bounds__(256) void k_agg(
        const bf16_t* __restrict__ H, const int* __restrict__ rowptr,
        const int* __restrict__ csr, const float* __restrict__ dis,
        const float* __restrict__ bias, bf16_t* __restrict__ out, int N) {
    constexpr int SUB = F / 8;          // lanes per node
    constexpr int NPW = 64 / SUB;       // nodes per wave
    constexpr int SH  = (SUB == 16) ? 4 : 3;
    int gtid = blockIdx.x * 256 + threadIdx.x;
    int wave = gtid >> 6, lane = gtid & 63;
    int sub = lane >> SH, sl = lane & (SUB - 1);
    int node = wave * NPW + sub;
    if (node >= N) return;
    float di = dis[node];
    int s = rowptr[node], e = rowptr[node + 1];

    auto load_row = [&](const bf16_t* p, float (&r)[8]) {
        u16x8 v = *(const u16x8*)p;
#pragma unroll
        for (int f = 0; f < 8; f++) r[f] = bf2f(v[f]);
    };

    float acc[8], acc2[8];
    {
        float r[8];
        load_row(H + (size_t)node * F + sl * 8, r);
        float sln = PRE ? 1.f : di * di;   // PRE: self row already carries di
#pragma unroll
        for (int f = 0; f < 8; f++) { acc[f] = r[f] * sln; acc2[f] = 0.f; }
    }
    int p = s;
    for (; p + 4 <= e; p += 4) {
        int s0 = csr[p], s1 = csr[p + 1], s2 = csr[p + 2], s3 = csr[p + 3];
        float r0[8], r1[8], r2[8], r3[8];
        load_row(H + (size_t)s0 * F + sl * 8, r0);
        load_row(H + (size_t)s1 * F + sl * 8, r1);
        load_row(H + (size_t)s2 * F + sl * 8, r2);
        load_row(H + (size_t)s3 * F + sl * 8, r3);
        if (PRE) {
#pragma unroll
            for (int f = 0; f < 8; f++) {
                acc[f]  += r0[f] + r2[f];
                acc2[f] += r1[f] + r3[f];
            }
        } else {
            float n0 = dis[s0] * di, n1 = dis[s1] * di;
            float n2 = dis[s2] * di, n3 = dis[s3] * di;
#pragma unroll
            for (int f = 0; f < 8; f++) {
                acc[f]  += r0[f] * n0; acc2[f] += r1[f] * n1;
                acc[f]  += r2[f] * n2; acc2[f] += r3[f] * n3;
            }
        }
    }
    if (p + 2 <= e) {
        int s0 = csr[p], s1 = csr[p + 1];
        float r0[8], r1[8];
        load_row(H + (size_t)s0 * F + sl * 8, r0);
        load_row(H + (size_t)s1 * F + sl * 8, r1);
        if (PRE) {
#pragma unroll
            for (int f = 0; f < 8; f++) { acc[f] += r0[f]; acc2[f] += r1[f]; }
        } else {
            float n0 = dis[s0] * di, n1 = dis[s1] * di;
#pragma unroll
            for (int f = 0; f < 8; f++) { acc[f] += r0[f] * n0; acc2[f] += r1[f] * n1; }
        }
        p += 2;
    }
    if (p < e) {
        int s0 = csr[p];
        float r0[8];
        load_row(H + (size_t)s0 * F + sl * 8, r0);
        if (PRE) {
#pragma unroll
            for (int f = 0; f < 8; f++) acc[f] += r0[f];
        } else {
            float n0 = dis[s0] * di;
#pragma unroll
            for (int f = 0; f < 8; f++) acc[f] += r0[f] * n0;
        }
    }

    float o[8];
#pragma unroll
    for (int f = 0; f < 8; f++) {
        float v = acc[f] + acc2[f];
        if (PRE) v *= di;
        if (BACT) {
            v += bias[sl * 8 + f];
            v = v > 0.f ? v : 0.1f * v;
        }
        o[f] = v;
    }
    u16x8 w = {f2bf(o[0]), f2bf(o[1]), f2bf(o[2]), f2bf(o[3]),
               f2bf(o[4]), f2bf(o[5]), f2bf(o[6]), f2bf(o[7])};
    *(u16x8*)(out + (size_t)node * F + sl * 8) = w;
}

// ---------------- fused MLP2-reduce + bias + lrelu + head ------------------

__global__ __launch_bounds__(256) void k_head2(
        const float* __restrict__ part, const float* __restrict__ L2b,
        const float* __restrict__ L3w, const float* __restrict__ L3b,
        float* __restrict__ out, int G) {
    int wv = (int)((blockIdx.x * blockDim.x + threadIdx.x) >> 6);
    int lane = threadIdx.x & 63;
    if (wv >= G) return;
    size_t base = (size_t)wv * 128 + lane * 2;
    size_t GM = (size_t)G * 128;
    float2 s = *(const float2*)&part[base];
#pragma unroll
    for (int z = 1; z < 4; z++) {
        float2 p = *(const float2*)&part[z * GM + base];
        s.x += p.x; s.y += p.y;
    }
    float2 b = *(const float2*)&L2b[lane * 2];
    float vx = s.x + b.x, vy = s.y + b.y;
    vx = vx > 0.f ? vx : 0.1f * vx;
    vy = vy > 0.f ? vy : 0.1f * vy;
    float2 wl = *(const float2*)&L3w[lane * 2];
    float d = vx * wl.x + vy * wl.y;
    for (int off = 32; off > 0; off >>= 1) d += __shfl_xor(d, off, 64);
    if (lane == 0) out[wv] = 1.f / (1.f + expf(-(d + L3b[0])));
}

// ---------------- launch ----------------

extern "C" void kernel_launch(void* const* d_in, const int* in_sizes, int n_in,
                              void* d_out, int out_size, void* d_ws, size_t ws_size,
                              hipStream_t stream) {
    const float* x   = (const float*)d_in[0];
    const int*   ei  = (const int*)d_in[1];
    const float* W1  = (const float*)d_in[2];  const float* b1  = (const float*)d_in[3];
    const float* W2  = (const float*)d_in[4];  const float* b2  = (const float*)d_in[5];
    const float* W3  = (const float*)d_in[6];  const float* b3  = (const float*)d_in[7];
    const float* L1w = (const float*)d_in[8];  const float* L1b = (const float*)d_in[9];
    const float* L2w = (const float*)d_in[10]; const float* L2b = (const float*)d_in[11];
    const float* L3w = (const float*)d_in[12]; const float* L3b = (const float*)d_in[13];
    float* out = (float*)d_out;

    const int C = 40;
    const int N = in_sizes[0] / C;     // 200000
    const int E = in_sizes[1] / 2;     // 1000000
    const int G = N / 40;              // 5000
    const int H1d = 128, H2d = 256, H3d = 128, M1 = 512, M2 = 128;
    const int K1 = 40 * H3d;           // 5120

    // ---- workspace layout ----
    char* wsb = (char*)d_ws;
    size_t off = 0;
    auto alloc = [&](size_t bytes) -> void* {
        void* p = wsb + off;
        off += (bytes + 255) & ~(size_t)255;
        return p;
    };
    int*    cnt8   = (int*)alloc(4 * 8 * (size_t)N);
    int*    rowptr = (int*)alloc(4 * (size_t)(N + 1));
    int*    cur    = (int*)alloc(4 * (size_t)N);
    int*    csr    = (int*)alloc(4 * (size_t)E);
    int*    bsum   = (int*)alloc(4 * 512);
    float*  dis    = (float*)alloc(4 * (size_t)N);
    bf16_t* Hb     = (bf16_t*)alloc(2 * (size_t)N * H2d);   // ping (102.4 MB)
    bf16_t* Xb     = (bf16_t*)alloc(2 * (size_t)N * H2d);   // pong (102.4 MB)
    bf16_t* W1b    = (bf16_t*)alloc(2 * (size_t)H1d * 64);
    bf16_t* W2b    = (bf16_t*)alloc(2 * (size_t)H2d * H1d);
    bf16_t* W3b    = (bf16_t*)alloc(2 * (size_t)H3d * H2d);
    bf16_t* L1wb   = (bf16_t*)alloc(2 * (size_t)M1 * K1);
    bf16_t* L2wb   = (bf16_t*)alloc(2 * (size_t)M2 * M1);
    if (off > ws_size) return;   // fail cleanly instead of faulting

    // aliasing (all within dead regions at time of use):
    int* src32 = (int*)Xb;        // packed edges during CSR build (Xb dead)
    int* dst32 = src32 + E;
    bf16_t* xb   = Hb;            // [N,64]  pad(x)          — dead after agg1
    bf16_t* A1b  = Xb;            // [N,64]  agg(x)          — overwrites src32/dst32
    bf16_t* H1   = Hb;            // [N,128] lrelu(A1 W1+b1)·dis — overwrites xb
    bf16_t* H3p  = Xb;            // [N,128] fused agg+conv2+3 out — overwrites A1b
    bf16_t* X3   = Hb;            // [N,128] lrelu(agg(H3p)+b3) — overwrites H1
    float*  part = (float*)Xb;    // MLP1 split-K partials [6][G*512] (61.4 MB)
    float*  part2 = part + 6 * (size_t)G * M1;   // MLP2 partials [4][G*128]

    // ---- weight pre-convert + x pad + cnt8 zero-fill (one dispatch) ----
    WcSeg s0 = {W1,  W1b,  H1d, 40,  64,  H1d * 64 / 8};
    WcSeg s1 = {W2,  W2b,  H2d, H1d, H1d, H2d * H1d / 8};
    WcSeg s2 = {W3,  W3b,  H3d, H2d, H2d, H3d * H2d / 8};
    WcSeg s3 = {L1w, L1wb, M1,  K1,  K1,  M1 * K1 / 8};
    WcSeg s4 = {L2w, L2wb, M2,  M1,  M1,  M2 * M1 / 8};
    WcSeg s5 = {x,   xb,   N,   40,  64,  N * 64 / 8};
    int wtotal = s0.nchunk + s1.nchunk + s2.nchunk + s3.nchunk + s4.nchunk + s5.nchunk;
    int ztotal = wtotal + 2 * N;       // 2N int4-chunks zero 8N ints of cnt8
    k_wconv<<<CDIV(ztotal, 256), 256, 0, stream>>>(s0, s1, s2, s3, s4, s5,
                                                   wtotal, cnt8, ztotal);

    // ---- CSR by dst (pack+hist+detect fused, XCD-range-filtered fill) ----
    k_packhist<<<CDIV(E, 256), 256, 0, stream>>>(ei, E, src32, dst32, cnt8, N);
    int nb = CDIV(N + 1, 1024);        // 196 <= 256
    k_blockred<<<nb, 256, 0, stream>>>(cnt8, bsum, N);
    k_scanwrite<<<nb, 256, 0, stream>>>(cnt8, bsum, rowptr, cur, dis, N, nb);
    int NR = CDIV(N, 8);               // nodes per XCD range
    k_fill_r<<<8 * CDIV(E, FILL_EPB), 256, 0, stream>>>(src32, dst32, E, cur, csr, N, NR);

    const int NB = CDIV(N, 128);       // 1563

    // ---- conv1 (aggregate-first in 40->64-dim); H1 output pre-scaled ----
    k_agg<64, false, false><<<CDIV(N, 32), 256, 0, stream>>>(xb, rowptr, csr, dis, nullptr, A1b, N);
    gemm_mfma<true, true, 1, false, true><<<dim3(1, NB), 256, 0, stream>>>(A1b, W1b, b1, H1, N, 64, H1d, 0, 0, 0, dis);
    // ---- agg(H1) + conv2 + conv3-transform fused in one kernel ----
    gemm_fused23<<<CDIV(N, 64), 256, 0, stream>>>(H1, rowptr, csr, dis, W2b, b2, W3b, H3p, N);
    k_agg<128, true, true><<<CDIV(N, 16), 256, 0, stream>>>(H3p, rowptr, csr, dis, b3, X3, N);

    // ---- readout MLP1: split-K S=6, XCD-grouped 1D grid (960 blocks) ----
    gemm_mfma<false, false, 0, true, false><<<960, 256, 0, stream>>>(X3, L1wb, nullptr, part, G, K1, M1, 896, 4, 40, nullptr);
    // ---- readout MLP2: k_red fused into A-staging; S=4, 160 blocks ----
    gemm_mlp2<<<160, 256, 0, stream>>>(part, L1b, L2wb, part2, G);
    k_head2<<<CDIV(G, 4), 256, 0, stream>>>(part2, L2b, L3w, L3b, out, G);
}

// Round 11
// 456.757 us; speedup vs baseline: 1.0751x; 1.0044x over previous
//
#include <hip/hip_runtime.h>
#include <cmath>

#define CDIV(a,b) (((a)+(b)-1)/(b))

typedef unsigned short bf16_t;
using short8 = __attribute__((ext_vector_type(8))) short;
using f32x4  = __attribute__((ext_vector_type(4))) float;
using u16x4  = __attribute__((ext_vector_type(4))) unsigned short;
using u16x8  = __attribute__((ext_vector_type(8))) unsigned short;

__device__ __forceinline__ float bf2f(unsigned short b) {
    unsigned u = ((unsigned)b) << 16;
    float f;
    __builtin_memcpy(&f, &u, 4);
    return f;
}
__device__ __forceinline__ unsigned short f2bf(float f) {
    unsigned u;
    __builtin_memcpy(&u, &f, 4);
    u = (u + 0x7FFFu + ((u >> 16) & 1u)) >> 16;
    return (unsigned short)u;
}

// async global->LDS, 16B per lane. LDS dest must be linear in lane order
// (wave-uniform base + lane*16); swizzle is folded into the GLOBAL address.
__device__ __forceinline__ void gload16(const bf16_t* g, unsigned short* l) {
    __builtin_amdgcn_global_load_lds(
        (const __attribute__((address_space(1))) void*)(g),
        (__attribute__((address_space(3))) void*)(l), 16, 0, 0);
}

__device__ __forceinline__ int edge_src(const int* ei, int E, int f, int i) {
    return f ? ei[2 * (size_t)i] : ei[i];
}
__device__ __forceinline__ int edge_dst(const int* ei, int E, int f, int i) {
    return f ? ei[2 * ((size_t)E + (size_t)i)] : ei[(size_t)E + (size_t)i];
}

// ---- pack edges to int32 + 8x-privatized dst histogram (detect inlined) ----
__global__ __launch_bounds__(256) void k_packhist(const int* __restrict__ ei, int E,
                                                  int* __restrict__ src32,
                                                  int* __restrict__ dst32,
                                                  int* __restrict__ cnt8, int N) {
    __shared__ int sflag;
    int t = threadIdx.x;
    if (t < 64) {   // whole wave 0: detect int64 layout from first 64 edges
        unsigned v = (unsigned)ei[2 * t + 1];
        unsigned long long m = __ballot(v != 0u);
        if (t == 0) sflag = (m == 0ULL) ? 1 : 0;
    }
    __syncthreads();
    int i = blockIdx.x * 256 + t;
    if (i >= E) return;
    int f = sflag;
    int s = edge_src(ei, E, f, i);
    int d = edge_dst(ei, E, f, i);
    src32[i] = s;
    dst32[i] = d;
    if ((unsigned)d < (unsigned)N)
        atomicAdd(&cnt8[(blockIdx.x & 7) * N + d], 1);
}

__global__ void k_blockred(const int* __restrict__ cnt8, int* __restrict__ bsum, int N) {
    __shared__ int sd[256];
    int b = blockIdx.x, t = threadIdx.x;
    int base = b * 1024 + t * 4;
    int s = 0;
#pragma unroll
    for (int i = 0; i < 4; i++) {
        int idx = base + i;
        if (idx < N)
#pragma unroll
            for (int r = 0; r < 8; r++) s += cnt8[r * N + idx];
    }
    sd[t] = s; __syncthreads();
    for (int off = 128; off > 0; off >>= 1) { if (t < off) sd[t] += sd[t + off]; __syncthreads(); }
    if (t == 0) bsum[b] = sd[0];
}

// scanwrite with the bsum scan inlined
__global__ void k_scanwrite(const int* __restrict__ cnt8, const int* __restrict__ bsum,
                            int* __restrict__ rowptr, int* __restrict__ cur,
                            float* __restrict__ dis, int N, int nb) {
    __shared__ int sb[256];
    __shared__ int sd[256];
    int b = blockIdx.x, t = threadIdx.x;
    int v0 = (t < nb) ? bsum[t] : 0;
    sb[t] = v0; __syncthreads();
    for (int off = 1; off < 256; off <<= 1) {
        int y = (t >= off) ? sb[t - off] : 0;
        __syncthreads();
        sb[t] += y;
        __syncthreads();
    }
    int block_pre = (b == 0) ? 0 : sb[b - 1];

    int base = b * 1024 + t * 4;
    int tot[4]; int s = 0;
#pragma unroll
    for (int i = 0; i < 4; i++) {
        int idx = base + i;
        tot[i] = 0;
        if (idx < N) {
#pragma unroll
            for (int r = 0; r < 8; r++) tot[i] += cnt8[r * N + idx];
        }
        s += tot[i];
    }
    sd[t] = s; __syncthreads();
    for (int off = 1; off < 256; off <<= 1) {
        int y = (t >= off) ? sd[t - off] : 0;
        __syncthreads();
        sd[t] += y;
        __syncthreads();
    }
    int pre = block_pre + sd[t] - s;
#pragma unroll
    for (int i = 0; i < 4; i++) {
        int idx = base + i;
        if (idx < N) {
            rowptr[idx] = pre;
            cur[idx] = pre;
            dis[idx] = rsqrtf((float)tot[i] + 1.0f);
            pre += tot[i];
        } else if (idx == N) {
            rowptr[N] = pre;
        }
    }
}

// Range-filtered fill (XCD write locality)
#define FILL_EPB 4096
__global__ __launch_bounds__(256) void k_fill_r(
        const int* __restrict__ src32, const int* __restrict__ dst32, int E,
        int* __restrict__ cur, int* __restrict__ csr, int N, int NR) {
    int r = blockIdx.x & 7;
    int chunk = blockIdx.x >> 3;
    int lo = r * NR;
    int hi = min(lo + NR, N);
    int base = chunk * FILL_EPB;
    int end = min(base + FILL_EPB, E);
    for (int i = base + threadIdx.x; i < end; i += 256) {
        int d = dst32[i];
        if (d >= lo && d < hi) {
            int s = src32[i];
            if ((unsigned)s < (unsigned)N) {
                int p = atomicAdd(&cur[d], 1);
                csr[p] = s;
            }
        }
    }
}

// ---------------- weight pre-convert + x pad + cnt8 zero-fill ---------------

struct WcSeg { const float* src; bf16_t* dst; int M, KW, KP, nchunk; };

__global__ __launch_bounds__(256) void k_wconv(WcSeg s0, WcSeg s1, WcSeg s2,
                                               WcSeg s3, WcSeg s4, WcSeg s5,
                                               int wtotal, int* __restrict__ zdst,
                                               int total) {
    int i = blockIdx.x * 256 + threadIdx.x;
    if (i >= total) return;
    if (i >= wtotal) {   // zero-fill tail: 16 B of cnt8 per thread
        int4 z = {0, 0, 0, 0};
        *(int4*)(zdst + (size_t)(i - wtotal) * 4) = z;
        return;
    }
    WcSeg s;
    if (i < s0.nchunk) s = s0;
    else if ((i -= s0.nchunk) < s1.nchunk) s = s1;
    else if ((i -= s1.nchunk) < s2.nchunk) s = s2;
    else if ((i -= s2.nchunk) < s3.nchunk) s = s3;
    else if ((i -= s3.nchunk) < s4.nchunk) s = s4;
    else { i -= s4.nchunk; s = s5; }
    int cpr = s.KP >> 3;                // chunks per row
    int row = i / cpr, kk = (i % cpr) << 3;
    short8 v = {};
    if (kk < s.KW) {
        const float4* p = (const float4*)(s.src + (size_t)row * s.KW + kk);
        float4 a = p[0], b = p[1];
        v[0] = (short)f2bf(a.x); v[1] = (short)f2bf(a.y);
        v[2] = (short)f2bf(a.z); v[3] = (short)f2bf(a.w);
        v[4] = (short)f2bf(b.x); v[5] = (short)f2bf(b.y);
        v[6] = (short)f2bf(b.z); v[7] = (short)f2bf(b.w);
    }
    *(short8*)(s.dst + (size_t)row * s.KP + kk) = v;
}

// ---------------- MFMA GEMM: C[i][j] = sum_k A[i][k] * Wb[j][k] --------------
// SCALE: multiply the (activated) output row by rowscale[row] in the CBF
// epilogue — used to pre-scale H1 by deg_inv_sqrt for the PRE aggregation.

template <bool CBF, bool BIAS, int ACT, bool SPLIT, bool SCALE>
__global__ __launch_bounds__(256) void gemm_mfma(
        const bf16_t* __restrict__ A, const bf16_t* __restrict__ Wb,
        const float* __restrict__ bias, void* __restrict__ Cv,
        int N, int K, int M, int Kseg, int nx, int ny,
        const float* __restrict__ rowscale) {
    constexpr int BM = 128, BK = 64;
    __shared__ __align__(16) unsigned short lds[4 * 64 * 68];
    unsigned short* Als = lds;
    unsigned short* Bls = lds + BM * BK;

    int t = threadIdx.x;
    int lane = t & 63, wid = t >> 6;
    int quad = lane >> 4, l15 = lane & 15;
    int wave_m = wid & 1, wave_n = wid >> 1;

    int bx, by, bz;
    if (SPLIT) {
        int bid = (int)blockIdx.x;
        int xcd = bid & 7, li = bid >> 3;
        bx = li % nx;
        int pl = li / nx;
        int ppx = (int)(gridDim.x >> 3) / nx;   // pairs per XCD
        int pair = xcd * ppx + pl;
        by = pair % ny;
        bz = pair / ny;
    } else {
        bx = blockIdx.x; by = blockIdx.y; bz = 0;
    }

    int bm0 = by * BM;     // node tile
    int bn0 = bx * BM;     // M tile
    int kbeg = SPLIT ? bz * Kseg : 0;
    int kend = SPLIT ? min(kbeg + Kseg, K) : K;

    f32x4 acc[4][4] = {};

    for (int k0 = kbeg; k0 < kend; k0 += BK) {
#pragma unroll
        for (int it = 0; it < 4; it++) {
            int idx = t + it * 256;
            int row = idx >> 3, sc = idx & 7;
            int c = sc ^ (row & 7);            // pre-swizzled source chunk
            int ga = bm0 + row; if (ga >= N) ga = N - 1;   // clamp (masked at store)
            gload16(A + (size_t)ga * K + k0 + c * 8, Als + idx * 8);
            gload16(Wb + (size_t)(bn0 + row) * K + k0 + c * 8, Bls + idx * 8);
        }
        __syncthreads();                        // drains vmcnt

#pragma unroll
        for (int ks = 0; ks < 2; ks++) {
            short8 af[4], bfr[4];
            int ck = ks * 4 + quad;
            int sw = (ck ^ (l15 & 7)) << 3;
#pragma unroll
            for (int mt = 0; mt < 4; mt++)
                af[mt] = *(const short8*)&Als[(wave_m * 64 + mt * 16 + l15) * BK + sw];
#pragma unroll
            for (int nt = 0; nt < 4; nt++)
                bfr[nt] = *(const short8*)&Bls[(wave_n * 64 + nt * 16 + l15) * BK + sw];
#pragma unroll
            for (int mt = 0; mt < 4; mt++)
#pragma unroll
                for (int nt = 0; nt < 4; nt++)
                    acc[mt][nt] = __builtin_amdgcn_mfma_f32_16x16x32_bf16(
                        af[mt], bfr[nt], acc[mt][nt], 0, 0, 0);
        }
        __syncthreads();
    }

    if (!SPLIT && CBF) {
        constexpr int TST = 68;
        unsigned short* tw = lds + wid * 64 * TST;
#pragma unroll
        for (int mt = 0; mt < 4; mt++) {
#pragma unroll
            for (int nt = 0; nt < 4; nt++) {
                int tcol = nt * 16 + l15;
                float bv = BIAS ? bias[bn0 + wave_n * 64 + tcol] : 0.f;
#pragma unroll
                for (int r = 0; r < 4; r++) {
                    float x = acc[mt][nt][r];
                    if (BIAS) x += bv;
                    if (ACT == 1) x = x > 0.f ? x : 0.1f * x;
                    if (SCALE) {
                        int row = bm0 + wave_m * 64 + mt * 16 + quad * 4 + r;
                        x *= rowscale[row < N ? row : N - 1];
                    }
                    tw[(mt * 16 + quad * 4 + r) * TST + tcol] = f2bf(x);
                }
            }
        }
        __syncthreads();
        bf16_t* C = (bf16_t*)Cv;
        int lrow0 = lane >> 3, lcol = (lane & 7) * 8;
#pragma unroll
        for (int it = 0; it < 8; it++) {
            int lrow = it * 8 + lrow0;
            int row = bm0 + wave_m * 64 + lrow;
            if (row < N) {
                u16x8 v = *(const u16x8*)&tw[lrow * TST + lcol];
                *(u16x8*)&C[(size_t)row * M + bn0 + wave_n * 64 + lcol] = v;
            }
        }
    } else {
        float* Pz = SPLIT ? ((float*)Cv + (size_t)bz * N * M) : (float*)Cv;
#pragma unroll
        for (int mt = 0; mt < 4; mt++) {
            int rbase = bm0 + wave_m * 64 + mt * 16 + quad * 4;
#pragma unroll
            for (int nt = 0; nt < 4; nt++) {
                int col = bn0 + wave_n * 64 + nt * 16 + l15;
                float bv = (BIAS && !SPLIT) ? bias[col] : 0.f;
#pragma unroll
                for (int r = 0; r < 4; r++) {
                    int row = rbase + r;
                    if (row >= N) continue;
                    float x = acc[mt][nt][r];
                    if (!SPLIT) {
                        if (BIAS) x += bv;
                        if (ACT == 1) x = x > 0.f ? x : 0.1f * x;
                    }
                    Pz[(size_t)row * M + col] = x;
                }
            }
        }
    }
}

// ---------------- MLP2 GEMM with fused MLP1-reduce in A-staging -------------
__global__ __launch_bounds__(256) void gemm_mlp2(
        const float* __restrict__ part6,   // [6][G*512] fp32
        const float* __restrict__ L1b,     // [512]
        const bf16_t* __restrict__ Wb,     // L2wb [128,512] bf16
        float* __restrict__ Pout,          // [4][G*128] fp32
        int G) {
    constexpr int BM = 128, BK = 64, K = 512, M = 128, NY = 40;
    __shared__ __align__(16) unsigned short lds[2 * BM * BK];   // 32 KB
    unsigned short* Als = lds;
    unsigned short* Bls = lds + BM * BK;

    int t = threadIdx.x;
    int lane = t & 63, wid = t >> 6;
    int quad = lane >> 4, l15 = lane & 15;
    int wave_m = wid & 1, wave_n = wid >> 1;

    int bid = (int)blockIdx.x;
    int xcd = bid & 7, li = bid >> 3;
    int ppx = (int)(gridDim.x >> 3);        // pairs per XCD (nx=1)
    int pair = xcd * ppx + li;
    int by = pair % NY;
    int bz = pair / NY;

    int bm0 = by * BM;
    int kbeg = bz * (K / 4);                // Kseg = 128
    size_t GK = (size_t)G * K;

    f32x4 acc[4][4] = {};

    for (int k0 = kbeg; k0 < kbeg + K / 4; k0 += BK) {
#pragma unroll
        for (int it = 0; it < 4; it++) {
            int idx = t + it * 256;
            int row = idx >> 3, sc = idx & 7;
            int cW = sc ^ (row & 7);
            gload16(Wb + (size_t)row * K + k0 + cW * 8, Bls + idx * 8);
            int g = bm0 + row; if (g >= G) g = G - 1;
            const float* pb = part6 + (size_t)g * K + k0 + sc * 8;
            float v[8] = {};
#pragma unroll
            for (int z = 0; z < 6; z++) {
                const float* pz = pb + (size_t)z * GK;
                float4 a = *(const float4*)pz;
                float4 b = *(const float4*)(pz + 4);
                v[0] += a.x; v[1] += a.y; v[2] += a.z; v[3] += a.w;
                v[4] += b.x; v[5] += b.y; v[6] += b.z; v[7] += b.w;
            }
            float4 b0 = *(const float4*)&L1b[k0 + sc * 8];
            float4 b1 = *(const float4*)&L1b[k0 + sc * 8 + 4];
            float bb[8] = {b0.x, b0.y, b0.z, b0.w, b1.x, b1.y, b1.z, b1.w};
            u16x8 o;
#pragma unroll
            for (int j = 0; j < 8; j++) {
                float xv = v[j] + bb[j];
                xv = xv > 0.f ? xv : 0.1f * xv;
                o[j] = f2bf(xv);
            }
            *(u16x8*)&Als[row * BK + ((sc ^ (row & 7)) << 3)] = o;
        }
        __syncthreads();                    // drains vmcnt + lgkm

#pragma unroll
        for (int ks = 0; ks < 2; ks++) {
            short8 af[4], bfr[4];
            int ck = ks * 4 + quad;
            int sw = (ck ^ (l15 & 7)) << 3;
#pragma unroll
            for (int mt = 0; mt < 4; mt++)
                af[mt] = *(const short8*)&Als[(wave_m * 64 + mt * 16 + l15) * BK + sw];
#pragma unroll
            for (int nt = 0; nt < 4; nt++)
                bfr[nt] = *(const short8*)&Bls[(wave_n * 64 + nt * 16 + l15) * BK + sw];
#pragma unroll
            for (int mt = 0; mt < 4; mt++)
#pragma unroll
                for (int nt = 0; nt < 4; nt++)
                    acc[mt][nt] = __builtin_amdgcn_mfma_f32_16x16x32_bf16(
                        af[mt], bfr[nt], acc[mt][nt], 0, 0, 0);
        }
        __syncthreads();
    }

    float* Pz = Pout + (size_t)bz * G * M;
#pragma unroll
    for (int mt = 0; mt < 4; mt++) {
        int rbase = bm0 + wave_m * 64 + mt * 16 + quad * 4;
#pragma unroll
        for (int nt = 0; nt < 4; nt++) {
            int col = wave_n * 64 + nt * 16 + l15;
#pragma unroll
            for (int r = 0; r < 4; r++) {
                int row = rbase + r;
                if (row >= G) continue;
                Pz[(size_t)row * M + col] = acc[mt][nt][r];
            }
        }
    }
}

// ------- fused agg(H1) + conv2-GEMM + lrelu + conv3-GEMM (BM=64, 48 KB) -----
// In-kernel PRE aggregation with 4-DEEP neighbor unroll: the fused kernel
// runs at ~12 waves/CU (latency-bound regime, 2.15 vs 3.8 TB/s standalone),
// so per-lane in-flight gather depth is the lever — 4 csr indices loaded,
// then all 16 row-chunk loads issued before any accumulation.
__global__ __launch_bounds__(256, 3) void gemm_fused23(
        const bf16_t* __restrict__ H1,   // [N,128] pre-scaled by dis
        const int* __restrict__ rowptr, const int* __restrict__ csr,
        const float* __restrict__ dis,
        const bf16_t* __restrict__ W2,   // [256,128] bf16
        const float*  __restrict__ b2,
        const bf16_t* __restrict__ W3,   // [128,256] bf16
        bf16_t* __restrict__ C,          // [N,128]
        int N) {
    __shared__ __align__(16) unsigned short lds[24576];   // 48 KB
    unsigned short* Als  = lds;            // [2][64][64] 16 KB  A tile (both halves)
    unsigned short* Bls  = lds + 8192;     // [256][64]   32 KB  W2 k-half tile
    unsigned short* H2ls = lds;            // [64][256]   32 KB  (aliases A + W2 head)
    unsigned short* B2ls = lds + 16384;    // [128][64]   16 KB  phase-2 W3 tile

    int t = threadIdx.x;
    int lane = t & 63, wid = t >> 6;
    int quad = lane >> 4, l15 = lane & 15;
    int wm = wid & 1, wn = wid >> 1;       // 2x2 wave tiling (both phases)
    int bm0 = blockIdx.x * 64;

    float bv[8];
#pragma unroll
    for (int nt = 0; nt < 8; nt++) bv[nt] = b2[wn * 128 + nt * 16 + l15];

    // ---- issue W2 k-half 0 staging first (flies under the gather) ----
#pragma unroll
    for (int it = 0; it < 8; it++) {           // W2 half: 2048 chunks
        int idx = t + it * 256;
        int row = idx >> 3, sc = idx & 7;
        int c = sc ^ (row & 7);
        gload16(W2 + (size_t)row * 128 + c * 8, Bls + idx * 8);
    }

    // ---- in-kernel PRE aggregation (4-deep) -> swizzled A tile in LDS ----
    {
        int r = t >> 2, l4 = t & 3;            // 64 rows x 4 lanes
        int row = bm0 + r; if (row >= N) row = N - 1;   // masked at C store
        int cb = l4 * 32;                      // 32 cols per lane
        const bf16_t* Hrow = H1 + (size_t)row * 128 + cb;
        float acc[32];
        {
            u16x8 v[4];
#pragma unroll
            for (int j = 0; j < 4; j++) v[j] = *(const u16x8*)(Hrow + j * 8);
#pragma unroll
            for (int j = 0; j < 4; j++)
#pragma unroll
                for (int f = 0; f < 8; f++) acc[j * 8 + f] = bf2f(v[j][f]);
        }
        int s = rowptr[row], e = rowptr[row + 1];
        int p = s;
        // 4-deep: 4 neighbor rows (16 chunk-loads) in flight per lane
        for (; p + 4 <= e; p += 4) {
            int s0 = csr[p], s1 = csr[p + 1], s2 = csr[p + 2], s3 = csr[p + 3];
            const bf16_t* p0 = H1 + (size_t)s0 * 128 + cb;
            const bf16_t* p1 = H1 + (size_t)s1 * 128 + cb;
            const bf16_t* p2 = H1 + (size_t)s2 * 128 + cb;
            const bf16_t* p3 = H1 + (size_t)s3 * 128 + cb;
            u16x8 a0[4], a1[4], a2[4], a3[4];
#pragma unroll
            for (int j = 0; j < 4; j++) {
                a0[j] = *(const u16x8*)(p0 + j * 8);
                a1[j] = *(const u16x8*)(p1 + j * 8);
                a2[j] = *(const u16x8*)(p2 + j * 8);
                a3[j] = *(const u16x8*)(p3 + j * 8);
            }
#pragma unroll
            for (int j = 0; j < 4; j++)
#pragma unroll
                for (int f = 0; f < 8; f++)
                    acc[j * 8 + f] += (bf2f(a0[j][f]) + bf2f(a1[j][f]))
                                    + (bf2f(a2[j][f]) + bf2f(a3[j][f]));
        }
        if (p + 2 <= e) {
            int s0 = csr[p], s1 = csr[p + 1];
            const bf16_t* p0 = H1 + (size_t)s0 * 128 + cb;
            const bf16_t* p1 = H1 + (size_t)s1 * 128 + cb;
            u16x8 a0[4], a1[4];
#pragma unroll
            for (int j = 0; j < 4; j++) { a0[j] = *(const u16x8*)(p0 + j * 8);
                                          a1[j] = *(const u16x8*)(p1 + j * 8); }
#pragma unroll
            for (int j = 0; j < 4; j++)
#pragma unroll
                for (int f = 0; f < 8; f++)
                    acc[j * 8 + f] += bf2f(a0[j][f]) + bf2f(a1[j][f]);
            p += 2;
        }
        if (p < e) {
            int s0 = csr[p];
            const bf16_t* p0 = H1 + (size_t)s0 * 128 + cb;
            u16x8 a0[4];
#pragma unroll
            for (int j = 0; j < 4; j++) a0[j] = *(const u16x8*)(p0 + j * 8);
#pragma unroll
            for (int j = 0; j < 4; j++)
#pragma unroll
                for (int f = 0; f < 8; f++) acc[j * 8 + f] += bf2f(a0[j][f]);
        }
        float di = dis[row];
#pragma unroll
        for (int j = 0; j < 4; j++) {
            int col0 = cb + j * 8;
            int h = col0 >> 6;                 // k-half
            int ck = (col0 & 63) >> 3;         // chunk within half
            int swc = ck ^ (r & 7);
            u16x8 o;
#pragma unroll
            for (int f = 0; f < 8; f++) o[f] = f2bf(acc[j * 8 + f] * di);
            *(u16x8*)&Als[h * 4096 + r * 64 + (swc << 3)] = o;
        }
    }
    __syncthreads();                           // gather ds_writes + W2 h0 loads

    // ---- phase 1: A x W2^T -> acc1 [64,256], per k-half ----
    f32x4 acc1[2][8] = {};
    for (int h = 0; h < 2; h++) {
        if (h > 0) {
#pragma unroll
            for (int it = 0; it < 8; it++) {   // W2 half 1
                int idx = t + it * 256;
                int row = idx >> 3, sc = idx & 7;
                int c = sc ^ (row & 7);
                gload16(W2 + (size_t)row * 128 + 64 + c * 8, Bls + idx * 8);
            }
            __syncthreads();
        }
#pragma unroll
        for (int ks = 0; ks < 2; ks++) {
            int ck = ks * 4 + quad;
            int sw = (ck ^ (l15 & 7)) << 3;
            short8 af[2];
#pragma unroll
            for (int mt = 0; mt < 2; mt++)
                af[mt] = *(const short8*)&Als[h * 4096 + (wm * 32 + mt * 16 + l15) * 64 + sw];
#pragma unroll
            for (int nt = 0; nt < 8; nt++) {
                short8 bfr = *(const short8*)&Bls[(wn * 128 + nt * 16 + l15) * 64 + sw];
#pragma unroll
                for (int mt = 0; mt < 2; mt++)
                    acc1[mt][nt] = __builtin_amdgcn_mfma_f32_16x16x32_bf16(
                        af[mt], bfr, acc1[mt][nt], 0, 0, 0);
            }
        }
        __syncthreads();
    }

    // ---- prefetch W3 k0=0 into B2ls while the H2 epilogue runs ----
#pragma unroll
    for (int it = 0; it < 4; it++) {           // W3: 1024 chunks
        int idx = t + it * 256;
        int row = idx >> 3, sc = idx & 7;
        int c = sc ^ (row & 7);
        gload16(W3 + (size_t)row * 256 + c * 8, B2ls + idx * 8);
    }

    // ---- phase-1 epilogue: bias + lrelu -> bf16, swizzled into H2ls ----
#pragma unroll
    for (int mt = 0; mt < 2; mt++) {
#pragma unroll
        for (int nt = 0; nt < 8; nt++) {
            int col = wn * 128 + nt * 16 + l15;
            int chunk = col >> 3, within = col & 7;
#pragma unroll
            for (int r = 0; r < 4; r++) {
                int row = wm * 32 + mt * 16 + quad * 4 + r;
                float xv = acc1[mt][nt][r] + bv[nt];
                xv = xv > 0.f ? xv : 0.1f * xv;
                H2ls[row * 256 + ((chunk ^ (row & 7)) << 3) + within] = f2bf(xv);
            }
        }
    }
    __syncthreads();   // drains W3 prefetch (vmcnt) + H2 ds_writes (lgkm)

    // ---- phase 2: C2 = H2ls * W3^T -> [64,128], wave owns 32x64 ----
    f32x4 acc2[2][4] = {};
    for (int k0 = 0; k0 < 256; k0 += 64) {
        if (k0 > 0) {
#pragma unroll
            for (int it = 0; it < 4; it++) {   // W3 tile: 1024 chunks
                int idx = t + it * 256;
                int row = idx >> 3, sc = idx & 7;
                int c = sc ^ (row & 7);
                gload16(W3 + (size_t)row * 256 + k0 + c * 8, B2ls + idx * 8);
            }
            __syncthreads();
        }
#pragma unroll
        for (int ks = 0; ks < 2; ks++) {
            int kc = (k0 >> 3) + ks * 4 + quad;
            int swa = (kc ^ (l15 & 7)) << 3;
            int swb = ((ks * 4 + quad) ^ (l15 & 7)) << 3;
            short8 af[2], bfr[4];
#pragma unroll
            for (int mt = 0; mt < 2; mt++)
                af[mt] = *(const short8*)&H2ls[(wm * 32 + mt * 16 + l15) * 256 + swa];
#pragma unroll
            for (int nt = 0; nt < 4; nt++)
                bfr[nt] = *(const short8*)&B2ls[(wn * 64 + nt * 16 + l15) * 64 + swb];
#pragma unroll
            for (int mt = 0; mt < 2; mt++)
#pragma unroll
                for (int nt = 0; nt < 4; nt++)
                    acc2[mt][nt] = __builtin_amdgcn_mfma_f32_16x16x32_bf16(
                        af[mt], bfr[nt], acc2[mt][nt], 0, 0, 0);
        }
        __syncthreads();
    }

    // ---- coalesced store epilogue (per-wave 32x64 via LDS), pre-scaled -----
    constexpr int TST = 68;
    unsigned short* tw = lds + wid * 32 * TST;     // 8704 shorts total, safe
#pragma unroll
    for (int mt = 0; mt < 2; mt++) {
#pragma unroll
        for (int r = 0; r < 4; r++) {
            int row = bm0 + wm * 32 + mt * 16 + quad * 4 + r;
            float ds = dis[row < N ? row : N - 1];
#pragma unroll
            for (int nt = 0; nt < 4; nt++) {
                int tcol = nt * 16 + l15;
                tw[(mt * 16 + quad * 4 + r) * TST + tcol] = f2bf(acc2[mt][nt][r] * ds);
            }
        }
    }
    __syncthreads();
    int lrow0 = lane >> 3, lcol = (lane & 7) * 8;
#pragma unroll
    for (int it = 0; it < 4; it++) {
        int lrow = it * 8 + lrow0;
        int row = bm0 + wm * 32 + lrow;
        if (row < N) {
            u16x8 v = *(const u16x8*)&tw[lrow * TST + lcol];
            *(u16x8*)&C[(size_t)row * 128 + wn * 64 + lcol] = v;
        }
    }
}

// ---------------- fused aggregation, sub-wave-per-node ----------------------
// PRE=true: input rows are pre-scaled by dis; inner loop is pure ADD.

template <int F, bool BACT, bool PRE>
__global__ __launch_bounds__(256) void k_agg(
        const bf16_t* __restrict__ H, const int* __restrict__ rowptr,
        const int* __restrict__ csr, const float* __restrict__ dis,
        const float* __restrict__ bias, bf16_t* __restrict__ out, int N) {
    constexpr int SUB = F / 8;          // lanes per node
    constexpr int NPW = 64 / SUB;       // nodes per wave
    constexpr int SH  = (SUB == 16) ? 4 : 3;
    int gtid = blockIdx.x * 256 + threadIdx.x;
    int wave = gtid >> 6, lane = gtid & 63;
    int sub = lane >> SH, sl = lane & (SUB - 1);
    int node = wave * NPW + sub;
    if (node >= N) return;
    float di = dis[node];
    int s = rowptr[node], e = rowptr[node + 1];

    auto load_row = [&](const bf16_t* p, float (&r)[8]) {
        u16x8 v = *(const u16x8*)p;
#pragma unroll
        for (int f = 0; f < 8; f++) r[f] = bf2f(v[f]);
    };

    float acc[8], acc2[8];
    {
        float r[8];
        load_row(H + (size_t)node * F + sl * 8, r);
        float sln = PRE ? 1.f : di * di;   // PRE: self row already carries di
#pragma unroll
        for (int f = 0; f < 8; f++) { acc[f] = r[f] * sln; acc2[f] = 0.f; }
    }
    int p = s;
    for (; p + 4 <= e; p += 4) {
        int s0 = csr[p], s1 = csr[p + 1], s2 = csr[p + 2], s3 = csr[p + 3];
        float r0[8], r1[8], r2[8], r3[8];
        load_row(H + (size_t)s0 * F + sl * 8, r0);
        load_row(H + (size_t)s1 * F + sl * 8, r1);
        load_row(H + (size_t)s2 * F + sl * 8, r2);
        load_row(H + (size_t)s3 * F + sl * 8, r3);
        if (PRE) {
#pragma unroll
            for (int f = 0; f < 8; f++) {
                acc[f]  += r0[f] + r2[f];
                acc2[f] += r1[f] + r3[f];
            }
        } else {
            float n0 = dis[s0] * di, n1 = dis[s1] * di;
            float n2 = dis[s2] * di, n3 = dis[s3] * di;
#pragma unroll
            for (int f = 0; f < 8; f++) {
                acc[f]  += r0[f] * n0; acc2[f] += r1[f] * n1;
                acc[f]  += r2[f] * n2; acc2[f] += r3[f] * n3;
            }
        }
    }
    if (p + 2 <= e) {
        int s0 = csr[p], s1 = csr[p + 1];
        float r0[8], r1[8];
        load_row(H + (size_t)s0 * F + sl * 8, r0);
        load_row(H + (size_t)s1 * F + sl * 8, r1);
        if (PRE) {
#pragma unroll
            for (int f = 0; f < 8; f++) { acc[f] += r0[f]; acc2[f] += r1[f]; }
        } else {
            float n0 = dis[s0] * di, n1 = dis[s1] * di;
#pragma unroll
            for (int f = 0; f < 8; f++) { acc[f] += r0[f] * n0; acc2[f] += r1[f] * n1; }
        }
        p += 2;
    }
    if (p < e) {
        int s0 = csr[p];
        float r0[8];
        load_row(H + (size_t)s0 * F + sl * 8, r0);
        if (PRE) {
#pragma unroll
            for (int f = 0; f < 8; f++) acc[f] += r0[f];
        } else {
            float n0 = dis[s0] * di;
#pragma unroll
            for (int f = 0; f < 8; f++) acc[f] += r0[f] * n0;
        }
    }

    float o[8];
#pragma unroll
    for (int f = 0; f < 8; f++) {
        float v = acc[f] + acc2[f];
        if (PRE) v *= di;
        if (BACT) {
            v += bias[sl * 8 + f];
            v = v > 0.f ? v : 0.1f * v;
        }
        o[f] = v;
    }
    u16x8 w = {f2bf(o[0]), f2bf(o[1]), f2bf(o[2]), f2bf(o[3]),
               f2bf(o[4]), f2bf(o[5]), f2bf(o[6]), f2bf(o[7])};
    *(u16x8*)(out + (size_t)node * F + sl * 8) = w;
}

// ---------------- fused MLP2-reduce + bias + lrelu + head ------------------

__global__ __launch_bounds__(256) void k_head2(
        const float* __restrict__ part, const float* __restrict__ L2b,
        const float* __restrict__ L3w, const float* __restrict__ L3b,
        float* __restrict__ out, int G) {
    int wv = (int)((blockIdx.x * blockDim.x + threadIdx.x) >> 6);
    int lane = threadIdx.x & 63;
    if (wv >= G) return;
    size_t base = (size_t)wv * 128 + lane * 2;
    size_t GM = (size_t)G * 128;
    float2 s = *(const float2*)&part[base];
#pragma unroll
    for (int z = 1; z < 4; z++) {
        float2 p = *(const float2*)&part[z * GM + base];
        s.x += p.x; s.y += p.y;
    }
    float2 b = *(const float2*)&L2b[lane * 2];
    float vx = s.x + b.x, vy = s.y + b.y;
    vx = vx > 0.f ? vx : 0.1f * vx;
    vy = vy > 0.f ? vy : 0.1f * vy;
    float2 wl = *(const float2*)&L3w[lane * 2];
    float d = vx * wl.x + vy * wl.y;
    for (int off = 32; off > 0; off >>= 1) d += __shfl_xor(d, off, 64);
    if (lane == 0) out[wv] = 1.f / (1.f + expf(-(d + L3b[0])));
}

// ---------------- launch ----------------

extern "C" void kernel_launch(void* const* d_in, const int* in_sizes, int n_in,
                              void* d_out, int out_size, void* d_ws, size_t ws_size,
                              hipStream_t stream) {
    const float* x   = (const float*)d_in[0];
    const int*   ei  = (const int*)d_in[1];
    const float* W1  = (const float*)d_in[2];  const float* b1  = (const float*)d_in[3];
    const float* W2  = (const float*)d_in[4];  const float* b2  = (const float*)d_in[5];
    const float* W3  = (const float*)d_in[6];  const float* b3  = (const float*)d_in[7];
    const float* L1w = (const float*)d_in[8];  const float* L1b = (const float*)d_in[9];
    const float* L2w = (const float*)d_in[10]; const float* L2b = (const float*)d_in[11];
    const float* L3w = (const float*)d_in[12]; const float* L3b = (const float*)d_in[13];
    float* out = (float*)d_out;

    const int C = 40;
    const int N = in_sizes[0] / C;     // 200000
    const int E = in_sizes[1] / 2;     // 1000000
    const int G = N / 40;              // 5000
    const int H1d = 128, H2d = 256, H3d = 128, M1 = 512, M2 = 128;
    const int K1 = 40 * H3d;           // 5120

    // ---- workspace layout ----
    char* wsb = (char*)d_ws;
    size_t off = 0;
    auto alloc = [&](size_t bytes) -> void* {
        void* p = wsb + off;
        off += (bytes + 255) & ~(size_t)255;
        return p;
    };
    int*    cnt8   = (int*)alloc(4 * 8 * (size_t)N);
    int*    rowptr = (int*)alloc(4 * (size_t)(N + 1));
    int*    cur    = (int*)alloc(4 * (size_t)N);
    int*    csr    = (int*)alloc(4 * (size_t)E);
    int*    bsum   = (int*)alloc(4 * 512);
    float*  dis    = (float*)alloc(4 * (size_t)N);
    bf16_t* Hb     = (bf16_t*)alloc(2 * (size_t)N * H2d);   // ping (102.4 MB)
    bf16_t* Xb     = (bf16_t*)alloc(2 * (size_t)N * H2d);   // pong (102.4 MB)
    bf16_t* W1b    = (bf16_t*)alloc(2 * (size_t)H1d * 64);
    bf16_t* W2b    = (bf16_t*)alloc(2 * (size_t)H2d * H1d);
    bf16_t* W3b    = (bf16_t*)alloc(2 * (size_t)H3d * H2d);
    bf16_t* L1wb   = (bf16_t*)alloc(2 * (size_t)M1 * K1);
    bf16_t* L2wb   = (bf16_t*)alloc(2 * (size_t)M2 * M1);
    if (off > ws_size) return;   // fail cleanly instead of faulting

    // aliasing (all within dead regions at time of use):
    int* src32 = (int*)Xb;        // packed edges during CSR build (Xb dead)
    int* dst32 = src32 + E;
    bf16_t* xb   = Hb;            // [N,64]  pad(x)          — dead after agg1
    bf16_t* A1b  = Xb;            // [N,64]  agg(x)          — overwrites src32/dst32
    bf16_t* H1   = Hb;            // [N,128] lrelu(A1 W1+b1)·dis — overwrites xb
    bf16_t* H3p  = Xb;            // [N,128] fused agg+conv2+3 out — overwrites A1b
    bf16_t* X3   = Hb;            // [N,128] lrelu(agg(H3p)+b3) — overwrites H1
    float*  part = (float*)Xb;    // MLP1 split-K partials [6][G*512] (61.4 MB)
    float*  part2 = part + 6 * (size_t)G * M1;   // MLP2 partials [4][G*128]

    // ---- weight pre-convert + x pad + cnt8 zero-fill (one dispatch) ----
    WcSeg s0 = {W1,  W1b,  H1d, 40,  64,  H1d * 64 / 8};
    WcSeg s1 = {W2,  W2b,  H2d, H1d, H1d, H2d * H1d / 8};
    WcSeg s2 = {W3,  W3b,  H3d, H2d, H2d, H3d * H2d / 8};
    WcSeg s3 = {L1w, L1wb, M1,  K1,  K1,  M1 * K1 / 8};
    WcSeg s4 = {L2w, L2wb, M2,  M1,  M1,  M2 * M1 / 8};
    WcSeg s5 = {x,   xb,   N,   40,  64,  N * 64 / 8};
    int wtotal = s0.nchunk + s1.nchunk + s2.nchunk + s3.nchunk + s4.nchunk + s5.nchunk;
    int ztotal = wtotal + 2 * N;       // 2N int4-chunks zero 8N ints of cnt8
    k_wconv<<<CDIV(ztotal, 256), 256, 0, stream>>>(s0, s1, s2, s3, s4, s5,
                                                   wtotal, cnt8, ztotal);

    // ---- CSR by dst (pack+hist+detect fused, XCD-range-filtered fill) ----
    k_packhist<<<CDIV(E, 256), 256, 0, stream>>>(ei, E, src32, dst32, cnt8, N);
    int nb = CDIV(N + 1, 1024);        // 196 <= 256
    k_blockred<<<nb, 256, 0, stream>>>(cnt8, bsum, N);
    k_scanwrite<<<nb, 256, 0, stream>>>(cnt8, bsum, rowptr, cur, dis, N, nb);
    int NR = CDIV(N, 8);               // nodes per XCD range
    k_fill_r<<<8 * CDIV(E, FILL_EPB), 256, 0, stream>>>(src32, dst32, E, cur, csr, N, NR);

    const int NB = CDIV(N, 128);       // 1563

    // ---- conv1 (aggregate-first in 40->64-dim); H1 output pre-scaled ----
    k_agg<64, false, false><<<CDIV(N, 32), 256, 0, stream>>>(xb, rowptr, csr, dis, nullptr, A1b, N);
    gemm_mfma<true, true, 1, false, true><<<dim3(1, NB), 256, 0, stream>>>(A1b, W1b, b1, H1, N, 64, H1d, 0, 0, 0, dis);
    // ---- agg(H1) + conv2 + conv3-transform fused in one kernel ----
    gemm_fused23<<<CDIV(N, 64), 256, 0, stream>>>(H1, rowptr, csr, dis, W2b, b2, W3b, H3p, N);
    k_agg<128, true, true><<<CDIV(N, 16), 256, 0, stream>>>(H3p, rowptr, csr, dis, b3, X3, N);

    // ---- readout MLP1: split-K S=6, XCD-grouped 1D grid (960 blocks) ----
    gemm_mfma<false, false, 0, true, false><<<960, 256, 0, stream>>>(X3, L1wb, nullptr, part, G, K1, M1, 896, 4, 40, nullptr);
    // ---- readout MLP2: k_red fused into A-staging; S=4, 160 blocks ----
    gemm_mlp2<<<160, 256, 0, stream>>>(part, L1b, L2wb, part2, G);
    k_head2<<<CDIV(G, 4), 256, 0, stream>>>(part2, L2b, L3w, L3b, out, G);
}

// Round 12
// 446.432 us; speedup vs baseline: 1.1000x; 1.0231x over previous
//
#include <hip/hip_runtime.h>
#include <cmath>

#define CDIV(a,b) (((a)+(b)-1)/(b))

typedef unsigned short bf16_t;
using short8 = __attribute__((ext_vector_type(8))) short;
using f32x4  = __attribute__((ext_vector_type(4))) float;
using u16x4  = __attribute__((ext_vector_type(4))) unsigned short;
using u16x8  = __attribute__((ext_vector_type(8))) unsigned short;

__device__ __forceinline__ float bf2f(unsigned short b) {
    unsigned u = ((unsigned)b) << 16;
    float f;
    __builtin_memcpy(&f, &u, 4);
    return f;
}
__device__ __forceinline__ unsigned short f2bf(float f) {
    unsigned u;
    __builtin_memcpy(&u, &f, 4);
    u = (u + 0x7FFFu + ((u >> 16) & 1u)) >> 16;
    return (unsigned short)u;
}

// async global->LDS, 16B per lane. LDS dest must be linear in lane order
// (wave-uniform base + lane*16); swizzle is folded into the GLOBAL address.
__device__ __forceinline__ void gload16(const bf16_t* g, unsigned short* l) {
    __builtin_amdgcn_global_load_lds(
        (const __attribute__((address_space(1))) void*)(g),
        (__attribute__((address_space(3))) void*)(l), 16, 0, 0);
}

__device__ __forceinline__ int edge_src(const int* ei, int E, int f, int i) {
    return f ? ei[2 * (size_t)i] : ei[i];
}
__device__ __forceinline__ int edge_dst(const int* ei, int E, int f, int i) {
    return f ? ei[2 * ((size_t)E + (size_t)i)] : ei[(size_t)E + (size_t)i];
}

// ---- pack edges to int32 + 8x-privatized dst histogram (detect inlined) ----
__global__ __launch_bounds__(256) void k_packhist(const int* __restrict__ ei, int E,
                                                  int* __restrict__ src32,
                                                  int* __restrict__ dst32,
                                                  int* __restrict__ cnt8, int N) {
    __shared__ int sflag;
    int t = threadIdx.x;
    if (t < 64) {   // whole wave 0: detect int64 layout from first 64 edges
        unsigned v = (unsigned)ei[2 * t + 1];
        unsigned long long m = __ballot(v != 0u);
        if (t == 0) sflag = (m == 0ULL) ? 1 : 0;
    }
    __syncthreads();
    int i = blockIdx.x * 256 + t;
    if (i >= E) return;
    int f = sflag;
    int s = edge_src(ei, E, f, i);
    int d = edge_dst(ei, E, f, i);
    src32[i] = s;
    dst32[i] = d;
    if ((unsigned)d < (unsigned)N)
        atomicAdd(&cnt8[(blockIdx.x & 7) * N + d], 1);
}

__global__ void k_blockred(const int* __restrict__ cnt8, int* __restrict__ bsum, int N) {
    __shared__ int sd[256];
    int b = blockIdx.x, t = threadIdx.x;
    int base = b * 1024 + t * 4;
    int s = 0;
#pragma unroll
    for (int i = 0; i < 4; i++) {
        int idx = base + i;
        if (idx < N)
#pragma unroll
            for (int r = 0; r < 8; r++) s += cnt8[r * N + idx];
    }
    sd[t] = s; __syncthreads();
    for (int off = 128; off > 0; off >>= 1) { if (t < off) sd[t] += sd[t + off]; __syncthreads(); }
    if (t == 0) bsum[b] = sd[0];
}

// scanwrite with the bsum scan inlined
__global__ void k_scanwrite(const int* __restrict__ cnt8, const int* __restrict__ bsum,
                            int* __restrict__ rowptr, int* __restrict__ cur,
                            float* __restrict__ dis, int N, int nb) {
    __shared__ int sb[256];
    __shared__ int sd[256];
    int b = blockIdx.x, t = threadIdx.x;
    int v0 = (t < nb) ? bsum[t] : 0;
    sb[t] = v0; __syncthreads();
    for (int off = 1; off < 256; off <<= 1) {
        int y = (t >= off) ? sb[t - off] : 0;
        __syncthreads();
        sb[t] += y;
        __syncthreads();
    }
    int block_pre = (b == 0) ? 0 : sb[b - 1];

    int base = b * 1024 + t * 4;
    int tot[4]; int s = 0;
#pragma unroll
    for (int i = 0; i < 4; i++) {
        int idx = base + i;
        tot[i] = 0;
        if (idx < N) {
#pragma unroll
            for (int r = 0; r < 8; r++) tot[i] += cnt8[r * N + idx];
        }
        s += tot[i];
    }
    sd[t] = s; __syncthreads();
    for (int off = 1; off < 256; off <<= 1) {
        int y = (t >= off) ? sd[t - off] : 0;
        __syncthreads();
        sd[t] += y;
        __syncthreads();
    }
    int pre = block_pre + sd[t] - s;
#pragma unroll
    for (int i = 0; i < 4; i++) {
        int idx = base + i;
        if (idx < N) {
            rowptr[idx] = pre;
            cur[idx] = pre;
            dis[idx] = rsqrtf((float)tot[i] + 1.0f);
            pre += tot[i];
        } else if (idx == N) {
            rowptr[N] = pre;
        }
    }
}

// Range-filtered fill (XCD write locality)
#define FILL_EPB 4096
__global__ __launch_bounds__(256) void k_fill_r(
        const int* __restrict__ src32, const int* __restrict__ dst32, int E,
        int* __restrict__ cur, int* __restrict__ csr, int N, int NR) {
    int r = blockIdx.x & 7;
    int chunk = blockIdx.x >> 3;
    int lo = r * NR;
    int hi = min(lo + NR, N);
    int base = chunk * FILL_EPB;
    int end = min(base + FILL_EPB, E);
    for (int i = base + threadIdx.x; i < end; i += 256) {
        int d = dst32[i];
        if (d >= lo && d < hi) {
            int s = src32[i];
            if ((unsigned)s < (unsigned)N) {
                int p = atomicAdd(&cur[d], 1);
                csr[p] = s;
            }
        }
    }
}

// ---------------- weight pre-convert + x pad + cnt8 zero-fill ---------------

struct WcSeg { const float* src; bf16_t* dst; int M, KW, KP, nchunk; };

__global__ __launch_bounds__(256) void k_wconv(WcSeg s0, WcSeg s1, WcSeg s2,
                                               WcSeg s3, WcSeg s4, WcSeg s5,
                                               int wtotal, int* __restrict__ zdst,
                                               int total) {
    int i = blockIdx.x * 256 + threadIdx.x;
    if (i >= total) return;
    if (i >= wtotal) {   // zero-fill tail: 16 B of cnt8 per thread
        int4 z = {0, 0, 0, 0};
        *(int4*)(zdst + (size_t)(i - wtotal) * 4) = z;
        return;
    }
    WcSeg s;
    if (i < s0.nchunk) s = s0;
    else if ((i -= s0.nchunk) < s1.nchunk) s = s1;
    else if ((i -= s1.nchunk) < s2.nchunk) s = s2;
    else if ((i -= s2.nchunk) < s3.nchunk) s = s3;
    else if ((i -= s3.nchunk) < s4.nchunk) s = s4;
    else { i -= s4.nchunk; s = s5; }
    int cpr = s.KP >> 3;                // chunks per row
    int row = i / cpr, kk = (i % cpr) << 3;
    short8 v = {};
    if (kk < s.KW) {
        const float4* p = (const float4*)(s.src + (size_t)row * s.KW + kk);
        float4 a = p[0], b = p[1];
        v[0] = (short)f2bf(a.x); v[1] = (short)f2bf(a.y);
        v[2] = (short)f2bf(a.z); v[3] = (short)f2bf(a.w);
        v[4] = (short)f2bf(b.x); v[5] = (short)f2bf(b.y);
        v[6] = (short)f2bf(b.z); v[7] = (short)f2bf(b.w);
    }
    *(short8*)(s.dst + (size_t)row * s.KP + kk) = v;
}

// ---------------- MFMA GEMM: C[i][j] = sum_k A[i][k] * Wb[j][k] --------------
// (SPLIT path used for MLP1; non-split CBF path no longer used for conv1.)

template <bool CBF, bool BIAS, int ACT, bool SPLIT, bool SCALE>
__global__ __launch_bounds__(256) void gemm_mfma(
        const bf16_t* __restrict__ A, const bf16_t* __restrict__ Wb,
        const float* __restrict__ bias, void* __restrict__ Cv,
        int N, int K, int M, int Kseg, int nx, int ny,
        const float* __restrict__ rowscale) {
    constexpr int BM = 128, BK = 64;
    __shared__ __align__(16) unsigned short lds[4 * 64 * 68];
    unsigned short* Als = lds;
    unsigned short* Bls = lds + BM * BK;

    int t = threadIdx.x;
    int lane = t & 63, wid = t >> 6;
    int quad = lane >> 4, l15 = lane & 15;
    int wave_m = wid & 1, wave_n = wid >> 1;

    int bx, by, bz;
    if (SPLIT) {
        int bid = (int)blockIdx.x;
        int xcd = bid & 7, li = bid >> 3;
        bx = li % nx;
        int pl = li / nx;
        int ppx = (int)(gridDim.x >> 3) / nx;   // pairs per XCD
        int pair = xcd * ppx + pl;
        by = pair % ny;
        bz = pair / ny;
    } else {
        bx = blockIdx.x; by = blockIdx.y; bz = 0;
    }

    int bm0 = by * BM;     // node tile
    int bn0 = bx * BM;     // M tile
    int kbeg = SPLIT ? bz * Kseg : 0;
    int kend = SPLIT ? min(kbeg + Kseg, K) : K;

    f32x4 acc[4][4] = {};

    for (int k0 = kbeg; k0 < kend; k0 += BK) {
#pragma unroll
        for (int it = 0; it < 4; it++) {
            int idx = t + it * 256;
            int row = idx >> 3, sc = idx & 7;
            int c = sc ^ (row & 7);            // pre-swizzled source chunk
            int ga = bm0 + row; if (ga >= N) ga = N - 1;   // clamp (masked at store)
            gload16(A + (size_t)ga * K + k0 + c * 8, Als + idx * 8);
            gload16(Wb + (size_t)(bn0 + row) * K + k0 + c * 8, Bls + idx * 8);
        }
        __syncthreads();                        // drains vmcnt

#pragma unroll
        for (int ks = 0; ks < 2; ks++) {
            short8 af[4], bfr[4];
            int ck = ks * 4 + quad;
            int sw = (ck ^ (l15 & 7)) << 3;
#pragma unroll
            for (int mt = 0; mt < 4; mt++)
                af[mt] = *(const short8*)&Als[(wave_m * 64 + mt * 16 + l15) * BK + sw];
#pragma unroll
            for (int nt = 0; nt < 4; nt++)
                bfr[nt] = *(const short8*)&Bls[(wave_n * 64 + nt * 16 + l15) * BK + sw];
#pragma unroll
            for (int mt = 0; mt < 4; mt++)
#pragma unroll
                for (int nt = 0; nt < 4; nt++)
                    acc[mt][nt] = __builtin_amdgcn_mfma_f32_16x16x32_bf16(
                        af[mt], bfr[nt], acc[mt][nt], 0, 0, 0);
        }
        __syncthreads();
    }

    if (!SPLIT && CBF) {
        constexpr int TST = 68;
        unsigned short* tw = lds + wid * 64 * TST;
#pragma unroll
        for (int mt = 0; mt < 4; mt++) {
#pragma unroll
            for (int nt = 0; nt < 4; nt++) {
                int tcol = nt * 16 + l15;
                float bv = BIAS ? bias[bn0 + wave_n * 64 + tcol] : 0.f;
#pragma unroll
                for (int r = 0; r < 4; r++) {
                    float x = acc[mt][nt][r];
                    if (BIAS) x += bv;
                    if (ACT == 1) x = x > 0.f ? x : 0.1f * x;
                    if (SCALE) {
                        int row = bm0 + wave_m * 64 + mt * 16 + quad * 4 + r;
                        x *= rowscale[row < N ? row : N - 1];
                    }
                    tw[(mt * 16 + quad * 4 + r) * TST + tcol] = f2bf(x);
                }
            }
        }
        __syncthreads();
        bf16_t* C = (bf16_t*)Cv;
        int lrow0 = lane >> 3, lcol = (lane & 7) * 8;
#pragma unroll
        for (int it = 0; it < 8; it++) {
            int lrow = it * 8 + lrow0;
            int row = bm0 + wave_m * 64 + lrow;
            if (row < N) {
                u16x8 v = *(const u16x8*)&tw[lrow * TST + lcol];
                *(u16x8*)&C[(size_t)row * M + bn0 + wave_n * 64 + lcol] = v;
            }
        }
    } else {
        float* Pz = SPLIT ? ((float*)Cv + (size_t)bz * N * M) : (float*)Cv;
#pragma unroll
        for (int mt = 0; mt < 4; mt++) {
            int rbase = bm0 + wave_m * 64 + mt * 16 + quad * 4;
#pragma unroll
            for (int nt = 0; nt < 4; nt++) {
                int col = bn0 + wave_n * 64 + nt * 16 + l15;
                float bv = (BIAS && !SPLIT) ? bias[col] : 0.f;
#pragma unroll
                for (int r = 0; r < 4; r++) {
                    int row = rbase + r;
                    if (row >= N) continue;
                    float x = acc[mt][nt][r];
                    if (!SPLIT) {
                        if (BIAS) x += bv;
                        if (ACT == 1) x = x > 0.f ? x : 0.1f * x;
                    }
                    Pz[(size_t)row * M + col] = x;
                }
            }
        }
    }
}

// ------- fused agg(x) + conv1-GEMM + bias + lrelu + dis-prescale ------------
// Per 128-row tile: in-kernel non-PRE gather of xb rows (2 lanes/row x 32
// cols, per-edge dis[s] gather since xb can't be pre-scaled before dis
// exists), swizzled into the A-LDS tile, then the single K=64 MFMA tile.
// Eliminates the k_agg<64> dispatch + the A1b 25.6 MB write / 25.6 MB read.
// W1 staging issued before the gather so it flies underneath.
__global__ __launch_bounds__(256, 4) void gemm_fused1(
        const bf16_t* __restrict__ xb,   // [N,64]
        const int* __restrict__ rowptr, const int* __restrict__ csr,
        const float* __restrict__ dis,
        const bf16_t* __restrict__ W1,   // [128,64] bf16
        const float* __restrict__ b1,
        bf16_t* __restrict__ H1,         // [N,128] = lrelu(agg W1^T + b1)·dis
        int N) {
    __shared__ __align__(16) unsigned short lds[17408];   // 34 KB (tw size)
    unsigned short* Als = lds;            // [128][64] 16 KB
    unsigned short* Bls = lds + 8192;     // [128][64] 16 KB

    int t = threadIdx.x;
    int lane = t & 63, wid = t >> 6;
    int quad = lane >> 4, l15 = lane & 15;
    int wave_m = wid & 1, wave_n = wid >> 1;
    int bm0 = blockIdx.x * 128;

    // ---- issue W1 staging first (flies under the gather) ----
#pragma unroll
    for (int it = 0; it < 4; it++) {           // 1024 chunks
        int idx = t + it * 256;
        int row = idx >> 3, sc = idx & 7;
        int c = sc ^ (row & 7);
        gload16(W1 + (size_t)row * 64 + c * 8, Bls + idx * 8);
    }

    // ---- in-kernel gather (non-PRE) -> swizzled A tile ----
    {
        int r = t >> 1, l2 = t & 1;            // 128 rows x 2 lanes
        int row = bm0 + r; if (row >= N) row = N - 1;   // masked at store
        int cb = l2 * 32;                      // 32 cols per lane
        const bf16_t* Xrow = xb + (size_t)row * 64 + cb;
        float di = dis[row];
        float acc[32];
        {
            u16x8 v[4];
#pragma unroll
            for (int j = 0; j < 4; j++) v[j] = *(const u16x8*)(Xrow + j * 8);
            float sln = di * di;               // self-loop norm
#pragma unroll
            for (int j = 0; j < 4; j++)
#pragma unroll
                for (int f = 0; f < 8; f++) acc[j * 8 + f] = bf2f(v[j][f]) * sln;
        }
        int s = rowptr[row], e = rowptr[row + 1];
        int p = s;
        for (; p + 2 <= e; p += 2) {
            int s0 = csr[p], s1 = csr[p + 1];
            float n0 = dis[s0] * di, n1 = dis[s1] * di;
            const bf16_t* p0 = xb + (size_t)s0 * 64 + cb;
            const bf16_t* p1 = xb + (size_t)s1 * 64 + cb;
            u16x8 a0[4], a1[4];
#pragma unroll
            for (int j = 0; j < 4; j++) { a0[j] = *(const u16x8*)(p0 + j * 8);
                                          a1[j] = *(const u16x8*)(p1 + j * 8); }
#pragma unroll
            for (int j = 0; j < 4; j++)
#pragma unroll
                for (int f = 0; f < 8; f++)
                    acc[j * 8 + f] += bf2f(a0[j][f]) * n0 + bf2f(a1[j][f]) * n1;
        }
        if (p < e) {
            int s0 = csr[p];
            float n0 = dis[s0] * di;
            const bf16_t* p0 = xb + (size_t)s0 * 64 + cb;
            u16x8 a0[4];
#pragma unroll
            for (int j = 0; j < 4; j++) a0[j] = *(const u16x8*)(p0 + j * 8);
#pragma unroll
            for (int j = 0; j < 4; j++)
#pragma unroll
                for (int f = 0; f < 8; f++) acc[j * 8 + f] += bf2f(a0[j][f]) * n0;
        }
#pragma unroll
        for (int j = 0; j < 4; j++) {
            int ck = l2 * 4 + j;               // chunk within row (0..7)
            int swc = ck ^ (r & 7);
            u16x8 o;
#pragma unroll
            for (int f = 0; f < 8; f++) o[f] = f2bf(acc[j * 8 + f]);
            *(u16x8*)&Als[r * 64 + (swc << 3)] = o;
        }
    }
    __syncthreads();                           // gather ds_writes + W1 loads

    // ---- single K=64 MFMA tile: wave owns 64x64 ----
    f32x4 acc[4][4] = {};
#pragma unroll
    for (int ks = 0; ks < 2; ks++) {
        short8 af[4], bfr[4];
        int ck = ks * 4 + quad;
        int sw = (ck ^ (l15 & 7)) << 3;
#pragma unroll
        for (int mt = 0; mt < 4; mt++)
            af[mt] = *(const short8*)&Als[(wave_m * 64 + mt * 16 + l15) * 64 + sw];
#pragma unroll
        for (int nt = 0; nt < 4; nt++)
            bfr[nt] = *(const short8*)&Bls[(wave_n * 64 + nt * 16 + l15) * 64 + sw];
#pragma unroll
        for (int mt = 0; mt < 4; mt++)
#pragma unroll
            for (int nt = 0; nt < 4; nt++)
                acc[mt][nt] = __builtin_amdgcn_mfma_f32_16x16x32_bf16(
                    af[mt], bfr[nt], acc[mt][nt], 0, 0, 0);
    }
    __syncthreads();

    // ---- epilogue: bias + lrelu + ·dis[row] -> coalesced via tw ----
    constexpr int TST = 68;
    unsigned short* tw = lds + wid * 64 * TST;   // 17408 shorts total, exact
#pragma unroll
    for (int mt = 0; mt < 4; mt++) {
#pragma unroll
        for (int r = 0; r < 4; r++) {
            int row = bm0 + wave_m * 64 + mt * 16 + quad * 4 + r;
            float ds = dis[row < N ? row : N - 1];
#pragma unroll
            for (int nt = 0; nt < 4; nt++) {
                int tcol = nt * 16 + l15;
                float x = acc[mt][nt][r] + b1[wave_n * 64 + tcol];
                x = x > 0.f ? x : 0.1f * x;
                tw[(mt * 16 + quad * 4 + r) * TST + tcol] = f2bf(x * ds);
            }
        }
    }
    __syncthreads();
    int lrow0 = lane >> 3, lcol = (lane & 7) * 8;
#pragma unroll
    for (int it = 0; it < 8; it++) {
        int lrow = it * 8 + lrow0;
        int row = bm0 + wave_m * 64 + lrow;
        if (row < N) {
            u16x8 v = *(const u16x8*)&tw[lrow * TST + lcol];
            *(u16x8*)&H1[(size_t)row * 128 + wave_n * 64 + lcol] = v;
        }
    }
}

// ---------------- MLP2 GEMM with fused MLP1-reduce in A-staging -------------
__global__ __launch_bounds__(256) void gemm_mlp2(
        const float* __restrict__ part6,   // [6][G*512] fp32
        const float* __restrict__ L1b,     // [512]
        const bf16_t* __restrict__ Wb,     // L2wb [128,512] bf16
        float* __restrict__ Pout,          // [4][G*128] fp32
        int G) {
    constexpr int BM = 128, BK = 64, K = 512, M = 128, NY = 40;
    __shared__ __align__(16) unsigned short lds[2 * BM * BK];   // 32 KB
    unsigned short* Als = lds;
    unsigned short* Bls = lds + BM * BK;

    int t = threadIdx.x;
    int lane = t & 63, wid = t >> 6;
    int quad = lane >> 4, l15 = lane & 15;
    int wave_m = wid & 1, wave_n = wid >> 1;

    int bid = (int)blockIdx.x;
    int xcd = bid & 7, li = bid >> 3;
    int ppx = (int)(gridDim.x >> 3);        // pairs per XCD (nx=1)
    int pair = xcd * ppx + li;
    int by = pair % NY;
    int bz = pair / NY;

    int bm0 = by * BM;
    int kbeg = bz * (K / 4);                // Kseg = 128
    size_t GK = (size_t)G * K;

    f32x4 acc[4][4] = {};

    for (int k0 = kbeg; k0 < kbeg + K / 4; k0 += BK) {
#pragma unroll
        for (int it = 0; it < 4; it++) {
            int idx = t + it * 256;
            int row = idx >> 3, sc = idx & 7;
            int cW = sc ^ (row & 7);
            gload16(Wb + (size_t)row * K + k0 + cW * 8, Bls + idx * 8);
            int g = bm0 + row; if (g >= G) g = G - 1;
            const float* pb = part6 + (size_t)g * K + k0 + sc * 8;
            float v[8] = {};
#pragma unroll
            for (int z = 0; z < 6; z++) {
                const float* pz = pb + (size_t)z * GK;
                float4 a = *(const float4*)pz;
                float4 b = *(const float4*)(pz + 4);
                v[0] += a.x; v[1] += a.y; v[2] += a.z; v[3] += a.w;
                v[4] += b.x; v[5] += b.y; v[6] += b.z; v[7] += b.w;
            }
            float4 b0 = *(const float4*)&L1b[k0 + sc * 8];
            float4 b1 = *(const float4*)&L1b[k0 + sc * 8 + 4];
            float bb[8] = {b0.x, b0.y, b0.z, b0.w, b1.x, b1.y, b1.z, b1.w};
            u16x8 o;
#pragma unroll
            for (int j = 0; j < 8; j++) {
                float xv = v[j] + bb[j];
                xv = xv > 0.f ? xv : 0.1f * xv;
                o[j] = f2bf(xv);
            }
            *(u16x8*)&Als[row * BK + ((sc ^ (row & 7)) << 3)] = o;
        }
        __syncthreads();                    // drains vmcnt + lgkm

#pragma unroll
        for (int ks = 0; ks < 2; ks++) {
            short8 af[4], bfr[4];
            int ck = ks * 4 + quad;
            int sw = (ck ^ (l15 & 7)) << 3;
#pragma unroll
            for (int mt = 0; mt < 4; mt++)
                af[mt] = *(const short8*)&Als[(wave_m * 64 + mt * 16 + l15) * BK + sw];
#pragma unroll
            for (int nt = 0; nt < 4; nt++)
                bfr[nt] = *(const short8*)&Bls[(wave_n * 64 + nt * 16 + l15) * BK + sw];
#pragma unroll
            for (int mt = 0; mt < 4; mt++)
#pragma unroll
                for (int nt = 0; nt < 4; nt++)
                    acc[mt][nt] = __builtin_amdgcn_mfma_f32_16x16x32_bf16(
                        af[mt], bfr[nt], acc[mt][nt], 0, 0, 0);
        }
        __syncthreads();
    }

    float* Pz = Pout + (size_t)bz * G * M;
#pragma unroll
    for (int mt = 0; mt < 4; mt++) {
        int rbase = bm0 + wave_m * 64 + mt * 16 + quad * 4;
#pragma unroll
        for (int nt = 0; nt < 4; nt++) {
            int col = wave_n * 64 + nt * 16 + l15;
#pragma unroll
            for (int r = 0; r < 4; r++) {
                int row = rbase + r;
                if (row >= G) continue;
                Pz[(size_t)row * M + col] = acc[mt][nt][r];
            }
        }
    }
}

// ------- fused agg(H1) + conv2-GEMM + lrelu + conv3-GEMM (BM=64, 48 KB) -----
__global__ __launch_bounds__(256, 3) void gemm_fused23(
        const bf16_t* __restrict__ H1,   // [N,128] pre-scaled by dis
        const int* __restrict__ rowptr, const int* __restrict__ csr,
        const float* __restrict__ dis,
        const bf16_t* __restrict__ W2,   // [256,128] bf16
        const float*  __restrict__ b2,
        const bf16_t* __restrict__ W3,   // [128,256] bf16
        bf16_t* __restrict__ C,          // [N,128]
        int N) {
    __shared__ __align__(16) unsigned short lds[24576];   // 48 KB
    unsigned short* Als  = lds;            // [2][64][64] 16 KB  A tile (both halves)
    unsigned short* Bls  = lds + 8192;     // [256][64]   32 KB  W2 k-half tile
    unsigned short* H2ls = lds;            // [64][256]   32 KB  (aliases A + W2 head)
    unsigned short* B2ls = lds + 16384;    // [128][64]   16 KB  phase-2 W3 tile

    int t = threadIdx.x;
    int lane = t & 63, wid = t >> 6;
    int quad = lane >> 4, l15 = lane & 15;
    int wm = wid & 1, wn = wid >> 1;       // 2x2 wave tiling (both phases)
    int bm0 = blockIdx.x * 64;

    float bv[8];
#pragma unroll
    for (int nt = 0; nt < 8; nt++) bv[nt] = b2[wn * 128 + nt * 16 + l15];

    // ---- issue W2 k-half 0 staging first (flies under the gather) ----
#pragma unroll
    for (int it = 0; it < 8; it++) {           // W2 half: 2048 chunks
        int idx = t + it * 256;
        int row = idx >> 3, sc = idx & 7;
        int c = sc ^ (row & 7);
        gload16(W2 + (size_t)row * 128 + c * 8, Bls + idx * 8);
    }

    // ---- in-kernel PRE aggregation (4-deep) -> swizzled A tile in LDS ----
    {
        int r = t >> 2, l4 = t & 3;            // 64 rows x 4 lanes
        int row = bm0 + r; if (row >= N) row = N - 1;   // masked at C store
        int cb = l4 * 32;                      // 32 cols per lane
        const bf16_t* Hrow = H1 + (size_t)row * 128 + cb;
        float acc[32];
        {
            u16x8 v[4];
#pragma unroll
            for (int j = 0; j < 4; j++) v[j] = *(const u16x8*)(Hrow + j * 8);
#pragma unroll
            for (int j = 0; j < 4; j++)
#pragma unroll
                for (int f = 0; f < 8; f++) acc[j * 8 + f] = bf2f(v[j][f]);
        }
        int s = rowptr[row], e = rowptr[row + 1];
        int p = s;
        for (; p + 4 <= e; p += 4) {
            int s0 = csr[p], s1 = csr[p + 1], s2 = csr[p + 2], s3 = csr[p + 3];
            const bf16_t* p0 = H1 + (size_t)s0 * 128 + cb;
            const bf16_t* p1 = H1 + (size_t)s1 * 128 + cb;
            const bf16_t* p2 = H1 + (size_t)s2 * 128 + cb;
            const bf16_t* p3 = H1 + (size_t)s3 * 128 + cb;
            u16x8 a0[4], a1[4], a2[4], a3[4];
#pragma unroll
            for (int j = 0; j < 4; j++) {
                a0[j] = *(const u16x8*)(p0 + j * 8);
                a1[j] = *(const u16x8*)(p1 + j * 8);
                a2[j] = *(const u16x8*)(p2 + j * 8);
                a3[j] = *(const u16x8*)(p3 + j * 8);
            }
#pragma unroll
            for (int j = 0; j < 4; j++)
#pragma unroll
                for (int f = 0; f < 8; f++)
                    acc[j * 8 + f] += (bf2f(a0[j][f]) + bf2f(a1[j][f]))
                                    + (bf2f(a2[j][f]) + bf2f(a3[j][f]));
        }
        if (p + 2 <= e) {
            int s0 = csr[p], s1 = csr[p + 1];
            const bf16_t* p0 = H1 + (size_t)s0 * 128 + cb;
            const bf16_t* p1 = H1 + (size_t)s1 * 128 + cb;
            u16x8 a0[4], a1[4];
#pragma unroll
            for (int j = 0; j < 4; j++) { a0[j] = *(const u16x8*)(p0 + j * 8);
                                          a1[j] = *(const u16x8*)(p1 + j * 8); }
#pragma unroll
            for (int j = 0; j < 4; j++)
#pragma unroll
                for (int f = 0; f < 8; f++)
                    acc[j * 8 + f] += bf2f(a0[j][f]) + bf2f(a1[j][f]);
            p += 2;
        }
        if (p < e) {
            int s0 = csr[p];
            const bf16_t* p0 = H1 + (size_t)s0 * 128 + cb;
            u16x8 a0[4];
#pragma unroll
            for (int j = 0; j < 4; j++) a0[j] = *(const u16x8*)(p0 + j * 8);
#pragma unroll
            for (int j = 0; j < 4; j++)
#pragma unroll
                for (int f = 0; f < 8; f++) acc[j * 8 + f] += bf2f(a0[j][f]);
        }
        float di = dis[row];
#pragma unroll
        for (int j = 0; j < 4; j++) {
            int col0 = cb + j * 8;
            int h = col0 >> 6;                 // k-half
            int ck = (col0 & 63) >> 3;         // chunk within half
            int swc = ck ^ (r & 7);
            u16x8 o;
#pragma unroll
            for (int f = 0; f < 8; f++) o[f] = f2bf(acc[j * 8 + f] * di);
            *(u16x8*)&Als[h * 4096 + r * 64 + (swc << 3)] = o;
        }
    }
    __syncthreads();                           // gather ds_writes + W2 h0 loads

    // ---- phase 1: A x W2^T -> acc1 [64,256], per k-half ----
    f32x4 acc1[2][8] = {};
    for (int h = 0; h < 2; h++) {
        if (h > 0) {
#pragma unroll
            for (int it = 0; it < 8; it++) {   // W2 half 1
                int idx = t + it * 256;
                int row = idx >> 3, sc = idx & 7;
                int c = sc ^ (row & 7);
                gload16(W2 + (size_t)row * 128 + 64 + c * 8, Bls + idx * 8);
            }
            __syncthreads();
        }
#pragma unroll
        for (int ks = 0; ks < 2; ks++) {
            int ck = ks * 4 + quad;
            int sw = (ck ^ (l15 & 7)) << 3;
            short8 af[2];
#pragma unroll
            for (int mt = 0; mt < 2; mt++)
                af[mt] = *(const short8*)&Als[h * 4096 + (wm * 32 + mt * 16 + l15) * 64 + sw];
#pragma unroll
            for (int nt = 0; nt < 8; nt++) {
                short8 bfr = *(const short8*)&Bls[(wn * 128 + nt * 16 + l15) * 64 + sw];
#pragma unroll
                for (int mt = 0; mt < 2; mt++)
                    acc1[mt][nt] = __builtin_amdgcn_mfma_f32_16x16x32_bf16(
                        af[mt], bfr, acc1[mt][nt], 0, 0, 0);
            }
        }
        __syncthreads();
    }

    // ---- prefetch W3 k0=0 into B2ls while the H2 epilogue runs ----
#pragma unroll
    for (int it = 0; it < 4; it++) {           // W3: 1024 chunks
        int idx = t + it * 256;
        int row = idx >> 3, sc = idx & 7;
        int c = sc ^ (row & 7);
        gload16(W3 + (size_t)row * 256 + c * 8, B2ls + idx * 8);
    }

    // ---- phase-1 epilogue: bias + lrelu -> bf16, swizzled into H2ls ----
#pragma unroll
    for (int mt = 0; mt < 2; mt++) {
#pragma unroll
        for (int nt = 0; nt < 8; nt++) {
            int col = wn * 128 + nt * 16 + l15;
            int chunk = col >> 3, within = col & 7;
#pragma unroll
            for (int r = 0; r < 4; r++) {
                int row = wm * 32 + mt * 16 + quad * 4 + r;
                float xv = acc1[mt][nt][r] + bv[nt];
                xv = xv > 0.f ? xv : 0.1f * xv;
                H2ls[row * 256 + ((chunk ^ (row & 7)) << 3) + within] = f2bf(xv);
            }
        }
    }
    __syncthreads();   // drains W3 prefetch (vmcnt) + H2 ds_writes (lgkm)

    // ---- phase 2: C2 = H2ls * W3^T -> [64,128], wave owns 32x64 ----
    f32x4 acc2[2][4] = {};
    for (int k0 = 0; k0 < 256; k0 += 64) {
        if (k0 > 0) {
#pragma unroll
            for (int it = 0; it < 4; it++) {   // W3 tile: 1024 chunks
                int idx = t + it * 256;
                int row = idx >> 3, sc = idx & 7;
                int c = sc ^ (row & 7);
                gload16(W3 + (size_t)row * 256 + k0 + c * 8, B2ls + idx * 8);
            }
            __syncthreads();
        }
#pragma unroll
        for (int ks = 0; ks < 2; ks++) {
            int kc = (k0 >> 3) + ks * 4 + quad;
            int swa = (kc ^ (l15 & 7)) << 3;
            int swb = ((ks * 4 + quad) ^ (l15 & 7)) << 3;
            short8 af[2], bfr[4];
#pragma unroll
            for (int mt = 0; mt < 2; mt++)
                af[mt] = *(const short8*)&H2ls[(wm * 32 + mt * 16 + l15) * 256 + swa];
#pragma unroll
            for (int nt = 0; nt < 4; nt++)
                bfr[nt] = *(const short8*)&B2ls[(wn * 64 + nt * 16 + l15) * 64 + swb];
#pragma unroll
            for (int mt = 0; mt < 2; mt++)
#pragma unroll
                for (int nt = 0; nt < 4; nt++)
                    acc2[mt][nt] = __builtin_amdgcn_mfma_f32_16x16x32_bf16(
                        af[mt], bfr[nt], acc2[mt][nt], 0, 0, 0);
        }
        __syncthreads();
    }

    // ---- coalesced store epilogue (per-wave 32x64 via LDS), pre-scaled -----
    constexpr int TST = 68;
    unsigned short* tw = lds + wid * 32 * TST;     // 8704 shorts total, safe
#pragma unroll
    for (int mt = 0; mt < 2; mt++) {
#pragma unroll
        for (int r = 0; r < 4; r++) {
            int row = bm0 + wm * 32 + mt * 16 + quad * 4 + r;
            float ds = dis[row < N ? row : N - 1];
#pragma unroll
            for (int nt = 0; nt < 4; nt++) {
                int tcol = nt * 16 + l15;
                tw[(mt * 16 + quad * 4 + r) * TST + tcol] = f2bf(acc2[mt][nt][r] * ds);
            }
        }
    }
    __syncthreads();
    int lrow0 = lane >> 3, lcol = (lane & 7) * 8;
#pragma unroll
    for (int it = 0; it < 4; it++) {
        int lrow = it * 8 + lrow0;
        int row = bm0 + wm * 32 + lrow;
        if (row < N) {
            u16x8 v = *(const u16x8*)&tw[lrow * TST + lcol];
            *(u16x8*)&C[(size_t)row * 128 + wn * 64 + lcol] = v;
        }
    }
}

// ---------------- fused aggregation, sub-wave-per-node (PRE form) -----------

template <int F, bool BACT, bool PRE>
__global__ __launch_bounds__(256) void k_agg(
        const bf16_t* __restrict__ H, const int* __restrict__ rowptr,
        const int* __restrict__ csr, const float* __restrict__ dis,
        const float* __restrict__ bias, bf16_t* __restrict__ out, int N) {
    constexpr int SUB = F / 8;          // lanes per node
    constexpr int NPW = 64 / SUB;       // nodes per wave
    constexpr int SH  = (SUB == 16) ? 4 : 3;
    int gtid = blockIdx.x * 256 + threadIdx.x;
    int wave = gtid >> 6, lane = gtid & 63;
    int sub = lane >> SH, sl = lane & (SUB - 1);
    int node = wave * NPW + sub;
    if (node >= N) return;
    float di = dis[node];
    int s = rowptr[node], e = rowptr[node + 1];

    auto load_row = [&](const bf16_t* p, float (&r)[8]) {
        u16x8 v = *(const u16x8*)p;
#pragma unroll
        for (int f = 0; f < 8; f++) r[f] = bf2f(v[f]);
    };

    float acc[8], acc2[8];
    {
        float r[8];
        load_row(H + (size_t)node * F + sl * 8, r);
        float sln = PRE ? 1.f : di * di;   // PRE: self row already carries di
#pragma unroll
        for (int f = 0; f < 8; f++) { acc[f] = r[f] * sln; acc2[f] = 0.f; }
    }
    int p = s;
    for (; p + 4 <= e; p += 4) {
        int s0 = csr[p], s1 = csr[p + 1], s2 = csr[p + 2], s3 = csr[p + 3];
        float r0[8], r1[8], r2[8], r3[8];
        load_row(H + (size_t)s0 * F + sl * 8, r0);
        load_row(H + (size_t)s1 * F + sl * 8, r1);
        load_row(H + (size_t)s2 * F + sl * 8, r2);
        load_row(H + (size_t)s3 * F + sl * 8, r3);
        if (PRE) {
#pragma unroll
            for (int f = 0; f < 8; f++) {
                acc[f]  += r0[f] + r2[f];
                acc2[f] += r1[f] + r3[f];
            }
        } else {
            float n0 = dis[s0] * di, n1 = dis[s1] * di;
            float n2 = dis[s2] * di, n3 = dis[s3] * di;
#pragma unroll
            for (int f = 0; f < 8; f++) {
                acc[f]  += r0[f] * n0; acc2[f] += r1[f] * n1;
                acc[f]  += r2[f] * n2; acc2[f] += r3[f] * n3;
            }
        }
    }
    if (p + 2 <= e) {
        int s0 = csr[p], s1 = csr[p + 1];
        float r0[8], r1[8];
        load_row(H + (size_t)s0 * F + sl * 8, r0);
        load_row(H + (size_t)s1 * F + sl * 8, r1);
        if (PRE) {
#pragma unroll
            for (int f = 0; f < 8; f++) { acc[f] += r0[f]; acc2[f] += r1[f]; }
        } else {
            float n0 = dis[s0] * di, n1 = dis[s1] * di;
#pragma unroll
            for (int f = 0; f < 8; f++) { acc[f] += r0[f] * n0; acc2[f] += r1[f] * n1; }
        }
        p += 2;
    }
    if (p < e) {
        int s0 = csr[p];
        float r0[8];
        load_row(H + (size_t)s0 * F + sl * 8, r0);
        if (PRE) {
#pragma unroll
            for (int f = 0; f < 8; f++) acc[f] += r0[f];
        } else {
            float n0 = dis[s0] * di;
#pragma unroll
            for (int f = 0; f < 8; f++) acc[f] += r0[f] * n0;
        }
    }

    float o[8];
#pragma unroll
    for (int f = 0; f < 8; f++) {
        float v = acc[f] + acc2[f];
        if (PRE) v *= di;
        if (BACT) {
            v += bias[sl * 8 + f];
            v = v > 0.f ? v : 0.1f * v;
        }
        o[f] = v;
    }
    u16x8 w = {f2bf(o[0]), f2bf(o[1]), f2bf(o[2]), f2bf(o[3]),
               f2bf(o[4]), f2bf(o[5]), f2bf(o[6]), f2bf(o[7])};
    *(u16x8*)(out + (size_t)node * F + sl * 8) = w;
}

// ---------------- fused MLP2-reduce + bias + lrelu + head ------------------

__global__ __launch_bounds__(256) void k_head2(
        const float* __restrict__ part, const float* __restrict__ L2b,
        const float* __restrict__ L3w, const float* __restrict__ L3b,
        float* __restrict__ out, int G) {
    int wv = (int)((blockIdx.x * blockDim.x + threadIdx.x) >> 6);
    int lane = threadIdx.x & 63;
    if (wv >= G) return;
    size_t base = (size_t)wv * 128 + lane * 2;
    size_t GM = (size_t)G * 128;
    float2 s = *(const float2*)&part[base];
#pragma unroll
    for (int z = 1; z < 4; z++) {
        float2 p = *(const float2*)&part[z * GM + base];
        s.x += p.x; s.y += p.y;
    }
    float2 b = *(const float2*)&L2b[lane * 2];
    float vx = s.x + b.x, vy = s.y + b.y;
    vx = vx > 0.f ? vx : 0.1f * vx;
    vy = vy > 0.f ? vy : 0.1f * vy;
    float2 wl = *(const float2*)&L3w[lane * 2];
    float d = vx * wl.x + vy * wl.y;
    for (int off = 32; off > 0; off >>= 1) d += __shfl_xor(d, off, 64);
    if (lane == 0) out[wv] = 1.f / (1.f + expf(-(d + L3b[0])));
}

// ---------------- launch ----------------

extern "C" void kernel_launch(void* const* d_in, const int* in_sizes, int n_in,
                              void* d_out, int out_size, void* d_ws, size_t ws_size,
                              hipStream_t stream) {
    const float* x   = (const float*)d_in[0];
    const int*   ei  = (const int*)d_in[1];
    const float* W1  = (const float*)d_in[2];  const float* b1  = (const float*)d_in[3];
    const float* W2  = (const float*)d_in[4];  const float* b2  = (const float*)d_in[5];
    const float* W3  = (const float*)d_in[6];  const float* b3  = (const float*)d_in[7];
    const float* L1w = (const float*)d_in[8];  const float* L1b = (const float*)d_in[9];
    const float* L2w = (const float*)d_in[10]; const float* L2b = (const float*)d_in[11];
    const float* L3w = (const float*)d_in[12]; const float* L3b = (const float*)d_in[13];
    float* out = (float*)d_out;

    const int C = 40;
    const int N = in_sizes[0] / C;     // 200000
    const int E = in_sizes[1] / 2;     // 1000000
    const int G = N / 40;              // 5000
    const int H1d = 128, H2d = 256, H3d = 128, M1 = 512, M2 = 128;
    const int K1 = 40 * H3d;           // 5120

    // ---- workspace layout ----
    char* wsb = (char*)d_ws;
    size_t off = 0;
    auto alloc = [&](size_t bytes) -> void* {
        void* p = wsb + off;
        off += (bytes + 255) & ~(size_t)255;
        return p;
    };
    int*    cnt8   = (int*)alloc(4 * 8 * (size_t)N);
    int*    rowptr = (int*)alloc(4 * (size_t)(N + 1));
    int*    cur    = (int*)alloc(4 * (size_t)N);
    int*    csr    = (int*)alloc(4 * (size_t)E);
    int*    bsum   = (int*)alloc(4 * 512);
    float*  dis    = (float*)alloc(4 * (size_t)N);
    bf16_t* Hb     = (bf16_t*)alloc(2 * (size_t)N * H2d);   // ping (102.4 MB)
    bf16_t* Xb     = (bf16_t*)alloc(2 * (size_t)N * H2d);   // pong (102.4 MB)
    bf16_t* W1b    = (bf16_t*)alloc(2 * (size_t)H1d * 64);
    bf16_t* W2b    = (bf16_t*)alloc(2 * (size_t)H2d * H1d);
    bf16_t* W3b    = (bf16_t*)alloc(2 * (size_t)H3d * H2d);
    bf16_t* L1wb   = (bf16_t*)alloc(2 * (size_t)M1 * K1);
    bf16_t* L2wb   = (bf16_t*)alloc(2 * (size_t)M2 * M1);
    if (off > ws_size) return;   // fail cleanly instead of faulting

    // aliasing (all within dead regions at time of use):
    //   xb [N,64] lives in Hb; fused1 reads it (random rows) so H1 must go
    //   to Xb (src32/dst32 are dead once k_fill_r completes, before fused1).
    //   fused23 reads H1 (Xb), writes H3p -> Hb (xb dead after fused1).
    //   k_agg PRE reads H3p (Hb), writes X3 -> Xb (H1 dead after fused23).
    //   MLP1 reads X3 (Xb), writes part -> Hb (H3p dead after k_agg).
    int* src32 = (int*)Xb;        // packed edges during CSR build
    int* dst32 = src32 + E;
    bf16_t* xb   = Hb;            // [N,64]  pad(x)
    bf16_t* H1   = Xb;            // [N,128] fused1 out (pre-scaled by dis)
    bf16_t* H3p  = Hb;            // [N,128] fused23 out (pre-scaled by dis)
    bf16_t* X3   = Xb;            // [N,128] lrelu(agg(H3p)+b3)
    float*  part = (float*)Hb;    // MLP1 split-K partials [6][G*512] (61.4 MB)
    float*  part2 = part + 6 * (size_t)G * M1;   // MLP2 partials [4][G*128]

    // ---- weight pre-convert + x pad + cnt8 zero-fill (one dispatch) ----
    WcSeg s0 = {W1,  W1b,  H1d, 40,  64,  H1d * 64 / 8};
    WcSeg s1 = {W2,  W2b,  H2d, H1d, H1d, H2d * H1d / 8};
    WcSeg s2 = {W3,  W3b,  H3d, H2d, H2d, H3d * H2d / 8};
    WcSeg s3 = {L1w, L1wb, M1,  K1,  K1,  M1 * K1 / 8};
    WcSeg s4 = {L2w, L2wb, M2,  M1,  M1,  M2 * M1 / 8};
    WcSeg s5 = {x,   xb,   N,   40,  64,  N * 64 / 8};
    int wtotal = s0.nchunk + s1.nchunk + s2.nchunk + s3.nchunk + s4.nchunk + s5.nchunk;
    int ztotal = wtotal + 2 * N;       // 2N int4-chunks zero 8N ints of cnt8
    k_wconv<<<CDIV(ztotal, 256), 256, 0, stream>>>(s0, s1, s2, s3, s4, s5,
                                                   wtotal, cnt8, ztotal);

    // ---- CSR by dst (pack+hist+detect fused, XCD-range-filtered fill) ----
    k_packhist<<<CDIV(E, 256), 256, 0, stream>>>(ei, E, src32, dst32, cnt8, N);
    int nb = CDIV(N + 1, 1024);        // 196 <= 256
    k_blockred<<<nb, 256, 0, stream>>>(cnt8, bsum, N);
    k_scanwrite<<<nb, 256, 0, stream>>>(cnt8, bsum, rowptr, cur, dis, N, nb);
    int NR = CDIV(N, 8);               // nodes per XCD range
    k_fill_r<<<8 * CDIV(E, FILL_EPB), 256, 0, stream>>>(src32, dst32, E, cur, csr, N, NR);

    // ---- conv1: agg(x) + GEMM fused; H1 output pre-scaled by dis ----
    gemm_fused1<<<CDIV(N, 128), 256, 0, stream>>>(xb, rowptr, csr, dis, W1b, b1, H1, N);
    // ---- agg(H1) + conv2 + conv3-transform fused in one kernel ----
    gemm_fused23<<<CDIV(N, 64), 256, 0, stream>>>(H1, rowptr, csr, dis, W2b, b2, W3b, H3p, N);
    k_agg<128, true, true><<<CDIV(N, 16), 256, 0, stream>>>(H3p, rowptr, csr, dis, b3, X3, N);

    // ---- readout MLP1: split-K S=6, XCD-grouped 1D grid (960 blocks) ----
    gemm_mfma<false, false, 0, true, false><<<960, 256, 0, stream>>>(X3, L1wb, nullptr, part, G, K1, M1, 896, 4, 40, nullptr);
    // ---- readout MLP2: k_red fused into A-staging; S=4, 160 blocks ----
    gemm_mlp2<<<160, 256, 0, stream>>>(part, L1b, L2wb, part2, G);
    k_head2<<<CDIV(G, 4), 256, 0, stream>>>(part2, L2b, L3w, L3b, out, G);
}